// Round 2
// baseline (2442.610 us; speedup 1.0000x reference)
//
#include <hip/hip_runtime.h>
#include <cstdint>
#include <cstddef>

constexpr int kS  = 2048;
constexpr int kD  = 1024;
constexpr int kH  = 16;
constexpr int kDH = 64;
constexpr int kR  = 16;

// ---------------- scalars: inv(2*bw^2), lam (fp64) ----------------
__global__ __launch_bounds__(64) void kar_scalars_kernel(const float* __restrict__ bw,
                                                         const float* __restrict__ lreg,
                                                         double* __restrict__ SC) {
  if (threadIdx.x == 0) {
    double b = log1p(exp((double)bw[0])) + 1e-6;   // softplus + EPS
    SC[0] = 1.0 / (2.0 * b * b);
    SC[1] = log1p(exp((double)lreg[0]));           // lam
  }
}

// ---------------- QKV projection: (2048x1024)x(1024x1024), head-layout out ----------------
__global__ __launch_bounds__(256) void kar_gemm_qkv_kernel(
    const float* __restrict__ x,
    const float* __restrict__ Wq, const float* __restrict__ Wk, const float* __restrict__ Wv,
    float* __restrict__ q, float* __restrict__ k, float* __restrict__ v) {
  const float* W = (blockIdx.z == 0) ? Wq : (blockIdx.z == 1) ? Wk : Wv;
  float* outp    = (blockIdx.z == 0) ? q  : (blockIdx.z == 1) ? k  : v;
  const int n0 = blockIdx.x * 64;
  const int m0 = blockIdx.y * 64;
  const int tid = threadIdx.x;
  const int tx = tid & 15, ty = tid >> 4;
  __shared__ float As[16][68];
  __shared__ float Bs[16][68];
  double acc[4][4] = {};
  const int lr = tid >> 2;
  const int lk = (tid & 3) * 4;
  const int br = tid >> 4;
  const int bc = (tid & 15) * 4;
  for (int k0 = 0; k0 < kD; k0 += 16) {
    const float4 a4 = *(const float4*)&x[(size_t)(m0 + lr) * kD + k0 + lk];
    const float4 b4 = *(const float4*)&W[(size_t)(k0 + br) * kD + n0 + bc];
    __syncthreads();
    As[lk + 0][lr] = a4.x; As[lk + 1][lr] = a4.y;
    As[lk + 2][lr] = a4.z; As[lk + 3][lr] = a4.w;
    *(float4*)&Bs[br][bc] = b4;
    __syncthreads();
    float c32[4][4] = {};
#pragma unroll
    for (int kk = 0; kk < 16; kk++) {
      const float4 av = *(const float4*)&As[kk][ty * 4];
      const float4 bv = *(const float4*)&Bs[kk][tx * 4];
      const float a_[4] = {av.x, av.y, av.z, av.w};
      const float b_[4] = {bv.x, bv.y, bv.z, bv.w};
#pragma unroll
      for (int i = 0; i < 4; i++)
#pragma unroll
        for (int j = 0; j < 4; j++) c32[i][j] = fmaf(a_[i], b_[j], c32[i][j]);
    }
#pragma unroll
    for (int i = 0; i < 4; i++)
#pragma unroll
      for (int j = 0; j < 4; j++) acc[i][j] += (double)c32[i][j];
  }
  const int h = n0 >> 6;  // 64-wide tile == one head
#pragma unroll
  for (int i = 0; i < 4; i++) {
    const int s = m0 + ty * 4 + i;
    float4 o;
    o.x = (float)acc[i][0]; o.y = (float)acc[i][1];
    o.z = (float)acc[i][2]; o.w = (float)acc[i][3];
    *(float4*)&outp[((size_t)h * kS + s) * kDH + tx * 4] = o;
  }
}

// ---------------- final GEMM: out = tmp @ Wo (plain layout) ----------------
__global__ __launch_bounds__(256) void kar_gemm_plain_kernel(
    const float* __restrict__ A, const float* __restrict__ W, float* __restrict__ C) {
  const int n0 = blockIdx.x * 64;
  const int m0 = blockIdx.y * 64;
  const int tid = threadIdx.x;
  const int tx = tid & 15, ty = tid >> 4;
  __shared__ float As[16][68];
  __shared__ float Bs[16][68];
  double acc[4][4] = {};
  const int lr = tid >> 2;
  const int lk = (tid & 3) * 4;
  const int br = tid >> 4;
  const int bc = (tid & 15) * 4;
  for (int k0 = 0; k0 < kD; k0 += 16) {
    const float4 a4 = *(const float4*)&A[(size_t)(m0 + lr) * kD + k0 + lk];
    const float4 b4 = *(const float4*)&W[(size_t)(k0 + br) * kD + n0 + bc];
    __syncthreads();
    As[lk + 0][lr] = a4.x; As[lk + 1][lr] = a4.y;
    As[lk + 2][lr] = a4.z; As[lk + 3][lr] = a4.w;
    *(float4*)&Bs[br][bc] = b4;
    __syncthreads();
    float c32[4][4] = {};
#pragma unroll
    for (int kk = 0; kk < 16; kk++) {
      const float4 av = *(const float4*)&As[kk][ty * 4];
      const float4 bv = *(const float4*)&Bs[kk][tx * 4];
      const float a_[4] = {av.x, av.y, av.z, av.w};
      const float b_[4] = {bv.x, bv.y, bv.z, bv.w};
#pragma unroll
      for (int i = 0; i < 4; i++)
#pragma unroll
        for (int j = 0; j < 4; j++) c32[i][j] = fmaf(a_[i], b_[j], c32[i][j]);
    }
#pragma unroll
    for (int i = 0; i < 4; i++)
#pragma unroll
      for (int j = 0; j < 4; j++) acc[i][j] += (double)c32[i][j];
  }
#pragma unroll
  for (int i = 0; i < 4; i++) {
    const int s = m0 + ty * 4 + i;
    float4 o;
    o.x = (float)acc[i][0]; o.y = (float)acc[i][1];
    o.z = (float)acc[i][2]; o.w = (float)acc[i][3];
    *(float4*)&C[(size_t)s * kD + n0 + tx * 4] = o;
  }
}

// ---------------- norms: qn/kn[h][s] = ||.||^2 (fp64) ----------------
__global__ __launch_bounds__(256) void kar_norms_kernel(const float* __restrict__ q,
                                                        const float* __restrict__ k,
                                                        double* __restrict__ qn,
                                                        double* __restrict__ kn) {
  int o = blockIdx.x * 256 + threadIdx.x;  // 0 .. 2*H*S-1
  const float* src; double* dst; int p;
  if (o < kH * kS) { src = q; dst = qn; p = o; }
  else             { src = k; dst = kn; p = o - kH * kS; }
  const float* row = src + (size_t)p * kDH;
  double s = 0.0;
  for (int i = 0; i < kDH; i += 4) {
    float4 x4 = *(const float4*)&row[i];
    s += (double)x4.x * (double)x4.x + (double)x4.y * (double)x4.y +
         (double)x4.z * (double)x4.z + (double)x4.w * (double)x4.w;
  }
  dst[p] = s;
}

// ---------------- U[h][s][p] = sum_r pe[s][r] * hp[h][r][p] ----------------
__global__ __launch_bounds__(256) void kar_u_kernel(const float* __restrict__ pe,
                                                    const float* __restrict__ hp,
                                                    float* __restrict__ U) {
  int o = blockIdx.x * 256 + threadIdx.x;  // < H*S*R
  int r = o & 15, s = (o >> 4) & 2047, h = o >> 15;
  double acc = 0.0;
#pragma unroll
  for (int rp = 0; rp < kR; rp++)
    acc += (double)pe[s * kR + rp] * (double)hp[((h * kR) + rp) * kR + r];
  U[o] = (float)acc;
}

// ---------------- K[h][s][t] = exp(-max(||q||^2+||k||^2-2 q.k,0) * inv2bw2) ----------------
__global__ __launch_bounds__(256) void kar_buildK_kernel(
    const float* __restrict__ q, const float* __restrict__ k,
    const double* __restrict__ qn, const double* __restrict__ kn,
    const double* __restrict__ SC, float* __restrict__ Kmat) {
  const int h  = blockIdx.z;
  const int t0 = blockIdx.x * 64;
  const int s0 = blockIdx.y * 64;
  const int tid = threadIdx.x;
  const int tx = tid & 15, ty = tid >> 4;
  __shared__ float Qs[64][68];   // [dh][s_local]
  __shared__ float Ks_[64][68];  // [dh][t_local]
  __shared__ double qns[64], kns[64];
  const float* qh = q + (size_t)h * kS * kDH;
  const float* kh = k + (size_t)h * kS * kDH;
#pragma unroll
  for (int rep = 0; rep < 4; rep++) {
    const int row = rep * 16 + (tid >> 4);
    const int c = (tid & 15) * 4;
    const float4 a = *(const float4*)&qh[(size_t)(s0 + row) * kDH + c];
    Qs[c + 0][row] = a.x; Qs[c + 1][row] = a.y; Qs[c + 2][row] = a.z; Qs[c + 3][row] = a.w;
    const float4 b = *(const float4*)&kh[(size_t)(t0 + row) * kDH + c];
    Ks_[c + 0][row] = b.x; Ks_[c + 1][row] = b.y; Ks_[c + 2][row] = b.z; Ks_[c + 3][row] = b.w;
  }
  if (tid < 64)                       qns[tid] = qn[h * kS + s0 + tid];
  else if (tid < 128)                 kns[tid - 64] = kn[h * kS + t0 + (tid - 64)];
  __syncthreads();
  double dot[4][4] = {};
  for (int kc = 0; kc < kDH; kc += 16) {
    float c32[4][4] = {};
#pragma unroll
    for (int kk = 0; kk < 16; kk++) {
      const float4 av = *(const float4*)&Qs[kc + kk][ty * 4];
      const float4 bv = *(const float4*)&Ks_[kc + kk][tx * 4];
      const float a_[4] = {av.x, av.y, av.z, av.w};
      const float b_[4] = {bv.x, bv.y, bv.z, bv.w};
#pragma unroll
      for (int i = 0; i < 4; i++)
#pragma unroll
        for (int j = 0; j < 4; j++) c32[i][j] = fmaf(a_[i], b_[j], c32[i][j]);
    }
#pragma unroll
    for (int i = 0; i < 4; i++)
#pragma unroll
      for (int j = 0; j < 4; j++) dot[i][j] += (double)c32[i][j];
  }
  const double c = SC[0];
#pragma unroll
  for (int i = 0; i < 4; i++) {
    const int s = s0 + ty * 4 + i;
    float4 o;
    double d0 = fmax(qns[ty * 4 + i] + kns[tx * 4 + 0] - 2.0 * dot[i][0], 0.0);
    double d1 = fmax(qns[ty * 4 + i] + kns[tx * 4 + 1] - 2.0 * dot[i][1], 0.0);
    double d2 = fmax(qns[ty * 4 + i] + kns[tx * 4 + 2] - 2.0 * dot[i][2], 0.0);
    double d3 = fmax(qns[ty * 4 + i] + kns[tx * 4 + 3] - 2.0 * dot[i][3], 0.0);
    o.x = (float)exp(-d0 * c); o.y = (float)exp(-d1 * c);
    o.z = (float)exp(-d2 * c); o.w = (float)exp(-d3 * c);
    *(float4*)&Kmat[((size_t)(h * kS + s)) * kS + t0 + tx * 4] = o;
  }
}

// ---------------- diag_p[h][s] = softplus(K_ss)*diag_scale[h] + reg (fp64 recompute) ----------------
__global__ __launch_bounds__(256) void kar_diagp_kernel(
    const float* __restrict__ q, const float* __restrict__ k,
    const double* __restrict__ qn, const double* __restrict__ kn,
    const double* __restrict__ SC, const float* __restrict__ dsc,
    const float* __restrict__ reg, double* __restrict__ dgp) {
  int o = blockIdx.x * 256 + threadIdx.x;  // < H*S
  int h = o >> 11;
  const float* qp = q + (size_t)o * kDH;
  const float* kp = k + (size_t)o * kDH;
  double dot = 0.0;
  for (int i = 0; i < kDH; i++) dot += (double)qp[i] * (double)kp[i];
  double dist = fmax(qn[o] + kn[o] - 2.0 * dot, 0.0);
  double Kss = exp(-dist * SC[0]);
  double sp  = log1p(exp(Kss));
  dgp[o] = sp * (double)dsc[h] + (double)reg[0];
}

// ---------------- Path A: per-head K @ alpha from materialized K ----------------
template <bool FINAL>
__global__ __launch_bounds__(256) void kar_iterk_kernel(
    const float* __restrict__ Kmat, const float* __restrict__ alpha,
    const float* __restrict__ v, const double* __restrict__ SC,
    float* __restrict__ outp) {
  const int h  = blockIdx.y;
  const int s0 = blockIdx.x * 64;
  const float* Kh = Kmat + (size_t)h * kS * kS;
  const float* ah = alpha + (size_t)h * kS * kDH;
  const float* vh = v + (size_t)h * kS * kDH;
  const int tid = threadIdx.x;
  const int tx = tid & 15, ty = tid >> 4;
  __shared__ float Ks_[16][68];
  __shared__ float As_[16][68];
  double acc[4][4] = {};
  const int lr = tid >> 2;
  const int lk = (tid & 3) * 4;
  const int br = tid >> 4;
  const int bc = (tid & 15) * 4;
  for (int t0 = 0; t0 < kS; t0 += 16) {
    const float4 a4 = *(const float4*)&Kh[(size_t)(s0 + lr) * kS + t0 + lk];
    const float4 b4 = *(const float4*)&ah[(size_t)(t0 + br) * kDH + bc];
    __syncthreads();
    Ks_[lk + 0][lr] = a4.x; Ks_[lk + 1][lr] = a4.y;
    Ks_[lk + 2][lr] = a4.z; Ks_[lk + 3][lr] = a4.w;
    *(float4*)&As_[br][bc] = b4;
    __syncthreads();
    float c32[4][4] = {};
#pragma unroll
    for (int kk = 0; kk < 16; kk++) {
      const float4 av = *(const float4*)&Ks_[kk][ty * 4];
      const float4 bv = *(const float4*)&As_[kk][tx * 4];
      const float a_[4] = {av.x, av.y, av.z, av.w};
      const float b_[4] = {bv.x, bv.y, bv.z, bv.w};
#pragma unroll
      for (int i = 0; i < 4; i++)
#pragma unroll
        for (int j = 0; j < 4; j++) c32[i][j] = fmaf(a_[i], b_[j], c32[i][j]);
    }
#pragma unroll
    for (int i = 0; i < 4; i++)
#pragma unroll
      for (int j = 0; j < 4; j++) acc[i][j] += (double)c32[i][j];
  }
  if (FINAL) {
#pragma unroll
    for (int i = 0; i < 4; i++) {
      const int s = s0 + ty * 4 + i;
      float4 o;
      o.x = (float)acc[i][0]; o.y = (float)acc[i][1];
      o.z = (float)acc[i][2]; o.w = (float)acc[i][3];
      *(float4*)&outp[(size_t)s * kD + h * kDH + tx * 4] = o;  // (s, h*64+dh)
    }
  } else {
    const double lam = SC[1];
#pragma unroll
    for (int i = 0; i < 4; i++) {
      const int s = s0 + ty * 4 + i;
      const float4 vv = *(const float4*)&vh[(size_t)s * kDH + tx * 4];
      const float4 aa = *(const float4*)&ah[(size_t)s * kDH + tx * 4];
      float4 o;
      o.x = (float)((double)vv.x - (acc[i][0] + lam * (double)aa.x));
      o.y = (float)((double)vv.y - (acc[i][1] + lam * (double)aa.y));
      o.z = (float)((double)vv.z - (acc[i][2] + lam * (double)aa.z));
      o.w = (float)((double)vv.w - (acc[i][3] + lam * (double)aa.w));
      *(float4*)&outp[((size_t)h * kS + s) * kDH + tx * 4] = o;
    }
  }
}

// ---------------- Path B: fused on-the-fly K tile * alpha (no K materialization) ----------------
// Per block: (s-block of 64, head). Loops over t-tiles of 64:
//   phase 1: 64x64 K tile = exp(-(qn+kn-2 q.k)*c) (fp32 products, fp64 fold/16, fp64 exp, fp32 store)
//   phase 2: acc += K_tile @ alpha_tile (fp32 products, fp64 fold/16)
// Identical rounding points to the materialized path.
template <bool FINAL>
__global__ __launch_bounds__(256) void kar_fused_iterk_kernel(
    const float* __restrict__ q, const float* __restrict__ k,
    const float* __restrict__ alpha, const float* __restrict__ v,
    const double* __restrict__ qn, const double* __restrict__ kn,
    const double* __restrict__ SC, float* __restrict__ outp) {
  const int h  = blockIdx.y;
  const int s0 = blockIdx.x * 64;
  const int tid = threadIdx.x;
  const int tx = tid & 15, ty = tid >> 4;
  __shared__ float Qs[64][68];   // [dh][s_local], persistent
  __shared__ float Ks_[64][68];  // phase1: [dh][t_local]; reused phase2 as Kt[t_local][s_local]
  __shared__ float As_[64][68];  // [t_local][d]
  __shared__ double qns[64], kns[64];
  const float* qh = q + (size_t)h * kS * kDH;
  const float* kh = k + (size_t)h * kS * kDH;
  const float* ah = alpha + (size_t)h * kS * kDH;
  const float* vh = v + (size_t)h * kS * kDH;

  {
    const int row = (tid >> 4);
    const int c = (tid & 15) * 4;
#pragma unroll
    for (int rep = 0; rep < 4; rep++) {
      const int rr = rep * 16 + row;
      const float4 a = *(const float4*)&qh[(size_t)(s0 + rr) * kDH + c];
      Qs[c + 0][rr] = a.x; Qs[c + 1][rr] = a.y; Qs[c + 2][rr] = a.z; Qs[c + 3][rr] = a.w;
    }
    if (tid < 64) qns[tid] = qn[h * kS + s0 + tid];
  }

  const double cc = SC[0];
  double acc[4][4] = {};
  for (int t0 = 0; t0 < kS; t0 += 64) {
    __syncthreads();  // previous phase-2 reads of Ks_/As_ done (and Qs/qns ready on first pass)
    {
      const int row = (tid >> 4);
      const int c = (tid & 15) * 4;
#pragma unroll
      for (int rep = 0; rep < 4; rep++) {
        const int rr = rep * 16 + row;
        const float4 b = *(const float4*)&kh[(size_t)(t0 + rr) * kDH + c];
        Ks_[c + 0][rr] = b.x; Ks_[c + 1][rr] = b.y; Ks_[c + 2][rr] = b.z; Ks_[c + 3][rr] = b.w;
        *(float4*)&As_[rr][c] = *(const float4*)&ah[(size_t)(t0 + rr) * kDH + c];
      }
      if (tid < 64) kns[tid] = kn[h * kS + t0 + tid];
    }
    __syncthreads();
    // phase 1: QK^T for this tile
    double dot[4][4] = {};
    for (int kc = 0; kc < kDH; kc += 16) {
      float c32[4][4] = {};
#pragma unroll
      for (int kk = 0; kk < 16; kk++) {
        const float4 av = *(const float4*)&Qs[kc + kk][ty * 4];
        const float4 bv = *(const float4*)&Ks_[kc + kk][tx * 4];
        const float a_[4] = {av.x, av.y, av.z, av.w};
        const float b_[4] = {bv.x, bv.y, bv.z, bv.w};
#pragma unroll
        for (int i = 0; i < 4; i++)
#pragma unroll
          for (int j = 0; j < 4; j++) c32[i][j] = fmaf(a_[i], b_[j], c32[i][j]);
      }
#pragma unroll
      for (int i = 0; i < 4; i++)
#pragma unroll
        for (int j = 0; j < 4; j++) dot[i][j] += (double)c32[i][j];
    }
    float Kv[4][4];
#pragma unroll
    for (int i = 0; i < 4; i++)
#pragma unroll
      for (int j = 0; j < 4; j++) {
        double d = fmax(qns[ty * 4 + i] + kns[tx * 4 + j] - 2.0 * dot[i][j], 0.0);
        Kv[i][j] = (float)exp(-d * cc);
      }
    __syncthreads();  // all lanes done reading Ks_ (k data)
    // store K tile transposed: Kt[t_local][s_local]
#pragma unroll
    for (int i = 0; i < 4; i++)
#pragma unroll
      for (int j = 0; j < 4; j++) Ks_[tx * 4 + j][ty * 4 + i] = Kv[i][j];
    __syncthreads();
    // phase 2: acc += Kt^T * alpha_tile  (output (s,d))
    for (int kc = 0; kc < 64; kc += 16) {
      float c32[4][4] = {};
#pragma unroll
      for (int kk = 0; kk < 16; kk++) {
        const float4 av = *(const float4*)&Ks_[kc + kk][ty * 4];  // K[t][s=ty*4..]
        const float4 bv = *(const float4*)&As_[kc + kk][tx * 4];  // alpha[t][d=tx*4..]
        const float a_[4] = {av.x, av.y, av.z, av.w};
        const float b_[4] = {bv.x, bv.y, bv.z, bv.w};
#pragma unroll
        for (int i = 0; i < 4; i++)
#pragma unroll
          for (int j = 0; j < 4; j++) c32[i][j] = fmaf(a_[i], b_[j], c32[i][j]);
      }
#pragma unroll
      for (int i = 0; i < 4; i++)
#pragma unroll
        for (int j = 0; j < 4; j++) acc[i][j] += (double)c32[i][j];
    }
  }
  if (FINAL) {
#pragma unroll
    for (int i = 0; i < 4; i++) {
      const int s = s0 + ty * 4 + i;
      float4 o;
      o.x = (float)acc[i][0]; o.y = (float)acc[i][1];
      o.z = (float)acc[i][2]; o.w = (float)acc[i][3];
      *(float4*)&outp[(size_t)s * kD + h * kDH + tx * 4] = o;
    }
  } else {
    const double lam = SC[1];
#pragma unroll
    for (int i = 0; i < 4; i++) {
      const int s = s0 + ty * 4 + i;
      const float4 vv = *(const float4*)&vh[(size_t)s * kDH + tx * 4];
      const float4 aa = *(const float4*)&ah[(size_t)s * kDH + tx * 4];
      float4 o;
      o.x = (float)((double)vv.x - (acc[i][0] + lam * (double)aa.x));
      o.y = (float)((double)vv.y - (acc[i][1] + lam * (double)aa.y));
      o.z = (float)((double)vv.z - (acc[i][2] + lam * (double)aa.z));
      o.w = (float)((double)vv.w - (acc[i][3] + lam * (double)aa.w));
      *(float4*)&outp[((size_t)h * kS + s) * kDH + tx * 4] = o;
    }
  }
}

// ---------------- ut_r partials ----------------
__global__ __launch_bounds__(256) void kar_utr_partial_kernel(
    const float* __restrict__ Ubuf, const float* __restrict__ rbuf,
    double* __restrict__ utrp) {
  const int h  = blockIdx.y;
  const int sb = blockIdx.x * 128;
  const int t  = threadIdx.x;
  __shared__ float Uch[32][16];
  __shared__ float Rch[32][64];
  double acc[4] = {};
  for (int cs = 0; cs < 128; cs += 32) {
    __syncthreads();
    if (t < 128) {
      const int i = t >> 2, f = (t & 3) * 4;
      *(float4*)&Uch[i][f] = *(const float4*)&Ubuf[((size_t)(h * kS) + sb + cs + i) * kR + f];
    }
#pragma unroll
    for (int rep = 0; rep < 2; rep++) {
      const int e = t + rep * 256;
      const int i = e >> 4, c = (e & 15) * 4;
      *(float4*)&Rch[i][c] = *(const float4*)&rbuf[((size_t)(h * kS) + sb + cs + i) * kDH + c];
    }
    __syncthreads();
    for (int i = 0; i < 32; i++) {
#pragma unroll
      for (int rep = 0; rep < 4; rep++) {
        const int p = t + rep * 256;
        const int r = p >> 6, d = p & 63;
        acc[rep] += (double)Uch[i][r] * (double)Rch[i][d];
      }
    }
  }
#pragma unroll
  for (int rep = 0; rep < 4; rep++) {
    const int p = t + rep * 256;
    const int r = p >> 6, d = p & 63;
    utrp[(((size_t)(h * 16) + blockIdx.x) * kR + r) * kDH + d] = acc[rep];
  }
}

__global__ __launch_bounds__(256) void kar_utr_reduce_kernel(const double* __restrict__ utrp,
                                                             double* __restrict__ utr) {
  int o = blockIdx.x * 256 + threadIdx.x;  // < H*R*DH
  int h = o >> 10, rd = o & 1023;
  double s = 0.0;
#pragma unroll
  for (int j = 0; j < 16; j++) s += utrp[(size_t)h * 16384 + (size_t)j * 1024 + rd];
  utr[o] = s;
}

// ---------------- alpha (+)= r*diag_p + U @ utr ----------------
__global__ __launch_bounds__(256) void kar_update_kernel(
    const float* __restrict__ rsrc, const double* __restrict__ dgp,
    const float* __restrict__ Ubuf, const double* __restrict__ utr,
    float* __restrict__ alpha, int first) {
  int e = blockIdx.x * 256 + threadIdx.x;  // < H*S*DH
  const int d = e & 63;
  const int s = (e >> 6) & 2047;
  const int h = e >> 17;
  const double rv = (double)rsrc[e];
  const double dp = dgp[h * kS + s];
  const float*  Us = &Ubuf[((size_t)(h * kS) + s) * kR];
  const double* uh = &utr[(size_t)h * kR * kDH];
  double sum = 0.0;
#pragma unroll
  for (int ri = 0; ri < kR; ri++) sum += (double)Us[ri] * uh[ri * kDH + d];
  const double p = rv * dp + sum;
  const double an = (first ? 0.0 : (double)alpha[e]) + p;
  alpha[e] = (float)an;
}

extern "C" void kernel_launch(void* const* d_in, const int* in_sizes, int n_in,
                              void* d_out, int out_size, void* d_ws, size_t ws_size,
                              hipStream_t stream) {
  (void)in_sizes; (void)n_in; (void)out_size;
  const float* x    = (const float*)d_in[0];
  const float* Wq   = (const float*)d_in[1];
  const float* Wk   = (const float*)d_in[2];
  const float* Wv   = (const float*)d_in[3];
  const float* Wo   = (const float*)d_in[4];
  const float* bw   = (const float*)d_in[5];
  const float* dsc  = (const float*)d_in[6];
  const float* pe   = (const float*)d_in[7];
  const float* hp   = (const float*)d_in[8];
  const float* reg  = (const float*)d_in[9];
  const float* lreg = (const float*)d_in[10];
  float* out = (float*)d_out;

  char* w = (char*)d_ws;
  size_t off = 0;
  auto take = [&](size_t bytes) -> void* {
    void* p = w + off;
    off += (bytes + 255) & ~(size_t)255;
    return p;
  };
  const size_t HSD = (size_t)kH * kS * kDH;  // 2M elements
  float*  q     = (float*)take(HSD * 4);
  float*  k     = (float*)take(HSD * 4);
  float*  v     = (float*)take(HSD * 4);
  float*  alpha = (float*)take(HSD * 4);
  float*  rbuf  = (float*)take(HSD * 4);
  float*  tmp   = (float*)take((size_t)kS * kD * 4);
  double* qn    = (double*)take((size_t)kH * kS * 8);
  double* kn    = (double*)take((size_t)kH * kS * 8);
  double* dgp   = (double*)take((size_t)kH * kS * 8);
  float*  U     = (float*)take((size_t)kH * kS * kR * 4);
  double* utr   = (double*)take((size_t)kH * kR * kDH * 8);
  double* utrp  = (double*)take((size_t)kH * 16 * kR * kDH * 8);
  double* SC    = (double*)take(256);
  const size_t need_base = off;
  float*  Km    = (float*)(w + off);
  const size_t need_full = off + (size_t)kH * kS * kS * 4;  // + 268 MB
  const bool materialize = (ws_size >= need_full) && (need_base <= ws_size);

  kar_scalars_kernel<<<1, 64, 0, stream>>>(bw, lreg, SC);
  kar_gemm_qkv_kernel<<<dim3(16, 32, 3), 256, 0, stream>>>(x, Wq, Wk, Wv, q, k, v);
  kar_norms_kernel<<<256, 256, 0, stream>>>(q, k, qn, kn);
  kar_u_kernel<<<2048, 256, 0, stream>>>(pe, hp, U);
  kar_diagp_kernel<<<128, 256, 0, stream>>>(q, k, qn, kn, SC, dsc, reg, dgp);
  if (materialize)
    kar_buildK_kernel<<<dim3(32, 32, kH), 256, 0, stream>>>(q, k, qn, kn, SC, Km);

  // Iteration 0: alpha == 0 exactly -> r == v (K@0 and lam*0 are exactly 0). Skip the GEMM.
  kar_utr_partial_kernel<<<dim3(16, kH), 256, 0, stream>>>(U, v, utrp);
  kar_utr_reduce_kernel<<<64, 256, 0, stream>>>(utrp, utr);
  kar_update_kernel<<<8192, 256, 0, stream>>>(v, dgp, U, utr, alpha, 1);

  for (int it = 1; it < 5; it++) {
    if (materialize)
      kar_iterk_kernel<false><<<dim3(32, kH), 256, 0, stream>>>(Km, alpha, v, SC, rbuf);
    else
      kar_fused_iterk_kernel<false><<<dim3(32, kH), 256, 0, stream>>>(q, k, alpha, v, qn, kn, SC, rbuf);
    kar_utr_partial_kernel<<<dim3(16, kH), 256, 0, stream>>>(U, rbuf, utrp);
    kar_utr_reduce_kernel<<<64, 256, 0, stream>>>(utrp, utr);
    kar_update_kernel<<<8192, 256, 0, stream>>>(rbuf, dgp, U, utr, alpha, 0);
  }

  if (materialize)
    kar_iterk_kernel<true><<<dim3(32, kH), 256, 0, stream>>>(Km, alpha, v, SC, tmp);
  else
    kar_fused_iterk_kernel<true><<<dim3(32, kH), 256, 0, stream>>>(q, k, alpha, v, qn, kn, SC, tmp);
  kar_gemm_plain_kernel<<<dim3(16, 32), 256, 0, stream>>>(tmp, Wo, out);
}

// Round 3
// 2360.134 us; speedup vs baseline: 1.0349x; 1.0349x over previous
//
#include <hip/hip_runtime.h>
#include <cstdint>
#include <cstddef>

constexpr int kS  = 2048;
constexpr int kD  = 1024;
constexpr int kH  = 16;
constexpr int kDH = 64;
constexpr int kR  = 16;

// fast exp(t) for t<=0, fp64 arg, ~1e-8 rel error (fp32-accurate result).
// Cody-Waite reduction in fp64 (single full-precision ln2: residual err n*2.3e-17,
// |n|<=145 -> 3.4e-15, negligible), degree-7 Taylor on r in [-0.3466,0.3466]
// (trunc err ~7e-9 rel), scale by 2^n via exponent bits.
__device__ __forceinline__ float kar_fast_expneg(double t) {
  if (t < -100.0) return 0.0f;  // exp(-100)=3.7e-44 ~ flushes to (sub)zero in fp32
  double n = rint(t * 1.4426950408889634);
  double r = fma(n, -0.6931471805599453, t);
  double p = 1.9841269841269841e-04;       // 1/5040
  p = fma(p, r, 1.3888888888888889e-03);   // 1/720
  p = fma(p, r, 8.3333333333333333e-03);   // 1/120
  p = fma(p, r, 4.1666666666666664e-02);   // 1/24
  p = fma(p, r, 1.6666666666666666e-01);   // 1/6
  p = fma(p, r, 5.0e-01);
  p = fma(p, r, 1.0);
  p = fma(p, r, 1.0);
  long long ni = (long long)n;             // n in [-145, 0]
  double sc = __longlong_as_double((unsigned long long)(ni + 1023) << 52);
  return (float)(p * sc);
}

// ---------------- scalars: inv(2*bw^2), lam (fp64) ----------------
__global__ __launch_bounds__(64) void kar_scalars_kernel(const float* __restrict__ bw,
                                                         const float* __restrict__ lreg,
                                                         double* __restrict__ SC) {
  if (threadIdx.x == 0) {
    double b = log1p(exp((double)bw[0])) + 1e-6;   // softplus + EPS
    SC[0] = 1.0 / (2.0 * b * b);
    SC[1] = log1p(exp((double)lreg[0]));           // lam
  }
}

// ---------------- QKV projection: (2048x1024)x(1024x1024), head-layout out ----------------
__global__ __launch_bounds__(256) void kar_gemm_qkv_kernel(
    const float* __restrict__ x,
    const float* __restrict__ Wq, const float* __restrict__ Wk, const float* __restrict__ Wv,
    float* __restrict__ q, float* __restrict__ k, float* __restrict__ v) {
  const float* W = (blockIdx.z == 0) ? Wq : (blockIdx.z == 1) ? Wk : Wv;
  float* outp    = (blockIdx.z == 0) ? q  : (blockIdx.z == 1) ? k  : v;
  const int n0 = blockIdx.x * 64;
  const int m0 = blockIdx.y * 64;
  const int tid = threadIdx.x;
  const int tx = tid & 15, ty = tid >> 4;
  __shared__ float As[16][68];
  __shared__ float Bs[16][68];
  double acc[4][4] = {};
  const int lr = tid >> 2;
  const int lk = (tid & 3) * 4;
  const int br = tid >> 4;
  const int bc = (tid & 15) * 4;
  for (int k0 = 0; k0 < kD; k0 += 16) {
    const float4 a4 = *(const float4*)&x[(size_t)(m0 + lr) * kD + k0 + lk];
    const float4 b4 = *(const float4*)&W[(size_t)(k0 + br) * kD + n0 + bc];
    __syncthreads();
    As[lk + 0][lr] = a4.x; As[lk + 1][lr] = a4.y;
    As[lk + 2][lr] = a4.z; As[lk + 3][lr] = a4.w;
    *(float4*)&Bs[br][bc] = b4;
    __syncthreads();
    float c32[4][4] = {};
#pragma unroll
    for (int kk = 0; kk < 16; kk++) {
      const float4 av = *(const float4*)&As[kk][ty * 4];
      const float4 bv = *(const float4*)&Bs[kk][tx * 4];
      const float a_[4] = {av.x, av.y, av.z, av.w};
      const float b_[4] = {bv.x, bv.y, bv.z, bv.w};
#pragma unroll
      for (int i = 0; i < 4; i++)
#pragma unroll
        for (int j = 0; j < 4; j++) c32[i][j] = fmaf(a_[i], b_[j], c32[i][j]);
    }
#pragma unroll
    for (int i = 0; i < 4; i++)
#pragma unroll
      for (int j = 0; j < 4; j++) acc[i][j] += (double)c32[i][j];
  }
  const int h = n0 >> 6;  // 64-wide tile == one head
#pragma unroll
  for (int i = 0; i < 4; i++) {
    const int s = m0 + ty * 4 + i;
    float4 o;
    o.x = (float)acc[i][0]; o.y = (float)acc[i][1];
    o.z = (float)acc[i][2]; o.w = (float)acc[i][3];
    *(float4*)&outp[((size_t)h * kS + s) * kDH + tx * 4] = o;
  }
}

// ---------------- final GEMM: out = tmp @ Wo (plain layout) ----------------
__global__ __launch_bounds__(256) void kar_gemm_plain_kernel(
    const float* __restrict__ A, const float* __restrict__ W, float* __restrict__ C) {
  const int n0 = blockIdx.x * 64;
  const int m0 = blockIdx.y * 64;
  const int tid = threadIdx.x;
  const int tx = tid & 15, ty = tid >> 4;
  __shared__ float As[16][68];
  __shared__ float Bs[16][68];
  double acc[4][4] = {};
  const int lr = tid >> 2;
  const int lk = (tid & 3) * 4;
  const int br = tid >> 4;
  const int bc = (tid & 15) * 4;
  for (int k0 = 0; k0 < kD; k0 += 16) {
    const float4 a4 = *(const float4*)&A[(size_t)(m0 + lr) * kD + k0 + lk];
    const float4 b4 = *(const float4*)&W[(size_t)(k0 + br) * kD + n0 + bc];
    __syncthreads();
    As[lk + 0][lr] = a4.x; As[lk + 1][lr] = a4.y;
    As[lk + 2][lr] = a4.z; As[lk + 3][lr] = a4.w;
    *(float4*)&Bs[br][bc] = b4;
    __syncthreads();
    float c32[4][4] = {};
#pragma unroll
    for (int kk = 0; kk < 16; kk++) {
      const float4 av = *(const float4*)&As[kk][ty * 4];
      const float4 bv = *(const float4*)&Bs[kk][tx * 4];
      const float a_[4] = {av.x, av.y, av.z, av.w};
      const float b_[4] = {bv.x, bv.y, bv.z, bv.w};
#pragma unroll
      for (int i = 0; i < 4; i++)
#pragma unroll
        for (int j = 0; j < 4; j++) c32[i][j] = fmaf(a_[i], b_[j], c32[i][j]);
    }
#pragma unroll
    for (int i = 0; i < 4; i++)
#pragma unroll
      for (int j = 0; j < 4; j++) acc[i][j] += (double)c32[i][j];
  }
#pragma unroll
  for (int i = 0; i < 4; i++) {
    const int s = m0 + ty * 4 + i;
    float4 o;
    o.x = (float)acc[i][0]; o.y = (float)acc[i][1];
    o.z = (float)acc[i][2]; o.w = (float)acc[i][3];
    *(float4*)&C[(size_t)s * kD + n0 + tx * 4] = o;
  }
}

// ---------------- norms: qn/kn[h][s] = ||.||^2 (fp64) ----------------
__global__ __launch_bounds__(256) void kar_norms_kernel(const float* __restrict__ q,
                                                        const float* __restrict__ k,
                                                        double* __restrict__ qn,
                                                        double* __restrict__ kn) {
  int o = blockIdx.x * 256 + threadIdx.x;  // 0 .. 2*H*S-1
  const float* src; double* dst; int p;
  if (o < kH * kS) { src = q; dst = qn; p = o; }
  else             { src = k; dst = kn; p = o - kH * kS; }
  const float* row = src + (size_t)p * kDH;
  double s = 0.0;
  for (int i = 0; i < kDH; i += 4) {
    float4 x4 = *(const float4*)&row[i];
    s += (double)x4.x * (double)x4.x + (double)x4.y * (double)x4.y +
         (double)x4.z * (double)x4.z + (double)x4.w * (double)x4.w;
  }
  dst[p] = s;
}

// ---------------- U[h][s][p] = sum_r pe[s][r] * hp[h][r][p] ----------------
__global__ __launch_bounds__(256) void kar_u_kernel(const float* __restrict__ pe,
                                                    const float* __restrict__ hp,
                                                    float* __restrict__ U) {
  int o = blockIdx.x * 256 + threadIdx.x;  // < H*S*R
  int r = o & 15, s = (o >> 4) & 2047, h = o >> 15;
  double acc = 0.0;
#pragma unroll
  for (int rp = 0; rp < kR; rp++)
    acc += (double)pe[s * kR + rp] * (double)hp[((h * kR) + rp) * kR + r];
  U[o] = (float)acc;
}

// ---------------- K[h][s][t] = exp(-max(||q||^2+||k||^2-2 q.k,0) * inv2bw2) ----------------
// Only launched for heads [0, gridDim.z)
__global__ __launch_bounds__(256) void kar_buildK_kernel(
    const float* __restrict__ q, const float* __restrict__ k,
    const double* __restrict__ qn, const double* __restrict__ kn,
    const double* __restrict__ SC, float* __restrict__ Kmat) {
  const int h  = blockIdx.z;
  const int t0 = blockIdx.x * 64;
  const int s0 = blockIdx.y * 64;
  const int tid = threadIdx.x;
  const int tx = tid & 15, ty = tid >> 4;
  __shared__ float Qs[64][68];   // [dh][s_local]
  __shared__ float Ks_[64][68];  // [dh][t_local]
  __shared__ double qns[64], kns[64];
  const float* qh = q + (size_t)h * kS * kDH;
  const float* kh = k + (size_t)h * kS * kDH;
#pragma unroll
  for (int rep = 0; rep < 4; rep++) {
    const int row = rep * 16 + (tid >> 4);
    const int c = (tid & 15) * 4;
    const float4 a = *(const float4*)&qh[(size_t)(s0 + row) * kDH + c];
    Qs[c + 0][row] = a.x; Qs[c + 1][row] = a.y; Qs[c + 2][row] = a.z; Qs[c + 3][row] = a.w;
    const float4 b = *(const float4*)&kh[(size_t)(t0 + row) * kDH + c];
    Ks_[c + 0][row] = b.x; Ks_[c + 1][row] = b.y; Ks_[c + 2][row] = b.z; Ks_[c + 3][row] = b.w;
  }
  if (tid < 64)                       qns[tid] = qn[h * kS + s0 + tid];
  else if (tid < 128)                 kns[tid - 64] = kn[h * kS + t0 + (tid - 64)];
  __syncthreads();
  double dot[4][4] = {};
  for (int kc = 0; kc < kDH; kc += 16) {
    float c32[4][4] = {};
#pragma unroll
    for (int kk = 0; kk < 16; kk++) {
      const float4 av = *(const float4*)&Qs[kc + kk][ty * 4];
      const float4 bv = *(const float4*)&Ks_[kc + kk][tx * 4];
      const float a_[4] = {av.x, av.y, av.z, av.w};
      const float b_[4] = {bv.x, bv.y, bv.z, bv.w};
#pragma unroll
      for (int i = 0; i < 4; i++)
#pragma unroll
        for (int j = 0; j < 4; j++) c32[i][j] = fmaf(a_[i], b_[j], c32[i][j]);
    }
#pragma unroll
    for (int i = 0; i < 4; i++)
#pragma unroll
      for (int j = 0; j < 4; j++) dot[i][j] += (double)c32[i][j];
  }
  const double c = SC[0];
#pragma unroll
  for (int i = 0; i < 4; i++) {
    const int s = s0 + ty * 4 + i;
    float4 o;
    double d0 = fmax(qns[ty * 4 + i] + kns[tx * 4 + 0] - 2.0 * dot[i][0], 0.0);
    double d1 = fmax(qns[ty * 4 + i] + kns[tx * 4 + 1] - 2.0 * dot[i][1], 0.0);
    double d2 = fmax(qns[ty * 4 + i] + kns[tx * 4 + 2] - 2.0 * dot[i][2], 0.0);
    double d3 = fmax(qns[ty * 4 + i] + kns[tx * 4 + 3] - 2.0 * dot[i][3], 0.0);
    o.x = kar_fast_expneg(-d0 * c); o.y = kar_fast_expneg(-d1 * c);
    o.z = kar_fast_expneg(-d2 * c); o.w = kar_fast_expneg(-d3 * c);
    *(float4*)&Kmat[((size_t)(h * kS + s)) * kS + t0 + tx * 4] = o;
  }
}

// ---------------- diag_p[h][s] = softplus(K_ss)*diag_scale[h] + reg (fp64 recompute) ----------------
__global__ __launch_bounds__(256) void kar_diagp_kernel(
    const float* __restrict__ q, const float* __restrict__ k,
    const double* __restrict__ qn, const double* __restrict__ kn,
    const double* __restrict__ SC, const float* __restrict__ dsc,
    const float* __restrict__ reg, double* __restrict__ dgp) {
  int o = blockIdx.x * 256 + threadIdx.x;  // < H*S
  int h = o >> 11;
  const float* qp = q + (size_t)o * kDH;
  const float* kp = k + (size_t)o * kDH;
  double dot = 0.0;
  for (int i = 0; i < kDH; i++) dot += (double)qp[i] * (double)kp[i];
  double dist = fmax(qn[o] + kn[o] - 2.0 * dot, 0.0);
  double Kss = exp(-dist * SC[0]);
  double sp  = log1p(exp(Kss));
  dgp[o] = sp * (double)dsc[h] + (double)reg[0];
}

// ---------------- Path A: per-head K @ alpha from materialized K (heads [0,gridDim.y)) ----------------
template <bool FINAL>
__global__ __launch_bounds__(256) void kar_iterk_kernel(
    const float* __restrict__ Kmat, const float* __restrict__ alpha,
    const float* __restrict__ v, const double* __restrict__ SC,
    float* __restrict__ outp) {
  const int h  = blockIdx.y;
  const int s0 = blockIdx.x * 64;
  const float* Kh = Kmat + (size_t)h * kS * kS;
  const float* ah = alpha + (size_t)h * kS * kDH;
  const float* vh = v + (size_t)h * kS * kDH;
  const int tid = threadIdx.x;
  const int tx = tid & 15, ty = tid >> 4;
  __shared__ float Ks_[16][68];
  __shared__ float As_[16][68];
  double acc[4][4] = {};
  const int lr = tid >> 2;
  const int lk = (tid & 3) * 4;
  const int br = tid >> 4;
  const int bc = (tid & 15) * 4;
  for (int t0 = 0; t0 < kS; t0 += 16) {
    const float4 a4 = *(const float4*)&Kh[(size_t)(s0 + lr) * kS + t0 + lk];
    const float4 b4 = *(const float4*)&ah[(size_t)(t0 + br) * kDH + bc];
    __syncthreads();
    Ks_[lk + 0][lr] = a4.x; Ks_[lk + 1][lr] = a4.y;
    Ks_[lk + 2][lr] = a4.z; Ks_[lk + 3][lr] = a4.w;
    *(float4*)&As_[br][bc] = b4;
    __syncthreads();
    float c32[4][4] = {};
#pragma unroll
    for (int kk = 0; kk < 16; kk++) {
      const float4 av = *(const float4*)&Ks_[kk][ty * 4];
      const float4 bv = *(const float4*)&As_[kk][tx * 4];
      const float a_[4] = {av.x, av.y, av.z, av.w};
      const float b_[4] = {bv.x, bv.y, bv.z, bv.w};
#pragma unroll
      for (int i = 0; i < 4; i++)
#pragma unroll
        for (int j = 0; j < 4; j++) c32[i][j] = fmaf(a_[i], b_[j], c32[i][j]);
    }
#pragma unroll
    for (int i = 0; i < 4; i++)
#pragma unroll
      for (int j = 0; j < 4; j++) acc[i][j] += (double)c32[i][j];
  }
  if (FINAL) {
#pragma unroll
    for (int i = 0; i < 4; i++) {
      const int s = s0 + ty * 4 + i;
      float4 o;
      o.x = (float)acc[i][0]; o.y = (float)acc[i][1];
      o.z = (float)acc[i][2]; o.w = (float)acc[i][3];
      *(float4*)&outp[(size_t)s * kD + h * kDH + tx * 4] = o;  // (s, h*64+dh)
    }
  } else {
    const double lam = SC[1];
#pragma unroll
    for (int i = 0; i < 4; i++) {
      const int s = s0 + ty * 4 + i;
      const float4 vv = *(const float4*)&vh[(size_t)s * kDH + tx * 4];
      const float4 aa = *(const float4*)&ah[(size_t)s * kDH + tx * 4];
      float4 o;
      o.x = (float)((double)vv.x - (acc[i][0] + lam * (double)aa.x));
      o.y = (float)((double)vv.y - (acc[i][1] + lam * (double)aa.y));
      o.z = (float)((double)vv.z - (acc[i][2] + lam * (double)aa.z));
      o.w = (float)((double)vv.w - (acc[i][3] + lam * (double)aa.w));
      *(float4*)&outp[((size_t)h * kS + s) * kDH + tx * 4] = o;
    }
  }
}

// ---------------- Path B (direct, zero extra ws): fused on-the-fly K tile * alpha ----------------
template <bool FINAL>
__global__ __launch_bounds__(256) void kar_fused_direct_kernel(
    const float* __restrict__ q, const float* __restrict__ k,
    const float* __restrict__ alpha, const float* __restrict__ v,
    const double* __restrict__ qn, const double* __restrict__ kn,
    const double* __restrict__ SC, float* __restrict__ outp) {
  const int h  = blockIdx.y;
  const int s0 = blockIdx.x * 64;
  const int tid = threadIdx.x;
  const int tx = tid & 15, ty = tid >> 4;
  __shared__ float Qs[64][68];
  __shared__ float Ks_[64][68];
  __shared__ float As_[64][68];
  __shared__ double qns[64], kns[64];
  const float* qh = q + (size_t)h * kS * kDH;
  const float* kh = k + (size_t)h * kS * kDH;
  const float* ah = alpha + (size_t)h * kS * kDH;
  const float* vh = v + (size_t)h * kS * kDH;
  {
    const int row = (tid >> 4);
    const int c = (tid & 15) * 4;
#pragma unroll
    for (int rep = 0; rep < 4; rep++) {
      const int rr = rep * 16 + row;
      const float4 a = *(const float4*)&qh[(size_t)(s0 + rr) * kDH + c];
      Qs[c + 0][rr] = a.x; Qs[c + 1][rr] = a.y; Qs[c + 2][rr] = a.z; Qs[c + 3][rr] = a.w;
    }
    if (tid < 64) qns[tid] = qn[h * kS + s0 + tid];
  }
  const double cc = SC[0];
  double acc[4][4] = {};
  for (int t0 = 0; t0 < kS; t0 += 64) {
    __syncthreads();
    {
      const int row = (tid >> 4);
      const int c = (tid & 15) * 4;
#pragma unroll
      for (int rep = 0; rep < 4; rep++) {
        const int rr = rep * 16 + row;
        const float4 b = *(const float4*)&kh[(size_t)(t0 + rr) * kDH + c];
        Ks_[c + 0][rr] = b.x; Ks_[c + 1][rr] = b.y; Ks_[c + 2][rr] = b.z; Ks_[c + 3][rr] = b.w;
        *(float4*)&As_[rr][c] = *(const float4*)&ah[(size_t)(t0 + rr) * kDH + c];
      }
      if (tid < 64) kns[tid] = kn[h * kS + t0 + tid];
    }
    __syncthreads();
    double dot[4][4] = {};
    for (int kc = 0; kc < kDH; kc += 16) {
      float c32[4][4] = {};
#pragma unroll
      for (int kk = 0; kk < 16; kk++) {
        const float4 av = *(const float4*)&Qs[kc + kk][ty * 4];
        const float4 bv = *(const float4*)&Ks_[kc + kk][tx * 4];
        const float a_[4] = {av.x, av.y, av.z, av.w};
        const float b_[4] = {bv.x, bv.y, bv.z, bv.w};
#pragma unroll
        for (int i = 0; i < 4; i++)
#pragma unroll
          for (int j = 0; j < 4; j++) c32[i][j] = fmaf(a_[i], b_[j], c32[i][j]);
      }
#pragma unroll
      for (int i = 0; i < 4; i++)
#pragma unroll
        for (int j = 0; j < 4; j++) dot[i][j] += (double)c32[i][j];
    }
    float Kv[4][4];
#pragma unroll
    for (int i = 0; i < 4; i++)
#pragma unroll
      for (int j = 0; j < 4; j++) {
        double d = fmax(qns[ty * 4 + i] + kns[tx * 4 + j] - 2.0 * dot[i][j], 0.0);
        Kv[i][j] = kar_fast_expneg(-d * cc);
      }
    __syncthreads();
#pragma unroll
    for (int i = 0; i < 4; i++)
#pragma unroll
      for (int j = 0; j < 4; j++) Ks_[tx * 4 + j][ty * 4 + i] = Kv[i][j];
    __syncthreads();
    for (int kc = 0; kc < 64; kc += 16) {
      float c32[4][4] = {};
#pragma unroll
      for (int kk = 0; kk < 16; kk++) {
        const float4 av = *(const float4*)&Ks_[kc + kk][ty * 4];
        const float4 bv = *(const float4*)&As_[kc + kk][tx * 4];
        const float a_[4] = {av.x, av.y, av.z, av.w};
        const float b_[4] = {bv.x, bv.y, bv.z, bv.w};
#pragma unroll
        for (int i = 0; i < 4; i++)
#pragma unroll
          for (int j = 0; j < 4; j++) c32[i][j] = fmaf(a_[i], b_[j], c32[i][j]);
      }
#pragma unroll
      for (int i = 0; i < 4; i++)
#pragma unroll
        for (int j = 0; j < 4; j++) acc[i][j] += (double)c32[i][j];
    }
  }
  if (FINAL) {
#pragma unroll
    for (int i = 0; i < 4; i++) {
      const int s = s0 + ty * 4 + i;
      float4 o;
      o.x = (float)acc[i][0]; o.y = (float)acc[i][1];
      o.z = (float)acc[i][2]; o.w = (float)acc[i][3];
      *(float4*)&outp[(size_t)s * kD + h * kDH + tx * 4] = o;
    }
  } else {
    const double lam = SC[1];
#pragma unroll
    for (int i = 0; i < 4; i++) {
      const int s = s0 + ty * 4 + i;
      const float4 vv = *(const float4*)&vh[(size_t)s * kDH + tx * 4];
      const float4 aa = *(const float4*)&ah[(size_t)s * kDH + tx * 4];
      float4 o;
      o.x = (float)((double)vv.x - (acc[i][0] + lam * (double)aa.x));
      o.y = (float)((double)vv.y - (acc[i][1] + lam * (double)aa.y));
      o.z = (float)((double)vv.z - (acc[i][2] + lam * (double)aa.z));
      o.w = (float)((double)vv.w - (acc[i][3] + lam * (double)aa.w));
      *(float4*)&outp[((size_t)h * kS + s) * kDH + tx * 4] = o;
    }
  }
}

// ---------------- Path B (t-split): fused partial K@alpha -> fp64 partials ----------------
// grid (32, hf, tsplit); head = h0 + blockIdx.y; t-range = [blockIdx.z*tlen, +tlen)
__global__ __launch_bounds__(256) void kar_fused_part_kernel(
    const float* __restrict__ q, const float* __restrict__ k,
    const float* __restrict__ alpha,
    const double* __restrict__ qn, const double* __restrict__ kn,
    const double* __restrict__ SC, double* __restrict__ partial,
    int h0, int tlen) {
  const int h  = h0 + blockIdx.y;
  const int s0 = blockIdx.x * 64;
  const int tbeg = blockIdx.z * tlen;
  const int tid = threadIdx.x;
  const int tx = tid & 15, ty = tid >> 4;
  __shared__ float Qs[64][68];
  __shared__ float Ks_[64][68];
  __shared__ float As_[64][68];
  __shared__ double qns[64], kns[64];
  const float* qh = q + (size_t)h * kS * kDH;
  const float* kh = k + (size_t)h * kS * kDH;
  const float* ah = alpha + (size_t)h * kS * kDH;
  {
    const int row = (tid >> 4);
    const int c = (tid & 15) * 4;
#pragma unroll
    for (int rep = 0; rep < 4; rep++) {
      const int rr = rep * 16 + row;
      const float4 a = *(const float4*)&qh[(size_t)(s0 + rr) * kDH + c];
      Qs[c + 0][rr] = a.x; Qs[c + 1][rr] = a.y; Qs[c + 2][rr] = a.z; Qs[c + 3][rr] = a.w;
    }
    if (tid < 64) qns[tid] = qn[h * kS + s0 + tid];
  }
  const double cc = SC[0];
  double acc[4][4] = {};
  for (int t0 = tbeg; t0 < tbeg + tlen; t0 += 64) {
    __syncthreads();
    {
      const int row = (tid >> 4);
      const int c = (tid & 15) * 4;
#pragma unroll
      for (int rep = 0; rep < 4; rep++) {
        const int rr = rep * 16 + row;
        const float4 b = *(const float4*)&kh[(size_t)(t0 + rr) * kDH + c];
        Ks_[c + 0][rr] = b.x; Ks_[c + 1][rr] = b.y; Ks_[c + 2][rr] = b.z; Ks_[c + 3][rr] = b.w;
        *(float4*)&As_[rr][c] = *(const float4*)&ah[(size_t)(t0 + rr) * kDH + c];
      }
      if (tid < 64) kns[tid] = kn[h * kS + t0 + tid];
    }
    __syncthreads();
    double dot[4][4] = {};
    for (int kc = 0; kc < kDH; kc += 16) {
      float c32[4][4] = {};
#pragma unroll
      for (int kk = 0; kk < 16; kk++) {
        const float4 av = *(const float4*)&Qs[kc + kk][ty * 4];
        const float4 bv = *(const float4*)&Ks_[kc + kk][tx * 4];
        const float a_[4] = {av.x, av.y, av.z, av.w};
        const float b_[4] = {bv.x, bv.y, bv.z, bv.w};
#pragma unroll
        for (int i = 0; i < 4; i++)
#pragma unroll
          for (int j = 0; j < 4; j++) c32[i][j] = fmaf(a_[i], b_[j], c32[i][j]);
      }
#pragma unroll
      for (int i = 0; i < 4; i++)
#pragma unroll
        for (int j = 0; j < 4; j++) dot[i][j] += (double)c32[i][j];
    }
    float Kv[4][4];
#pragma unroll
    for (int i = 0; i < 4; i++)
#pragma unroll
      for (int j = 0; j < 4; j++) {
        double d = fmax(qns[ty * 4 + i] + kns[tx * 4 + j] - 2.0 * dot[i][j], 0.0);
        Kv[i][j] = kar_fast_expneg(-d * cc);
      }
    __syncthreads();
#pragma unroll
    for (int i = 0; i < 4; i++)
#pragma unroll
      for (int j = 0; j < 4; j++) Ks_[tx * 4 + j][ty * 4 + i] = Kv[i][j];
    __syncthreads();
    for (int kc = 0; kc < 64; kc += 16) {
      float c32[4][4] = {};
#pragma unroll
      for (int kk = 0; kk < 16; kk++) {
        const float4 av = *(const float4*)&Ks_[kc + kk][ty * 4];
        const float4 bv = *(const float4*)&As_[kc + kk][tx * 4];
        const float a_[4] = {av.x, av.y, av.z, av.w};
        const float b_[4] = {bv.x, bv.y, bv.z, bv.w};
#pragma unroll
        for (int i = 0; i < 4; i++)
#pragma unroll
          for (int j = 0; j < 4; j++) c32[i][j] = fmaf(a_[i], b_[j], c32[i][j]);
      }
#pragma unroll
      for (int i = 0; i < 4; i++)
#pragma unroll
        for (int j = 0; j < 4; j++) acc[i][j] += (double)c32[i][j];
    }
  }
  const size_t slot = (size_t)blockIdx.y * gridDim.z + blockIdx.z;
#pragma unroll
  for (int i = 0; i < 4; i++) {
    const int s = s0 + ty * 4 + i;
    double* dst = &partial[((slot * kS) + s) * kDH + tx * 4];
    double2 p0; p0.x = acc[i][0]; p0.y = acc[i][1];
    double2 p1; p1.x = acc[i][2]; p1.y = acc[i][3];
    *(double2*)&dst[0] = p0;
    *(double2*)&dst[2] = p1;
  }
}

// ---------------- combine fp64 partials -> r (or tmp for FINAL) for fused heads ----------------
template <bool FINAL>
__global__ __launch_bounds__(256) void kar_combine_kernel(
    const double* __restrict__ partial, const float* __restrict__ alpha,
    const float* __restrict__ v, const double* __restrict__ SC,
    float* __restrict__ outp, int h0, int tsplit) {
  int e = blockIdx.x * 256 + threadIdx.x;   // < hf * kS * kDH
  const int low = e & 131071;               // s*64 + d
  const int f = e >> 17;
  double sum = 0.0;
  for (int tz = 0; tz < tsplit; tz++)
    sum += partial[((size_t)(f * tsplit + tz) << 17) + low];
  const int h = h0 + f;
  const int d = low & 63;
  const int s = low >> 6;
  const size_t eg = ((size_t)h * kS + s) * kDH + d;
  if (FINAL) {
    outp[(size_t)s * kD + h * kDH + d] = (float)sum;
  } else {
    const double lam = SC[1];
    outp[eg] = (float)((double)v[eg] - (sum + lam * (double)alpha[eg]));
  }
}

// ---------------- ut_r partials ----------------
__global__ __launch_bounds__(256) void kar_utr_partial_kernel(
    const float* __restrict__ Ubuf, const float* __restrict__ rbuf,
    double* __restrict__ utrp) {
  const int h  = blockIdx.y;
  const int sb = blockIdx.x * 128;
  const int t  = threadIdx.x;
  __shared__ float Uch[32][16];
  __shared__ float Rch[32][64];
  double acc[4] = {};
  for (int cs = 0; cs < 128; cs += 32) {
    __syncthreads();
    if (t < 128) {
      const int i = t >> 2, f = (t & 3) * 4;
      *(float4*)&Uch[i][f] = *(const float4*)&Ubuf[((size_t)(h * kS) + sb + cs + i) * kR + f];
    }
#pragma unroll
    for (int rep = 0; rep < 2; rep++) {
      const int e = t + rep * 256;
      const int i = e >> 4, c = (e & 15) * 4;
      *(float4*)&Rch[i][c] = *(const float4*)&rbuf[((size_t)(h * kS) + sb + cs + i) * kDH + c];
    }
    __syncthreads();
    for (int i = 0; i < 32; i++) {
#pragma unroll
      for (int rep = 0; rep < 4; rep++) {
        const int p = t + rep * 256;
        const int r = p >> 6, d = p & 63;
        acc[rep] += (double)Uch[i][r] * (double)Rch[i][d];
      }
    }
  }
#pragma unroll
  for (int rep = 0; rep < 4; rep++) {
    const int p = t + rep * 256;
    const int r = p >> 6, d = p & 63;
    utrp[(((size_t)(h * 16) + blockIdx.x) * kR + r) * kDH + d] = acc[rep];
  }
}

__global__ __launch_bounds__(256) void kar_utr_reduce_kernel(const double* __restrict__ utrp,
                                                             double* __restrict__ utr) {
  int o = blockIdx.x * 256 + threadIdx.x;  // < H*R*DH
  int h = o >> 10, rd = o & 1023;
  double s = 0.0;
#pragma unroll
  for (int j = 0; j < 16; j++) s += utrp[(size_t)h * 16384 + (size_t)j * 1024 + rd];
  utr[o] = s;
}

// ---------------- alpha (+)= r*diag_p + U @ utr ----------------
__global__ __launch_bounds__(256) void kar_update_kernel(
    const float* __restrict__ rsrc, const double* __restrict__ dgp,
    const float* __restrict__ Ubuf, const double* __restrict__ utr,
    float* __restrict__ alpha, int first) {
  int e = blockIdx.x * 256 + threadIdx.x;  // < H*S*DH
  const int d = e & 63;
  const int s = (e >> 6) & 2047;
  const int h = e >> 17;
  const double rv = (double)rsrc[e];
  const double dp = dgp[h * kS + s];
  const float*  Us = &Ubuf[((size_t)(h * kS) + s) * kR];
  const double* uh = &utr[(size_t)h * kR * kDH];
  double sum = 0.0;
#pragma unroll
  for (int ri = 0; ri < kR; ri++) sum += (double)Us[ri] * uh[ri * kDH + d];
  const double p = rv * dp + sum;
  const double an = (first ? 0.0 : (double)alpha[e]) + p;
  alpha[e] = (float)an;
}

extern "C" void kernel_launch(void* const* d_in, const int* in_sizes, int n_in,
                              void* d_out, int out_size, void* d_ws, size_t ws_size,
                              hipStream_t stream) {
  (void)in_sizes; (void)n_in; (void)out_size;
  const float* x    = (const float*)d_in[0];
  const float* Wq   = (const float*)d_in[1];
  const float* Wk   = (const float*)d_in[2];
  const float* Wv   = (const float*)d_in[3];
  const float* Wo   = (const float*)d_in[4];
  const float* bw   = (const float*)d_in[5];
  const float* dsc  = (const float*)d_in[6];
  const float* pe   = (const float*)d_in[7];
  const float* hp   = (const float*)d_in[8];
  const float* reg  = (const float*)d_in[9];
  const float* lreg = (const float*)d_in[10];
  float* out = (float*)d_out;

  char* w = (char*)d_ws;
  size_t off = 0;
  auto take = [&](size_t bytes) -> void* {
    void* p = w + off;
    off += (bytes + 255) & ~(size_t)255;
    return p;
  };
  const size_t HSD = (size_t)kH * kS * kDH;  // 2M elements
  float*  q     = (float*)take(HSD * 4);
  float*  k     = (float*)take(HSD * 4);
  float*  v     = (float*)take(HSD * 4);
  float*  alpha = (float*)take(HSD * 4);
  float*  rbuf  = (float*)take(HSD * 4);
  float*  tmp   = (float*)take((size_t)kS * kD * 4);
  double* qn    = (double*)take((size_t)kH * kS * 8);
  double* kn    = (double*)take((size_t)kH * kS * 8);
  double* dgp   = (double*)take((size_t)kH * kS * 8);
  float*  U     = (float*)take((size_t)kH * kS * kR * 4);
  double* utr   = (double*)take((size_t)kH * kR * kDH * 8);
  double* utrp  = (double*)take((size_t)kH * 16 * kR * kDH * 8);
  double* SC    = (double*)take(256);
  const size_t base = off;

  // ---- adaptive split: materialize as many heads of K as ws_size allows ----
  const size_t headK = (size_t)kS * kS * 4;  // 16.78 MB per head
  const size_t avail = (ws_size > base) ? (ws_size - base) : 0;
  int heads_mat = 0, tsplit = 0;
  size_t km_off = base;
  if (avail >= (size_t)kH * headK) {
    heads_mat = kH; tsplit = 0;
  } else {
    bool found = false;
    for (int hm = kH - 1; hm >= 0 && !found; hm--) {
      const int hfc = kH - hm;
      const int ts = (hfc >= 16) ? 2 : (hfc >= 8) ? 4 : 8;
      const size_t reserve = (size_t)hfc * ts * kS * kDH * 8;  // fp64 partials
      if (avail >= reserve + (size_t)hm * headK) {
        heads_mat = hm; tsplit = ts; km_off = base + reserve; found = true;
      }
    }
    if (!found) { heads_mat = 0; tsplit = 0; }  // direct fused fallback (zero extra ws)
  }
  double* partial = (double*)(w + base);
  float*  Km      = (float*)(w + km_off);
  const int hf   = kH - heads_mat;
  const int tlen = tsplit ? (kS / tsplit) : kS;

  kar_scalars_kernel<<<1, 64, 0, stream>>>(bw, lreg, SC);
  kar_gemm_qkv_kernel<<<dim3(16, 32, 3), 256, 0, stream>>>(x, Wq, Wk, Wv, q, k, v);
  kar_norms_kernel<<<256, 256, 0, stream>>>(q, k, qn, kn);
  kar_u_kernel<<<2048, 256, 0, stream>>>(pe, hp, U);
  kar_diagp_kernel<<<128, 256, 0, stream>>>(q, k, qn, kn, SC, dsc, reg, dgp);
  if (heads_mat > 0)
    kar_buildK_kernel<<<dim3(32, 32, heads_mat), 256, 0, stream>>>(q, k, qn, kn, SC, Km);

  // Iteration 0: alpha == 0 exactly -> r == v. Skip all K applications.
  kar_utr_partial_kernel<<<dim3(16, kH), 256, 0, stream>>>(U, v, utrp);
  kar_utr_reduce_kernel<<<64, 256, 0, stream>>>(utrp, utr);
  kar_update_kernel<<<8192, 256, 0, stream>>>(v, dgp, U, utr, alpha, 1);

  for (int it = 1; it < 5; it++) {
    if (heads_mat > 0)
      kar_iterk_kernel<false><<<dim3(32, heads_mat), 256, 0, stream>>>(Km, alpha, v, SC, rbuf);
    if (hf > 0) {
      if (tsplit > 0) {
        kar_fused_part_kernel<<<dim3(32, hf, tsplit), 256, 0, stream>>>(
            q, k, alpha, qn, kn, SC, partial, heads_mat, tlen);
        kar_combine_kernel<false><<<hf * 512, 256, 0, stream>>>(
            partial, alpha, v, SC, rbuf, heads_mat, tsplit);
      } else {
        kar_fused_direct_kernel<false><<<dim3(32, kH), 256, 0, stream>>>(
            q, k, alpha, v, qn, kn, SC, rbuf);
      }
    }
    kar_utr_partial_kernel<<<dim3(16, kH), 256, 0, stream>>>(U, rbuf, utrp);
    kar_utr_reduce_kernel<<<64, 256, 0, stream>>>(utrp, utr);
    kar_update_kernel<<<8192, 256, 0, stream>>>(rbuf, dgp, U, utr, alpha, 0);
  }

  if (heads_mat > 0)
    kar_iterk_kernel<true><<<dim3(32, heads_mat), 256, 0, stream>>>(Km, alpha, v, SC, tmp);
  if (hf > 0) {
    if (tsplit > 0) {
      kar_fused_part_kernel<<<dim3(32, hf, tsplit), 256, 0, stream>>>(
          q, k, alpha, qn, kn, SC, partial, heads_mat, tlen);
      kar_combine_kernel<true><<<hf * 512, 256, 0, stream>>>(
          partial, alpha, v, SC, tmp, heads_mat, tsplit);
    } else {
      kar_fused_direct_kernel<true><<<dim3(32, kH), 256, 0, stream>>>(
          q, k, alpha, v, qn, kn, SC, tmp);
    }
  }
  kar_gemm_plain_kernel<<<dim3(16, 32), 256, 0, stream>>>(tmp, Wo, out);
}

// Round 4
// 1261.268 us; speedup vs baseline: 1.9366x; 1.8712x over previous
//
#include <hip/hip_runtime.h>
#include <cstdint>
#include <cstddef>

constexpr int kS  = 2048;
constexpr int kD  = 1024;
constexpr int kH  = 16;
constexpr int kDH = 64;
constexpr int kR  = 16;

typedef __attribute__((ext_vector_type(8))) short bf16x8;
typedef __attribute__((ext_vector_type(4))) float f32x4;

// RNE float -> bf16 bits
__device__ __forceinline__ unsigned short kar_f2bf(float x) {
  unsigned u = __float_as_uint(x);
  return (unsigned short)((u + 0x7FFFu + ((u >> 16) & 1u)) >> 16);
}
// split x ~= hi + lo (bf16 each), residual ~2^-16 |x|
__device__ __forceinline__ void kar_split_bf(float x, short& hi, short& lo) {
  unsigned short h = kar_f2bf(x);
  float hf = __uint_as_float((unsigned)h << 16);
  hi = (short)h;
  lo = (short)kar_f2bf(x - hf);
}

// ---------------- scalars: inv(2*bw^2), lam (fp64) ----------------
__global__ __launch_bounds__(64) void kar_scalars_kernel(const float* __restrict__ bw,
                                                         const float* __restrict__ lreg,
                                                         double* __restrict__ SC) {
  if (threadIdx.x == 0) {
    double b = log1p(exp((double)bw[0])) + 1e-6;   // softplus + EPS
    SC[0] = 1.0 / (2.0 * b * b);
    SC[1] = log1p(exp((double)lreg[0]));           // lam
  }
}

// ---------------- QKV projection: (2048x1024)x(1024x1024), head-layout out ----------------
__global__ __launch_bounds__(256) void kar_gemm_qkv_kernel(
    const float* __restrict__ x,
    const float* __restrict__ Wq, const float* __restrict__ Wk, const float* __restrict__ Wv,
    float* __restrict__ q, float* __restrict__ k, float* __restrict__ v) {
  const float* W = (blockIdx.z == 0) ? Wq : (blockIdx.z == 1) ? Wk : Wv;
  float* outp    = (blockIdx.z == 0) ? q  : (blockIdx.z == 1) ? k  : v;
  const int n0 = blockIdx.x * 64;
  const int m0 = blockIdx.y * 64;
  const int tid = threadIdx.x;
  const int tx = tid & 15, ty = tid >> 4;
  __shared__ float As[16][68];
  __shared__ float Bs[16][68];
  double acc[4][4] = {};
  const int lr = tid >> 2;
  const int lk = (tid & 3) * 4;
  const int br = tid >> 4;
  const int bc = (tid & 15) * 4;
  for (int k0 = 0; k0 < kD; k0 += 16) {
    const float4 a4 = *(const float4*)&x[(size_t)(m0 + lr) * kD + k0 + lk];
    const float4 b4 = *(const float4*)&W[(size_t)(k0 + br) * kD + n0 + bc];
    __syncthreads();
    As[lk + 0][lr] = a4.x; As[lk + 1][lr] = a4.y;
    As[lk + 2][lr] = a4.z; As[lk + 3][lr] = a4.w;
    *(float4*)&Bs[br][bc] = b4;
    __syncthreads();
    float c32[4][4] = {};
#pragma unroll
    for (int kk = 0; kk < 16; kk++) {
      const float4 av = *(const float4*)&As[kk][ty * 4];
      const float4 bv = *(const float4*)&Bs[kk][tx * 4];
      const float a_[4] = {av.x, av.y, av.z, av.w};
      const float b_[4] = {bv.x, bv.y, bv.z, bv.w};
#pragma unroll
      for (int i = 0; i < 4; i++)
#pragma unroll
        for (int j = 0; j < 4; j++) c32[i][j] = fmaf(a_[i], b_[j], c32[i][j]);
    }
#pragma unroll
    for (int i = 0; i < 4; i++)
#pragma unroll
      for (int j = 0; j < 4; j++) acc[i][j] += (double)c32[i][j];
  }
  const int h = n0 >> 6;  // 64-wide tile == one head
#pragma unroll
  for (int i = 0; i < 4; i++) {
    const int s = m0 + ty * 4 + i;
    float4 o;
    o.x = (float)acc[i][0]; o.y = (float)acc[i][1];
    o.z = (float)acc[i][2]; o.w = (float)acc[i][3];
    *(float4*)&outp[((size_t)h * kS + s) * kDH + tx * 4] = o;
  }
}

// ---------------- final GEMM: out = tmp @ Wo (plain layout) ----------------
__global__ __launch_bounds__(256) void kar_gemm_plain_kernel(
    const float* __restrict__ A, const float* __restrict__ W, float* __restrict__ C) {
  const int n0 = blockIdx.x * 64;
  const int m0 = blockIdx.y * 64;
  const int tid = threadIdx.x;
  const int tx = tid & 15, ty = tid >> 4;
  __shared__ float As[16][68];
  __shared__ float Bs[16][68];
  double acc[4][4] = {};
  const int lr = tid >> 2;
  const int lk = (tid & 3) * 4;
  const int br = tid >> 4;
  const int bc = (tid & 15) * 4;
  for (int k0 = 0; k0 < kD; k0 += 16) {
    const float4 a4 = *(const float4*)&A[(size_t)(m0 + lr) * kD + k0 + lk];
    const float4 b4 = *(const float4*)&W[(size_t)(k0 + br) * kD + n0 + bc];
    __syncthreads();
    As[lk + 0][lr] = a4.x; As[lk + 1][lr] = a4.y;
    As[lk + 2][lr] = a4.z; As[lk + 3][lr] = a4.w;
    *(float4*)&Bs[br][bc] = b4;
    __syncthreads();
    float c32[4][4] = {};
#pragma unroll
    for (int kk = 0; kk < 16; kk++) {
      const float4 av = *(const float4*)&As[kk][ty * 4];
      const float4 bv = *(const float4*)&Bs[kk][tx * 4];
      const float a_[4] = {av.x, av.y, av.z, av.w};
      const float b_[4] = {bv.x, bv.y, bv.z, bv.w};
#pragma unroll
      for (int i = 0; i < 4; i++)
#pragma unroll
        for (int j = 0; j < 4; j++) c32[i][j] = fmaf(a_[i], b_[j], c32[i][j]);
    }
#pragma unroll
    for (int i = 0; i < 4; i++)
#pragma unroll
      for (int j = 0; j < 4; j++) acc[i][j] += (double)c32[i][j];
  }
#pragma unroll
  for (int i = 0; i < 4; i++) {
    const int s = m0 + ty * 4 + i;
    float4 o;
    o.x = (float)acc[i][0]; o.y = (float)acc[i][1];
    o.z = (float)acc[i][2]; o.w = (float)acc[i][3];
    *(float4*)&C[(size_t)s * kD + n0 + tx * 4] = o;
  }
}

// ---------------- norms: qn/kn[h][s] = ||.||^2 (fp64) ----------------
__global__ __launch_bounds__(256) void kar_norms_kernel(const float* __restrict__ q,
                                                        const float* __restrict__ k,
                                                        double* __restrict__ qn,
                                                        double* __restrict__ kn) {
  int o = blockIdx.x * 256 + threadIdx.x;  // 0 .. 2*H*S-1
  const float* src; double* dst; int p;
  if (o < kH * kS) { src = q; dst = qn; p = o; }
  else             { src = k; dst = kn; p = o - kH * kS; }
  const float* row = src + (size_t)p * kDH;
  double s = 0.0;
  for (int i = 0; i < kDH; i += 4) {
    float4 x4 = *(const float4*)&row[i];
    s += (double)x4.x * (double)x4.x + (double)x4.y * (double)x4.y +
         (double)x4.z * (double)x4.z + (double)x4.w * (double)x4.w;
  }
  dst[p] = s;
}

// ---------------- U[h][s][p] = sum_r pe[s][r] * hp[h][r][p] ----------------
__global__ __launch_bounds__(256) void kar_u_kernel(const float* __restrict__ pe,
                                                    const float* __restrict__ hp,
                                                    float* __restrict__ U) {
  int o = blockIdx.x * 256 + threadIdx.x;  // < H*S*R
  int r = o & 15, s = (o >> 4) & 2047, h = o >> 15;
  double acc = 0.0;
#pragma unroll
  for (int rp = 0; rp < kR; rp++)
    acc += (double)pe[s * kR + rp] * (double)hp[((h * kR) + rp) * kR + r];
  U[o] = (float)acc;
}

// ---------------- diag_p[h][s] = softplus(K_ss)*diag_scale[h] + reg (fp64 recompute) ----------------
__global__ __launch_bounds__(256) void kar_diagp_kernel(
    const float* __restrict__ q, const float* __restrict__ k,
    const double* __restrict__ qn, const double* __restrict__ kn,
    const double* __restrict__ SC, const float* __restrict__ dsc,
    const float* __restrict__ reg, double* __restrict__ dgp) {
  int o = blockIdx.x * 256 + threadIdx.x;  // < H*S
  int h = o >> 11;
  const float* qp = q + (size_t)o * kDH;
  const float* kp = k + (size_t)o * kDH;
  double dot = 0.0;
  for (int i = 0; i < kDH; i++) dot += (double)qp[i] * (double)kp[i];
  double dist = fmax(qn[o] + kn[o] - 2.0 * dot, 0.0);
  double Kss = exp(-dist * SC[0]);
  double sp  = log1p(exp(Kss));
  dgp[o] = sp * (double)dsc[h] + (double)reg[0];
}

// ---------------- fused K-apply via split-bf16 MFMA ----------------
// Per (64-row s-block, head): loop t in chunks of 64:
//  phase 1: dot = Q.K^T via 3-MFMA split (hi*hi + lo*hi + hi*lo), fp32 acc
//           P = expf(min(2dot - qn - kn, 0) * c)  [fp32], split -> LDS [s][t]
//  phase 2: acc += P @ alpha via 3-MFMA split, persistent f32x4 accumulators
// Error budget: QK^T split err ~2.4e-3 abs on dist -> K rel ~1.4e-3
//   -> out err ~4e-8 vs threshold 5.87e-7 (14x margin).
template <bool FINAL>
__global__ __launch_bounds__(256, 2) void kar_mfma_iter_kernel(
    const float* __restrict__ q, const float* __restrict__ k,
    const float* __restrict__ alpha, const float* __restrict__ v,
    const double* __restrict__ qn, const double* __restrict__ kn,
    const double* __restrict__ SC, float* __restrict__ outp) {
  constexpr int LDW = 72;  // bf16 row stride: 144 B = 36 banks, 16B-aligned rows
  __shared__ short Qh[64 * LDW], Ql[64 * LDW];
  __shared__ short Kh[64 * LDW], Kl[64 * LDW];
  __shared__ short Ph[64 * LDW], Pl[64 * LDW];
  __shared__ short Ah[64 * LDW], Al[64 * LDW];   // alpha^T [d][t]
  __shared__ float qns[64], kns[64];
  const int h   = blockIdx.y;
  const int s0  = blockIdx.x * 64;
  const int tid = threadIdx.x;
  const int lane = tid & 63;
  const int wv   = tid >> 6;     // wave 0..3
  const int l16  = lane & 15;
  const int qd   = lane >> 4;    // quad 0..3
  const int m16  = wv * 16;      // this wave's 16 s-rows
  const float* qh = q + ((size_t)h * kS + s0) * kDH;
  const float* kh = k + (size_t)h * kS * kDH;
  const float* ah = alpha + (size_t)h * kS * kDH;

  // ---- stage Q (split) once ----
  {
    const int row = tid >> 4;          // 0..15
    const int c4  = (tid & 15) * 4;
#pragma unroll
    for (int rep = 0; rep < 4; rep++) {
      const int r = rep * 16 + row;
      const float4 a = *(const float4*)&qh[(size_t)r * kDH + c4];
      short h0, l0, h1, l1, h2, l2, h3, l3;
      kar_split_bf(a.x, h0, l0); kar_split_bf(a.y, h1, l1);
      kar_split_bf(a.z, h2, l2); kar_split_bf(a.w, h3, l3);
      *(short4*)&Qh[r * LDW + c4] = make_short4(h0, h1, h2, h3);
      *(short4*)&Ql[r * LDW + c4] = make_short4(l0, l1, l2, l3);
    }
    if (tid < 64) qns[tid] = (float)qn[h * kS + s0 + tid];
  }
  const float cc   = (float)SC[0];
  f32x4 acco[4];
#pragma unroll
  for (int i = 0; i < 4; i++) acco[i] = (f32x4){0.f, 0.f, 0.f, 0.f};

  for (int t0 = 0; t0 < kS; t0 += 64) {
    __syncthreads();   // prev phase-2 done reading K/A; P safe (per-wave rows)
    // ---- stage K (split) and alpha^T (split) for this chunk ----
    {
      const int row = tid >> 4;
      const int c4  = (tid & 15) * 4;
#pragma unroll
      for (int rep = 0; rep < 4; rep++) {
        const int r = rep * 16 + row;
        const float4 b = *(const float4*)&kh[(size_t)(t0 + r) * kDH + c4];
        short h0, l0, h1, l1, h2, l2, h3, l3;
        kar_split_bf(b.x, h0, l0); kar_split_bf(b.y, h1, l1);
        kar_split_bf(b.z, h2, l2); kar_split_bf(b.w, h3, l3);
        *(short4*)&Kh[r * LDW + c4] = make_short4(h0, h1, h2, h3);
        *(short4*)&Kl[r * LDW + c4] = make_short4(l0, l1, l2, l3);
        const float4 av = *(const float4*)&ah[(size_t)(t0 + r) * kDH + c4];
        kar_split_bf(av.x, h0, l0); kar_split_bf(av.y, h1, l1);
        kar_split_bf(av.z, h2, l2); kar_split_bf(av.w, h3, l3);
        Ah[(c4 + 0) * LDW + r] = h0; Al[(c4 + 0) * LDW + r] = l0;
        Ah[(c4 + 1) * LDW + r] = h1; Al[(c4 + 1) * LDW + r] = l1;
        Ah[(c4 + 2) * LDW + r] = h2; Al[(c4 + 2) * LDW + r] = l2;
        Ah[(c4 + 3) * LDW + r] = h3; Al[(c4 + 3) * LDW + r] = l3;
      }
      if (tid < 64) kns[tid] = (float)kn[h * kS + t0 + tid];
    }
    __syncthreads();
    // ---- phase 1: QK^T (split-bf16 MFMA) ----
    f32x4 accp[4];
#pragma unroll
    for (int i = 0; i < 4; i++) accp[i] = (f32x4){0.f, 0.f, 0.f, 0.f};
#pragma unroll
    for (int kt = 0; kt < 2; kt++) {
      const int ko = kt * 32 + qd * 8;
      const bf16x8 aH = *(const bf16x8*)&Qh[(m16 + l16) * LDW + ko];
      const bf16x8 aL = *(const bf16x8*)&Ql[(m16 + l16) * LDW + ko];
#pragma unroll
      for (int nt = 0; nt < 4; nt++) {
        const bf16x8 bH = *(const bf16x8*)&Kh[(nt * 16 + l16) * LDW + ko];
        const bf16x8 bL = *(const bf16x8*)&Kl[(nt * 16 + l16) * LDW + ko];
        accp[nt] = __builtin_amdgcn_mfma_f32_16x16x32_bf16(aH, bH, accp[nt], 0, 0, 0);
        accp[nt] = __builtin_amdgcn_mfma_f32_16x16x32_bf16(aL, bH, accp[nt], 0, 0, 0);
        accp[nt] = __builtin_amdgcn_mfma_f32_16x16x32_bf16(aH, bL, accp[nt], 0, 0, 0);
      }
    }
    // ---- exp + split + store P [s][t] (each wave writes only its 16 rows) ----
#pragma unroll
    for (int nt = 0; nt < 4; nt++) {
      const int tcol = nt * 16 + l16;
      const float kv = kns[tcol];
#pragma unroll
      for (int r = 0; r < 4; r++) {
        const int srow = m16 + qd * 4 + r;
        const float e2 = fmaf(2.0f, accp[nt][r], -(qns[srow] + kv));
        const float val = __expf(fminf(e2, 0.0f) * cc);
        short hb, lb; kar_split_bf(val, hb, lb);
        Ph[srow * LDW + tcol] = hb;
        Pl[srow * LDW + tcol] = lb;
      }
    }
    // ---- phase 2: acc += P @ alpha (split-bf16 MFMA); per-wave P rows, no barrier ----
#pragma unroll
    for (int kt = 0; kt < 2; kt++) {
      const int ko = kt * 32 + qd * 8;
      const bf16x8 pH = *(const bf16x8*)&Ph[(m16 + l16) * LDW + ko];
      const bf16x8 pL = *(const bf16x8*)&Pl[(m16 + l16) * LDW + ko];
#pragma unroll
      for (int dt = 0; dt < 4; dt++) {
        const bf16x8 bH = *(const bf16x8*)&Ah[(dt * 16 + l16) * LDW + ko];
        const bf16x8 bL = *(const bf16x8*)&Al[(dt * 16 + l16) * LDW + ko];
        acco[dt] = __builtin_amdgcn_mfma_f32_16x16x32_bf16(pH, bH, acco[dt], 0, 0, 0);
        acco[dt] = __builtin_amdgcn_mfma_f32_16x16x32_bf16(pL, bH, acco[dt], 0, 0, 0);
        acco[dt] = __builtin_amdgcn_mfma_f32_16x16x32_bf16(pH, bL, acco[dt], 0, 0, 0);
      }
    }
  }
  // ---- epilogue ----
  if (FINAL) {
#pragma unroll
    for (int dt = 0; dt < 4; dt++) {
#pragma unroll
      for (int r = 0; r < 4; r++) {
        const int s = s0 + m16 + qd * 4 + r;
        const int d = dt * 16 + l16;
        outp[(size_t)s * kD + h * kDH + d] = acco[dt][r];
      }
    }
  } else {
    const float lamf = (float)SC[1];
#pragma unroll
    for (int dt = 0; dt < 4; dt++) {
#pragma unroll
      for (int r = 0; r < 4; r++) {
        const int s = s0 + m16 + qd * 4 + r;
        const int d = dt * 16 + l16;
        const size_t eg = ((size_t)h * kS + s) * kDH + d;
        outp[eg] = v[eg] - (acco[dt][r] + lamf * alpha[eg]);
      }
    }
  }
}

// ---------------- ut_r partials ----------------
__global__ __launch_bounds__(256) void kar_utr_partial_kernel(
    const float* __restrict__ Ubuf, const float* __restrict__ rbuf,
    double* __restrict__ utrp) {
  const int h  = blockIdx.y;
  const int sb = blockIdx.x * 128;
  const int t  = threadIdx.x;
  __shared__ float Uch[32][16];
  __shared__ float Rch[32][64];
  double acc[4] = {};
  for (int cs = 0; cs < 128; cs += 32) {
    __syncthreads();
    if (t < 128) {
      const int i = t >> 2, f = (t & 3) * 4;
      *(float4*)&Uch[i][f] = *(const float4*)&Ubuf[((size_t)(h * kS) + sb + cs + i) * kR + f];
    }
#pragma unroll
    for (int rep = 0; rep < 2; rep++) {
      const int e = t + rep * 256;
      const int i = e >> 4, c = (e & 15) * 4;
      *(float4*)&Rch[i][c] = *(const float4*)&rbuf[((size_t)(h * kS) + sb + cs + i) * kDH + c];
    }
    __syncthreads();
    for (int i = 0; i < 32; i++) {
#pragma unroll
      for (int rep = 0; rep < 4; rep++) {
        const int p = t + rep * 256;
        const int r = p >> 6, d = p & 63;
        acc[rep] += (double)Uch[i][r] * (double)Rch[i][d];
      }
    }
  }
#pragma unroll
  for (int rep = 0; rep < 4; rep++) {
    const int p = t + rep * 256;
    const int r = p >> 6, d = p & 63;
    utrp[(((size_t)(h * 16) + blockIdx.x) * kR + r) * kDH + d] = acc[rep];
  }
}

__global__ __launch_bounds__(256) void kar_utr_reduce_kernel(const double* __restrict__ utrp,
                                                             double* __restrict__ utr) {
  int o = blockIdx.x * 256 + threadIdx.x;  // < H*R*DH
  int h = o >> 10, rd = o & 1023;
  double s = 0.0;
#pragma unroll
  for (int j = 0; j < 16; j++) s += utrp[(size_t)h * 16384 + (size_t)j * 1024 + rd];
  utr[o] = s;
}

// ---------------- alpha (+)= r*diag_p + U @ utr ----------------
__global__ __launch_bounds__(256) void kar_update_kernel(
    const float* __restrict__ rsrc, const double* __restrict__ dgp,
    const float* __restrict__ Ubuf, const double* __restrict__ utr,
    float* __restrict__ alpha, int first) {
  int e = blockIdx.x * 256 + threadIdx.x;  // < H*S*DH
  const int d = e & 63;
  const int s = (e >> 6) & 2047;
  const int h = e >> 17;
  const double rv = (double)rsrc[e];
  const double dp = dgp[h * kS + s];
  const float*  Us = &Ubuf[((size_t)(h * kS) + s) * kR];
  const double* uh = &utr[(size_t)h * kR * kDH];
  double sum = 0.0;
#pragma unroll
  for (int ri = 0; ri < kR; ri++) sum += (double)Us[ri] * uh[ri * kDH + d];
  const double p = rv * dp + sum;
  const double an = (first ? 0.0 : (double)alpha[e]) + p;
  alpha[e] = (float)an;
}

extern "C" void kernel_launch(void* const* d_in, const int* in_sizes, int n_in,
                              void* d_out, int out_size, void* d_ws, size_t ws_size,
                              hipStream_t stream) {
  (void)in_sizes; (void)n_in; (void)out_size; (void)ws_size;
  const float* x    = (const float*)d_in[0];
  const float* Wq   = (const float*)d_in[1];
  const float* Wk   = (const float*)d_in[2];
  const float* Wv   = (const float*)d_in[3];
  const float* Wo   = (const float*)d_in[4];
  const float* bw   = (const float*)d_in[5];
  const float* dsc  = (const float*)d_in[6];
  const float* pe   = (const float*)d_in[7];
  const float* hp   = (const float*)d_in[8];
  const float* reg  = (const float*)d_in[9];
  const float* lreg = (const float*)d_in[10];
  float* out = (float*)d_out;

  char* w = (char*)d_ws;
  size_t off = 0;
  auto take = [&](size_t bytes) -> void* {
    void* p = w + off;
    off += (bytes + 255) & ~(size_t)255;
    return p;
  };
  const size_t HSD = (size_t)kH * kS * kDH;  // 2M elements
  float*  q     = (float*)take(HSD * 4);
  float*  k     = (float*)take(HSD * 4);
  float*  v     = (float*)take(HSD * 4);
  float*  alpha = (float*)take(HSD * 4);
  float*  rbuf  = (float*)take(HSD * 4);
  float*  tmp   = (float*)take((size_t)kS * kD * 4);
  double* qn    = (double*)take((size_t)kH * kS * 8);
  double* kn    = (double*)take((size_t)kH * kS * 8);
  double* dgp   = (double*)take((size_t)kH * kS * 8);
  float*  U     = (float*)take((size_t)kH * kS * kR * 4);
  double* utr   = (double*)take((size_t)kH * kR * kDH * 8);
  double* utrp  = (double*)take((size_t)kH * 16 * kR * kDH * 8);
  double* SC    = (double*)take(256);

  kar_scalars_kernel<<<1, 64, 0, stream>>>(bw, lreg, SC);
  kar_gemm_qkv_kernel<<<dim3(16, 32, 3), 256, 0, stream>>>(x, Wq, Wk, Wv, q, k, v);
  kar_norms_kernel<<<256, 256, 0, stream>>>(q, k, qn, kn);
  kar_u_kernel<<<2048, 256, 0, stream>>>(pe, hp, U);
  kar_diagp_kernel<<<128, 256, 0, stream>>>(q, k, qn, kn, SC, dsc, reg, dgp);

  // Iteration 0: alpha == 0 exactly -> r == v. Skip the K application.
  kar_utr_partial_kernel<<<dim3(16, kH), 256, 0, stream>>>(U, v, utrp);
  kar_utr_reduce_kernel<<<64, 256, 0, stream>>>(utrp, utr);
  kar_update_kernel<<<8192, 256, 0, stream>>>(v, dgp, U, utr, alpha, 1);

  for (int it = 1; it < 5; it++) {
    kar_mfma_iter_kernel<false><<<dim3(32, kH), 256, 0, stream>>>(
        q, k, alpha, v, qn, kn, SC, rbuf);
    kar_utr_partial_kernel<<<dim3(16, kH), 256, 0, stream>>>(U, rbuf, utrp);
    kar_utr_reduce_kernel<<<64, 256, 0, stream>>>(utrp, utr);
    kar_update_kernel<<<8192, 256, 0, stream>>>(rbuf, dgp, U, utr, alpha, 0);
  }

  kar_mfma_iter_kernel<true><<<dim3(32, kH), 256, 0, stream>>>(
      q, k, alpha, v, qn, kn, SC, tmp);
  kar_gemm_plain_kernel<<<dim3(16, 32), 256, 0, stream>>>(tmp, Wo, out);
}

// Round 6
// 877.820 us; speedup vs baseline: 2.7826x; 1.4368x over previous
//
#include <hip/hip_runtime.h>
#include <cstdint>
#include <cstddef>

constexpr int kS  = 2048;
constexpr int kD  = 1024;
constexpr int kH  = 16;
constexpr int kDH = 64;
constexpr int kR  = 16;

typedef __attribute__((ext_vector_type(8))) short bf16x8;
typedef __attribute__((ext_vector_type(4))) float f32x4;

__device__ __forceinline__ unsigned short kar_f2bf(float x) {
  unsigned u = __float_as_uint(x);
  return (unsigned short)((u + 0x7FFFu + ((u >> 16) & 1u)) >> 16);
}
__device__ __forceinline__ float kar_bf2f(short h) {
  return __uint_as_float((unsigned)(unsigned short)h << 16);
}
__device__ __forceinline__ void kar_split_bf(float x, short& hi, short& lo) {
  unsigned short h = kar_f2bf(x);
  float hf = __uint_as_float((unsigned)h << 16);
  hi = (short)h;
  lo = (short)kar_f2bf(x - hf);
}

// ---------------- scalars ----------------
__global__ __launch_bounds__(64) void kar_scalars_kernel(const float* __restrict__ bw,
                                                         const float* __restrict__ lreg,
                                                         double* __restrict__ SC) {
  if (threadIdx.x == 0) {
    double b = log1p(exp((double)bw[0])) + 1e-6;
    SC[0] = 1.0 / (2.0 * b * b);
    SC[1] = log1p(exp((double)lreg[0]));
  }
}

// ---------------- U[h][s][p] ----------------
__global__ __launch_bounds__(256) void kar_u_kernel(const float* __restrict__ pe,
                                                    const float* __restrict__ hp,
                                                    float* __restrict__ U) {
  int o = blockIdx.x * 256 + threadIdx.x;
  int r = o & 15, s = (o >> 4) & 2047, h = o >> 15;
  double acc = 0.0;
#pragma unroll
  for (int rp = 0; rp < kR; rp++)
    acc += (double)pe[s * kR + rp] * (double)hp[((h * kR) + rp) * kR + r];
  U[o] = (float)acc;
}

// ---------------- ut_r partials / reduce / update ----------------
__global__ __launch_bounds__(256) void kar_utr_partial_kernel(
    const float* __restrict__ Ubuf, const float* __restrict__ rbuf,
    double* __restrict__ utrp) {
  const int h  = blockIdx.y;
  const int sb = blockIdx.x * 128;
  const int t  = threadIdx.x;
  __shared__ float Uch[32][16];
  __shared__ float Rch[32][64];
  double acc[4] = {};
  for (int cs = 0; cs < 128; cs += 32) {
    __syncthreads();
    if (t < 128) {
      const int i = t >> 2, f = (t & 3) * 4;
      *(float4*)&Uch[i][f] = *(const float4*)&Ubuf[((size_t)(h * kS) + sb + cs + i) * kR + f];
    }
#pragma unroll
    for (int rep = 0; rep < 2; rep++) {
      const int e = t + rep * 256;
      const int i = e >> 4, c = (e & 15) * 4;
      *(float4*)&Rch[i][c] = *(const float4*)&rbuf[((size_t)(h * kS) + sb + cs + i) * kDH + c];
    }
    __syncthreads();
    for (int i = 0; i < 32; i++) {
#pragma unroll
      for (int rep = 0; rep < 4; rep++) {
        const int p = t + rep * 256;
        const int r = p >> 6, d = p & 63;
        acc[rep] += (double)Uch[i][r] * (double)Rch[i][d];
      }
    }
  }
#pragma unroll
  for (int rep = 0; rep < 4; rep++) {
    const int p = t + rep * 256;
    const int r = p >> 6, d = p & 63;
    utrp[(((size_t)(h * 16) + blockIdx.x) * kR + r) * kDH + d] = acc[rep];
  }
}

__global__ __launch_bounds__(256) void kar_utr_reduce_kernel(const double* __restrict__ utrp,
                                                             double* __restrict__ utr) {
  int o = blockIdx.x * 256 + threadIdx.x;
  int h = o >> 10, rd = o & 1023;
  double s = 0.0;
#pragma unroll
  for (int j = 0; j < 16; j++) s += utrp[(size_t)h * 16384 + (size_t)j * 1024 + rd];
  utr[o] = s;
}

__global__ __launch_bounds__(256) void kar_update_kernel(
    const float* __restrict__ rsrc, const double* __restrict__ dgp,
    const float* __restrict__ Ubuf, const double* __restrict__ utr,
    float* __restrict__ alpha, int first) {
  int e = blockIdx.x * 256 + threadIdx.x;
  const int d = e & 63;
  const int s = (e >> 6) & 2047;
  const int h = e >> 17;
  const double rv = (double)rsrc[e];
  const double dp = dgp[h * kS + s];
  const float*  Us = &Ubuf[((size_t)(h * kS) + s) * kR];
  const double* uh = &utr[(size_t)h * kR * kDH];
  double sum = 0.0;
#pragma unroll
  for (int ri = 0; ri < kR; ri++) sum += (double)Us[ri] * uh[ri * kDH + d];
  const double p = rv * dp + sum;
  const double an = (first ? 0.0 : (double)alpha[e]) + p;
  alpha[e] = (float)an;
}

// ================= NEW PATH kernels =================

__global__ __launch_bounds__(256) void kar_xsplit_kernel(const float* __restrict__ x,
                                                         short* __restrict__ xh,
                                                         short* __restrict__ xl) {
  size_t e = ((size_t)blockIdx.x * 256 + threadIdx.x) * 4;
  float4 a = *(const float4*)&x[e];
  short h0, l0, h1, l1, h2, l2, h3, l3;
  kar_split_bf(a.x, h0, l0); kar_split_bf(a.y, h1, l1);
  kar_split_bf(a.z, h2, l2); kar_split_bf(a.w, h3, l3);
  *(short4*)&xh[e] = make_short4(h0, h1, h2, h3);
  *(short4*)&xl[e] = make_short4(l0, l1, l2, l3);
}

__global__ __launch_bounds__(256) void kar_wsplit_kernel(
    const float* __restrict__ Wq, const float* __restrict__ Wk,
    const float* __restrict__ Wv, const float* __restrict__ Wo,
    short* __restrict__ WTh, short* __restrict__ WTl) {
  const float* W = (blockIdx.z == 0) ? Wq : (blockIdx.z == 1) ? Wk
                 : (blockIdx.z == 2) ? Wv : Wo;
  short* oh = WTh + (size_t)blockIdx.z * kD * kD;
  short* ol = WTl + (size_t)blockIdx.z * kD * kD;
  const int n0 = blockIdx.x * 64, k0 = blockIdx.y * 64;
  __shared__ float T[64][65];
  const int t = threadIdx.x;
  const int r16 = t >> 4, c4 = (t & 15) * 4;
#pragma unroll
  for (int it = 0; it < 4; it++) {
    int r = it * 16 + r16;
    float4 a = *(const float4*)&W[(size_t)(k0 + r) * kD + n0 + c4];
    T[r][c4] = a.x; T[r][c4 + 1] = a.y; T[r][c4 + 2] = a.z; T[r][c4 + 3] = a.w;
  }
  __syncthreads();
#pragma unroll
  for (int it = 0; it < 4; it++) {
    int n = it * 16 + r16;
    float v0 = T[c4][n], v1 = T[c4 + 1][n], v2 = T[c4 + 2][n], v3 = T[c4 + 3][n];
    short h0, l0, h1, l1, h2, l2, h3, l3;
    kar_split_bf(v0, h0, l0); kar_split_bf(v1, h1, l1);
    kar_split_bf(v2, h2, l2); kar_split_bf(v3, h3, l3);
    *(short4*)&oh[(size_t)(n0 + n) * kD + k0 + c4] = make_short4(h0, h1, h2, h3);
    *(short4*)&ol[(size_t)(n0 + n) * kD + k0 + c4] = make_short4(l0, l1, l2, l3);
  }
}

__global__ __launch_bounds__(256) void kar_asplit_kernel(const float* __restrict__ alpha,
                                                         short* __restrict__ ath,
                                                         short* __restrict__ atl) {
  const int h = blockIdx.y, s0 = blockIdx.x * 64;
  __shared__ float T[64][65];
  const int t = threadIdx.x;
  const int r16 = t >> 4, c4 = (t & 15) * 4;
#pragma unroll
  for (int it = 0; it < 4; it++) {
    int r = it * 16 + r16;  // s-local
    float4 a = *(const float4*)&alpha[(((size_t)h * kS) + s0 + r) * kDH + c4];
    T[r][c4] = a.x; T[r][c4 + 1] = a.y; T[r][c4 + 2] = a.z; T[r][c4 + 3] = a.w;
  }
  __syncthreads();
#pragma unroll
  for (int it = 0; it < 4; it++) {
    int d = it * 16 + r16;
    float v0 = T[c4][d], v1 = T[c4 + 1][d], v2 = T[c4 + 2][d], v3 = T[c4 + 3][d];
    short h0, l0, h1, l1, h2, l2, h3, l3;
    kar_split_bf(v0, h0, l0); kar_split_bf(v1, h1, l1);
    kar_split_bf(v2, h2, l2); kar_split_bf(v3, h3, l3);
    *(short4*)&ath[((size_t)h * kDH + d) * kS + s0 + c4] = make_short4(h0, h1, h2, h3);
    *(short4*)&atl[((size_t)h * kDH + d) * kS + s0 + c4] = make_short4(l0, l1, l2, l3);
  }
}

// MFMA split-bf16 GEMM: QKV. z=0,1: split dumps q/k; z=2: v fp32.
__global__ __launch_bounds__(256) void kar_mfma_gemm_qkv_kernel(
    const short* __restrict__ xh, const short* __restrict__ xl,
    const short* __restrict__ WTh, const short* __restrict__ WTl,
    float* __restrict__ v,
    short* __restrict__ qsh, short* __restrict__ qsl,
    short* __restrict__ ksh, short* __restrict__ ksl) {
  const int z = blockIdx.z;
  const short* Bh = WTh + (size_t)z * kD * kD;
  const short* Bl = WTl + (size_t)z * kD * kD;
  const int n0 = blockIdx.x * 64;   // head = blockIdx.x
  const int m0 = blockIdx.y * 128;
  constexpr int LW = 40;
  __shared__ short Xh[128 * LW], Xl[128 * LW], Wh[64 * LW], Wl[64 * LW];
  const int t = threadIdx.x, lane = t & 63, wv = t >> 6;
  const int wm = wv >> 1, wn = wv & 1, l16 = lane & 15, qd = lane >> 4;
  f32x4 acc[4][2];
#pragma unroll
  for (int i = 0; i < 4; i++)
#pragma unroll
    for (int j = 0; j < 2; j++) acc[i][j] = (f32x4){0.f, 0.f, 0.f, 0.f};
  const int xrow = t >> 1, xc = (t & 1) * 16;
  for (int k0 = 0; k0 < kD; k0 += 32) {
    __syncthreads();
    {  // X rows: 2 threads/row x 16 shorts each (two bf16x8) = 32 shorts
      const size_t xs = (size_t)(m0 + xrow) * kD + k0 + xc;
      *(bf16x8*)&Xh[xrow * LW + xc]     = *(const bf16x8*)&xh[xs];
      *(bf16x8*)&Xh[xrow * LW + xc + 8] = *(const bf16x8*)&xh[xs + 8];
      *(bf16x8*)&Xl[xrow * LW + xc]     = *(const bf16x8*)&xl[xs];
      *(bf16x8*)&Xl[xrow * LW + xc + 8] = *(const bf16x8*)&xl[xs + 8];
    }
    if (t < 128) {
      const int wrow = t >> 1, wc = (t & 1) * 16;
      const size_t wsrc = (size_t)(n0 + wrow) * kD + k0 + wc;
      *(bf16x8*)&Wh[wrow * LW + wc]     = *(const bf16x8*)&Bh[wsrc];
      *(bf16x8*)&Wh[wrow * LW + wc + 8] = *(const bf16x8*)&Bh[wsrc + 8];
    } else {
      const int t2 = t - 128, wrow = t2 >> 1, wc = (t2 & 1) * 16;
      const size_t wsrc = (size_t)(n0 + wrow) * kD + k0 + wc;
      *(bf16x8*)&Wl[wrow * LW + wc]     = *(const bf16x8*)&Bl[wsrc];
      *(bf16x8*)&Wl[wrow * LW + wc + 8] = *(const bf16x8*)&Bl[wsrc + 8];
    }
    __syncthreads();
    bf16x8 bH[2], bL[2];
#pragma unroll
    for (int ni = 0; ni < 2; ni++) {
      const int rn = wn * 32 + ni * 16 + l16;
      bH[ni] = *(const bf16x8*)&Wh[rn * LW + qd * 8];
      bL[ni] = *(const bf16x8*)&Wl[rn * LW + qd * 8];
    }
#pragma unroll
    for (int mi = 0; mi < 4; mi++) {
      const int rm = wm * 64 + mi * 16 + l16;
      const bf16x8 aH = *(const bf16x8*)&Xh[rm * LW + qd * 8];
      const bf16x8 aL = *(const bf16x8*)&Xl[rm * LW + qd * 8];
#pragma unroll
      for (int ni = 0; ni < 2; ni++) {
        acc[mi][ni] = __builtin_amdgcn_mfma_f32_16x16x32_bf16(aH, bH[ni], acc[mi][ni], 0, 0, 0);
        acc[mi][ni] = __builtin_amdgcn_mfma_f32_16x16x32_bf16(aL, bH[ni], acc[mi][ni], 0, 0, 0);
        acc[mi][ni] = __builtin_amdgcn_mfma_f32_16x16x32_bf16(aH, bL[ni], acc[mi][ni], 0, 0, 0);
      }
    }
  }
  const int h = blockIdx.x;
#pragma unroll
  for (int mi = 0; mi < 4; mi++)
#pragma unroll
    for (int ni = 0; ni < 2; ni++) {
      const int d = wn * 32 + ni * 16 + l16;
#pragma unroll
      for (int r = 0; r < 4; r++) {
        const int s = m0 + wm * 64 + mi * 16 + qd * 4 + r;
        const float val = acc[mi][ni][r];
        const size_t idx = (((size_t)h * kS) + s) * kDH + d;
        if (z == 2) {
          v[idx] = val;
        } else {
          short hh, ll; kar_split_bf(val, hh, ll);
          if (z == 0) { qsh[idx] = hh; qsl[idx] = ll; }
          else        { ksh[idx] = hh; ksl[idx] = ll; }
        }
      }
    }
}

// MFMA split-bf16 GEMM: out = tmp @ Wo
__global__ __launch_bounds__(256) void kar_mfma_gemm_wo_kernel(
    const short* __restrict__ th, const short* __restrict__ tl,
    const short* __restrict__ Bh, const short* __restrict__ Bl,
    float* __restrict__ outp) {
  const int n0 = blockIdx.x * 64;
  const int m0 = blockIdx.y * 128;
  constexpr int LW = 40;
  __shared__ short Xh[128 * LW], Xl[128 * LW], Wh[64 * LW], Wl[64 * LW];
  const int t = threadIdx.x, lane = t & 63, wv = t >> 6;
  const int wm = wv >> 1, wn = wv & 1, l16 = lane & 15, qd = lane >> 4;
  f32x4 acc[4][2];
#pragma unroll
  for (int i = 0; i < 4; i++)
#pragma unroll
    for (int j = 0; j < 2; j++) acc[i][j] = (f32x4){0.f, 0.f, 0.f, 0.f};
  const int xrow = t >> 1, xc = (t & 1) * 16;
  for (int k0 = 0; k0 < kD; k0 += 32) {
    __syncthreads();
    {
      const size_t xs = (size_t)(m0 + xrow) * kD + k0 + xc;
      *(bf16x8*)&Xh[xrow * LW + xc]     = *(const bf16x8*)&th[xs];
      *(bf16x8*)&Xh[xrow * LW + xc + 8] = *(const bf16x8*)&th[xs + 8];
      *(bf16x8*)&Xl[xrow * LW + xc]     = *(const bf16x8*)&tl[xs];
      *(bf16x8*)&Xl[xrow * LW + xc + 8] = *(const bf16x8*)&tl[xs + 8];
    }
    if (t < 128) {
      const int wrow = t >> 1, wc = (t & 1) * 16;
      const size_t wsrc = (size_t)(n0 + wrow) * kD + k0 + wc;
      *(bf16x8*)&Wh[wrow * LW + wc]     = *(const bf16x8*)&Bh[wsrc];
      *(bf16x8*)&Wh[wrow * LW + wc + 8] = *(const bf16x8*)&Bh[wsrc + 8];
    } else {
      const int t2 = t - 128, wrow = t2 >> 1, wc = (t2 & 1) * 16;
      const size_t wsrc = (size_t)(n0 + wrow) * kD + k0 + wc;
      *(bf16x8*)&Wl[wrow * LW + wc]     = *(const bf16x8*)&Bl[wsrc];
      *(bf16x8*)&Wl[wrow * LW + wc + 8] = *(const bf16x8*)&Bl[wsrc + 8];
    }
    __syncthreads();
    bf16x8 bH[2], bL[2];
#pragma unroll
    for (int ni = 0; ni < 2; ni++) {
      const int rn = wn * 32 + ni * 16 + l16;
      bH[ni] = *(const bf16x8*)&Wh[rn * LW + qd * 8];
      bL[ni] = *(const bf16x8*)&Wl[rn * LW + qd * 8];
    }
#pragma unroll
    for (int mi = 0; mi < 4; mi++) {
      const int rm = wm * 64 + mi * 16 + l16;
      const bf16x8 aH = *(const bf16x8*)&Xh[rm * LW + qd * 8];
      const bf16x8 aL = *(const bf16x8*)&Xl[rm * LW + qd * 8];
#pragma unroll
      for (int ni = 0; ni < 2; ni++) {
        acc[mi][ni] = __builtin_amdgcn_mfma_f32_16x16x32_bf16(aH, bH[ni], acc[mi][ni], 0, 0, 0);
        acc[mi][ni] = __builtin_amdgcn_mfma_f32_16x16x32_bf16(aL, bH[ni], acc[mi][ni], 0, 0, 0);
        acc[mi][ni] = __builtin_amdgcn_mfma_f32_16x16x32_bf16(aH, bL[ni], acc[mi][ni], 0, 0, 0);
      }
    }
  }
#pragma unroll
  for (int mi = 0; mi < 4; mi++)
#pragma unroll
    for (int ni = 0; ni < 2; ni++) {
      const int col = n0 + wn * 32 + ni * 16 + l16;
#pragma unroll
      for (int r = 0; r < 4; r++) {
        const int s = m0 + wm * 64 + mi * 16 + qd * 4 + r;
        outp[(size_t)s * kD + col] = acc[mi][ni][r];
      }
    }
}

// norms from splits
__global__ __launch_bounds__(256) void kar_norms2_kernel(
    const short* __restrict__ qsh, const short* __restrict__ qsl,
    const short* __restrict__ ksh, const short* __restrict__ ksl,
    double* __restrict__ qn, double* __restrict__ kn) {
  int o = blockIdx.x * 256 + threadIdx.x;
  const short *sh, *sl; double* dst; int p;
  if (o < kH * kS) { sh = qsh; sl = qsl; dst = qn; p = o; }
  else             { sh = ksh; sl = ksl; dst = kn; p = o - kH * kS; }
  const short* rh = sh + (size_t)p * kDH;
  const short* rl = sl + (size_t)p * kDH;
  double s = 0.0;
  for (int i = 0; i < kDH; i += 4) {
    short4 a = *(const short4*)&rh[i];
    short4 b = *(const short4*)&rl[i];
    double e0 = (double)kar_bf2f(a.x) + (double)kar_bf2f(b.x);
    double e1 = (double)kar_bf2f(a.y) + (double)kar_bf2f(b.y);
    double e2 = (double)kar_bf2f(a.z) + (double)kar_bf2f(b.z);
    double e3 = (double)kar_bf2f(a.w) + (double)kar_bf2f(b.w);
    s += e0 * e0 + e1 * e1 + e2 * e2 + e3 * e3;
  }
  dst[p] = s;
}

// diag_p from splits
__global__ __launch_bounds__(256) void kar_diagp2_kernel(
    const short* __restrict__ qsh, const short* __restrict__ qsl,
    const short* __restrict__ ksh, const short* __restrict__ ksl,
    const double* __restrict__ qn, const double* __restrict__ kn,
    const double* __restrict__ SC, const float* __restrict__ dsc,
    const float* __restrict__ reg, double* __restrict__ dgp) {
  int o = blockIdx.x * 256 + threadIdx.x;
  int h = o >> 11;
  const short* qh = qsh + (size_t)o * kDH;
  const short* ql = qsl + (size_t)o * kDH;
  const short* kh = ksh + (size_t)o * kDH;
  const short* kl = ksl + (size_t)o * kDH;
  double dot = 0.0;
  for (int i = 0; i < kDH; i++) {
    double qi = (double)kar_bf2f(qh[i]) + (double)kar_bf2f(ql[i]);
    double ki = (double)kar_bf2f(kh[i]) + (double)kar_bf2f(kl[i]);
    dot += qi * ki;
  }
  double dist = fmax(qn[o] + kn[o] - 2.0 * dot, 0.0);
  double Kss = exp(-dist * SC[0]);
  double sp  = log1p(exp(Kss));
  dgp[o] = sp * (double)dsc[h] + (double)reg[0];
}

// fused K-apply: presplit q/k/alpha^T staging, split-bf16 MFMA
template <bool FINAL>
__global__ __launch_bounds__(256, 2) void kar_mfma_iter2_kernel(
    const short* __restrict__ qsh, const short* __restrict__ qsl,
    const short* __restrict__ ksh, const short* __restrict__ ksl,
    const short* __restrict__ ath, const short* __restrict__ atl,
    const float* __restrict__ alpha, const float* __restrict__ v,
    const double* __restrict__ qn, const double* __restrict__ kn,
    const double* __restrict__ SC, float* __restrict__ outp,
    short* __restrict__ tmph, short* __restrict__ tmpl) {
  constexpr int LDW = 72;
  __shared__ short Qh[64 * LDW], Ql[64 * LDW];
  __shared__ short Kh[64 * LDW], Kl[64 * LDW];
  __shared__ short Ph[64 * LDW], Pl[64 * LDW];
  __shared__ short Ah[64 * LDW], Al[64 * LDW];
  __shared__ float qns[64], kns[64];
  const int h   = blockIdx.y;
  const int s0  = blockIdx.x * 64;
  const int tid = threadIdx.x;
  const int lane = tid & 63;
  const int wv   = tid >> 6;
  const int l16  = lane & 15;
  const int qd   = lane >> 4;
  const int m16  = wv * 16;
  const int row = tid >> 2, c8 = (tid & 3) * 16;  // 4 threads/row x 16 shorts
  // stage Q once
  {
    const size_t src = (((size_t)h * kS) + s0 + row) * kDH;
    *(bf16x8*)&Qh[row * LDW + c8]     = *(const bf16x8*)&qsh[src + c8];
    *(bf16x8*)&Qh[row * LDW + c8 + 8] = *(const bf16x8*)&qsh[src + c8 + 8];
    *(bf16x8*)&Ql[row * LDW + c8]     = *(const bf16x8*)&qsl[src + c8];
    *(bf16x8*)&Ql[row * LDW + c8 + 8] = *(const bf16x8*)&qsl[src + c8 + 8];
  }
  if (tid < 64) qns[tid] = (float)qn[h * kS + s0 + tid];
  const float cc = (float)SC[0];
  f32x4 acco[4];
#pragma unroll
  for (int i = 0; i < 4; i++) acco[i] = (f32x4){0.f, 0.f, 0.f, 0.f};

  for (int t0 = 0; t0 < kS; t0 += 64) {
    __syncthreads();
    {
      const size_t ksrc = (((size_t)h * kS) + t0 + row) * kDH;
      *(bf16x8*)&Kh[row * LDW + c8]     = *(const bf16x8*)&ksh[ksrc + c8];
      *(bf16x8*)&Kh[row * LDW + c8 + 8] = *(const bf16x8*)&ksh[ksrc + c8 + 8];
      *(bf16x8*)&Kl[row * LDW + c8]     = *(const bf16x8*)&ksl[ksrc + c8];
      *(bf16x8*)&Kl[row * LDW + c8 + 8] = *(const bf16x8*)&ksl[ksrc + c8 + 8];
      const size_t asrc = ((size_t)h * kDH + row) * kS + t0;
      *(bf16x8*)&Ah[row * LDW + c8]     = *(const bf16x8*)&ath[asrc + c8];
      *(bf16x8*)&Ah[row * LDW + c8 + 8] = *(const bf16x8*)&ath[asrc + c8 + 8];
      *(bf16x8*)&Al[row * LDW + c8]     = *(const bf16x8*)&atl[asrc + c8];
      *(bf16x8*)&Al[row * LDW + c8 + 8] = *(const bf16x8*)&atl[asrc + c8 + 8];
    }
    if (tid < 64) kns[tid] = (float)kn[h * kS + t0 + tid];
    __syncthreads();
    // phase 1: QK^T
    f32x4 accp[4];
#pragma unroll
    for (int i = 0; i < 4; i++) accp[i] = (f32x4){0.f, 0.f, 0.f, 0.f};
#pragma unroll
    for (int kt = 0; kt < 2; kt++) {
      const int ko = kt * 32 + qd * 8;
      const bf16x8 aH = *(const bf16x8*)&Qh[(m16 + l16) * LDW + ko];
      const bf16x8 aL = *(const bf16x8*)&Ql[(m16 + l16) * LDW + ko];
#pragma unroll
      for (int nt = 0; nt < 4; nt++) {
        const bf16x8 bH = *(const bf16x8*)&Kh[(nt * 16 + l16) * LDW + ko];
        const bf16x8 bL = *(const bf16x8*)&Kl[(nt * 16 + l16) * LDW + ko];
        accp[nt] = __builtin_amdgcn_mfma_f32_16x16x32_bf16(aH, bH, accp[nt], 0, 0, 0);
        accp[nt] = __builtin_amdgcn_mfma_f32_16x16x32_bf16(aL, bH, accp[nt], 0, 0, 0);
        accp[nt] = __builtin_amdgcn_mfma_f32_16x16x32_bf16(aH, bL, accp[nt], 0, 0, 0);
      }
    }
    // exp + split + store P [s][t] (per-wave rows, no barrier needed)
#pragma unroll
    for (int nt = 0; nt < 4; nt++) {
      const int tcol = nt * 16 + l16;
      const float kv = kns[tcol];
#pragma unroll
      for (int r = 0; r < 4; r++) {
        const int srow = m16 + qd * 4 + r;
        const float e2 = fmaf(2.0f, accp[nt][r], -(qns[srow] + kv));
        const float val = __expf(fminf(e2, 0.0f) * cc);
        short hb, lb; kar_split_bf(val, hb, lb);
        Ph[srow * LDW + tcol] = hb;
        Pl[srow * LDW + tcol] = lb;
      }
    }
    // phase 2: acc += P @ alpha
#pragma unroll
    for (int kt = 0; kt < 2; kt++) {
      const int ko = kt * 32 + qd * 8;
      const bf16x8 pH = *(const bf16x8*)&Ph[(m16 + l16) * LDW + ko];
      const bf16x8 pL = *(const bf16x8*)&Pl[(m16 + l16) * LDW + ko];
#pragma unroll
      for (int dt = 0; dt < 4; dt++) {
        const bf16x8 bH = *(const bf16x8*)&Ah[(dt * 16 + l16) * LDW + ko];
        const bf16x8 bL = *(const bf16x8*)&Al[(dt * 16 + l16) * LDW + ko];
        acco[dt] = __builtin_amdgcn_mfma_f32_16x16x32_bf16(pH, bH, acco[dt], 0, 0, 0);
        acco[dt] = __builtin_amdgcn_mfma_f32_16x16x32_bf16(pL, bH, acco[dt], 0, 0, 0);
        acco[dt] = __builtin_amdgcn_mfma_f32_16x16x32_bf16(pH, bL, acco[dt], 0, 0, 0);
      }
    }
  }
  if (FINAL) {
#pragma unroll
    for (int dt = 0; dt < 4; dt++) {
#pragma unroll
      for (int r = 0; r < 4; r++) {
        const int s = s0 + m16 + qd * 4 + r;
        const int d = dt * 16 + l16;
        short hh, ll; kar_split_bf(acco[dt][r], hh, ll);
        tmph[(size_t)s * kD + h * kDH + d] = hh;
        tmpl[(size_t)s * kD + h * kDH + d] = ll;
      }
    }
  } else {
    const float lamf = (float)SC[1];
#pragma unroll
    for (int dt = 0; dt < 4; dt++) {
#pragma unroll
      for (int r = 0; r < 4; r++) {
        const int s = s0 + m16 + qd * 4 + r;
        const int d = dt * 16 + l16;
        const size_t eg = ((size_t)h * kS + s) * kDH + d;
        outp[eg] = v[eg] - (acco[dt][r] + lamf * alpha[eg]);
      }
    }
  }
}

// ================= OLD PATH (R4 fallback) kernels =================
__global__ __launch_bounds__(256) void kar_gemm_qkv_f32_kernel(
    const float* __restrict__ x,
    const float* __restrict__ Wq, const float* __restrict__ Wk, const float* __restrict__ Wv,
    float* __restrict__ q, float* __restrict__ k, float* __restrict__ v) {
  const float* W = (blockIdx.z == 0) ? Wq : (blockIdx.z == 1) ? Wk : Wv;
  float* outp    = (blockIdx.z == 0) ? q  : (blockIdx.z == 1) ? k  : v;
  const int n0 = blockIdx.x * 64;
  const int m0 = blockIdx.y * 64;
  const int tid = threadIdx.x;
  const int tx = tid & 15, ty = tid >> 4;
  __shared__ float As[16][68];
  __shared__ float Bs[16][68];
  double acc[4][4] = {};
  const int lr = tid >> 2;
  const int lk = (tid & 3) * 4;
  const int br = tid >> 4;
  const int bc = (tid & 15) * 4;
  for (int k0 = 0; k0 < kD; k0 += 16) {
    const float4 a4 = *(const float4*)&x[(size_t)(m0 + lr) * kD + k0 + lk];
    const float4 b4 = *(const float4*)&W[(size_t)(k0 + br) * kD + n0 + bc];
    __syncthreads();
    As[lk + 0][lr] = a4.x; As[lk + 1][lr] = a4.y;
    As[lk + 2][lr] = a4.z; As[lk + 3][lr] = a4.w;
    *(float4*)&Bs[br][bc] = b4;
    __syncthreads();
    float c32[4][4] = {};
#pragma unroll
    for (int kk = 0; kk < 16; kk++) {
      const float4 av = *(const float4*)&As[kk][ty * 4];
      const float4 bv = *(const float4*)&Bs[kk][tx * 4];
      const float a_[4] = {av.x, av.y, av.z, av.w};
      const float b_[4] = {bv.x, bv.y, bv.z, bv.w};
#pragma unroll
      for (int i = 0; i < 4; i++)
#pragma unroll
        for (int j = 0; j < 4; j++) c32[i][j] = fmaf(a_[i], b_[j], c32[i][j]);
    }
#pragma unroll
    for (int i = 0; i < 4; i++)
#pragma unroll
      for (int j = 0; j < 4; j++) acc[i][j] += (double)c32[i][j];
  }
  const int h = n0 >> 6;
#pragma unroll
  for (int i = 0; i < 4; i++) {
    const int s = m0 + ty * 4 + i;
    float4 o;
    o.x = (float)acc[i][0]; o.y = (float)acc[i][1];
    o.z = (float)acc[i][2]; o.w = (float)acc[i][3];
    *(float4*)&outp[((size_t)h * kS + s) * kDH + tx * 4] = o;
  }
}

__global__ __launch_bounds__(256) void kar_gemm_plain_kernel(
    const float* __restrict__ A, const float* __restrict__ W, float* __restrict__ C) {
  const int n0 = blockIdx.x * 64;
  const int m0 = blockIdx.y * 64;
  const int tid = threadIdx.x;
  const int tx = tid & 15, ty = tid >> 4;
  __shared__ float As[16][68];
  __shared__ float Bs[16][68];
  double acc[4][4] = {};
  const int lr = tid >> 2;
  const int lk = (tid & 3) * 4;
  const int br = tid >> 4;
  const int bc = (tid & 15) * 4;
  for (int k0 = 0; k0 < kD; k0 += 16) {
    const float4 a4 = *(const float4*)&A[(size_t)(m0 + lr) * kD + k0 + lk];
    const float4 b4 = *(const float4*)&W[(size_t)(k0 + br) * kD + n0 + bc];
    __syncthreads();
    As[lk + 0][lr] = a4.x; As[lk + 1][lr] = a4.y;
    As[lk + 2][lr] = a4.z; As[lk + 3][lr] = a4.w;
    *(float4*)&Bs[br][bc] = b4;
    __syncthreads();
    float c32[4][4] = {};
#pragma unroll
    for (int kk = 0; kk < 16; kk++) {
      const float4 av = *(const float4*)&As[kk][ty * 4];
      const float4 bv = *(const float4*)&Bs[kk][tx * 4];
      const float a_[4] = {av.x, av.y, av.z, av.w};
      const float b_[4] = {bv.x, bv.y, bv.z, bv.w};
#pragma unroll
      for (int i = 0; i < 4; i++)
#pragma unroll
        for (int j = 0; j < 4; j++) c32[i][j] = fmaf(a_[i], b_[j], c32[i][j]);
    }
#pragma unroll
    for (int i = 0; i < 4; i++)
#pragma unroll
      for (int j = 0; j < 4; j++) acc[i][j] += (double)c32[i][j];
  }
#pragma unroll
  for (int i = 0; i < 4; i++) {
    const int s = m0 + ty * 4 + i;
    float4 o;
    o.x = (float)acc[i][0]; o.y = (float)acc[i][1];
    o.z = (float)acc[i][2]; o.w = (float)acc[i][3];
    *(float4*)&C[(size_t)s * kD + n0 + tx * 4] = o;
  }
}

__global__ __launch_bounds__(256) void kar_norms_f32_kernel(const float* __restrict__ q,
                                                            const float* __restrict__ k,
                                                            double* __restrict__ qn,
                                                            double* __restrict__ kn) {
  int o = blockIdx.x * 256 + threadIdx.x;
  const float* src; double* dst; int p;
  if (o < kH * kS) { src = q; dst = qn; p = o; }
  else             { src = k; dst = kn; p = o - kH * kS; }
  const float* rowp = src + (size_t)p * kDH;
  double s = 0.0;
  for (int i = 0; i < kDH; i += 4) {
    float4 x4 = *(const float4*)&rowp[i];
    s += (double)x4.x * (double)x4.x + (double)x4.y * (double)x4.y +
         (double)x4.z * (double)x4.z + (double)x4.w * (double)x4.w;
  }
  dst[p] = s;
}

__global__ __launch_bounds__(256) void kar_diagp_f32_kernel(
    const float* __restrict__ q, const float* __restrict__ k,
    const double* __restrict__ qn, const double* __restrict__ kn,
    const double* __restrict__ SC, const float* __restrict__ dsc,
    const float* __restrict__ reg, double* __restrict__ dgp) {
  int o = blockIdx.x * 256 + threadIdx.x;
  int h = o >> 11;
  const float* qp = q + (size_t)o * kDH;
  const float* kp = k + (size_t)o * kDH;
  double dot = 0.0;
  for (int i = 0; i < kDH; i++) dot += (double)qp[i] * (double)kp[i];
  double dist = fmax(qn[o] + kn[o] - 2.0 * dot, 0.0);
  double Kss = exp(-dist * SC[0]);
  double sp  = log1p(exp(Kss));
  dgp[o] = sp * (double)dsc[h] + (double)reg[0];
}

template <bool FINAL>
__global__ __launch_bounds__(256, 2) void kar_mfma_iterA_kernel(
    const float* __restrict__ q, const float* __restrict__ k,
    const float* __restrict__ alpha, const float* __restrict__ v,
    const double* __restrict__ qn, const double* __restrict__ kn,
    const double* __restrict__ SC, float* __restrict__ outp) {
  constexpr int LDW = 72;
  __shared__ short Qh[64 * LDW], Ql[64 * LDW];
  __shared__ short Kh[64 * LDW], Kl[64 * LDW];
  __shared__ short Ph[64 * LDW], Pl[64 * LDW];
  __shared__ short Ah[64 * LDW], Al[64 * LDW];
  __shared__ float qns[64], kns[64];
  const int h   = blockIdx.y;
  const int s0  = blockIdx.x * 64;
  const int tid = threadIdx.x;
  const int lane = tid & 63;
  const int wv   = tid >> 6;
  const int l16  = lane & 15;
  const int qd   = lane >> 4;
  const int m16  = wv * 16;
  const float* qh = q + ((size_t)h * kS + s0) * kDH;
  const float* kh = k + (size_t)h * kS * kDH;
  const float* ah = alpha + (size_t)h * kS * kDH;
  {
    const int row = tid >> 4;
    const int c4  = (tid & 15) * 4;
#pragma unroll
    for (int rep = 0; rep < 4; rep++) {
      const int r = rep * 16 + row;
      const float4 a = *(const float4*)&qh[(size_t)r * kDH + c4];
      short h0, l0, h1, l1, h2, l2, h3, l3;
      kar_split_bf(a.x, h0, l0); kar_split_bf(a.y, h1, l1);
      kar_split_bf(a.z, h2, l2); kar_split_bf(a.w, h3, l3);
      *(short4*)&Qh[r * LDW + c4] = make_short4(h0, h1, h2, h3);
      *(short4*)&Ql[r * LDW + c4] = make_short4(l0, l1, l2, l3);
    }
    if (tid < 64) qns[tid] = (float)qn[h * kS + s0 + tid];
  }
  const float cc = (float)SC[0];
  f32x4 acco[4];
#pragma unroll
  for (int i = 0; i < 4; i++) acco[i] = (f32x4){0.f, 0.f, 0.f, 0.f};
  for (int t0 = 0; t0 < kS; t0 += 64) {
    __syncthreads();
    {
      const int row = tid >> 4;
      const int c4  = (tid & 15) * 4;
#pragma unroll
      for (int rep = 0; rep < 4; rep++) {
        const int r = rep * 16 + row;
        const float4 b = *(const float4*)&kh[(size_t)(t0 + r) * kDH + c4];
        short h0, l0, h1, l1, h2, l2, h3, l3;
        kar_split_bf(b.x, h0, l0); kar_split_bf(b.y, h1, l1);
        kar_split_bf(b.z, h2, l2); kar_split_bf(b.w, h3, l3);
        *(short4*)&Kh[r * LDW + c4] = make_short4(h0, h1, h2, h3);
        *(short4*)&Kl[r * LDW + c4] = make_short4(l0, l1, l2, l3);
        const float4 av = *(const float4*)&ah[(size_t)(t0 + r) * kDH + c4];
        kar_split_bf(av.x, h0, l0); kar_split_bf(av.y, h1, l1);
        kar_split_bf(av.z, h2, l2); kar_split_bf(av.w, h3, l3);
        Ah[(c4 + 0) * LDW + r] = h0; Al[(c4 + 0) * LDW + r] = l0;
        Ah[(c4 + 1) * LDW + r] = h1; Al[(c4 + 1) * LDW + r] = l1;
        Ah[(c4 + 2) * LDW + r] = h2; Al[(c4 + 2) * LDW + r] = l2;
        Ah[(c4 + 3) * LDW + r] = h3; Al[(c4 + 3) * LDW + r] = l3;
      }
      if (tid < 64) kns[tid] = (float)kn[h * kS + t0 + tid];
    }
    __syncthreads();
    f32x4 accp[4];
#pragma unroll
    for (int i = 0; i < 4; i++) accp[i] = (f32x4){0.f, 0.f, 0.f, 0.f};
#pragma unroll
    for (int kt = 0; kt < 2; kt++) {
      const int ko = kt * 32 + qd * 8;
      const bf16x8 aH = *(const bf16x8*)&Qh[(m16 + l16) * LDW + ko];
      const bf16x8 aL = *(const bf16x8*)&Ql[(m16 + l16) * LDW + ko];
#pragma unroll
      for (int nt = 0; nt < 4; nt++) {
        const bf16x8 bH = *(const bf16x8*)&Kh[(nt * 16 + l16) * LDW + ko];
        const bf16x8 bL = *(const bf16x8*)&Kl[(nt * 16 + l16) * LDW + ko];
        accp[nt] = __builtin_amdgcn_mfma_f32_16x16x32_bf16(aH, bH, accp[nt], 0, 0, 0);
        accp[nt] = __builtin_amdgcn_mfma_f32_16x16x32_bf16(aL, bH, accp[nt], 0, 0, 0);
        accp[nt] = __builtin_amdgcn_mfma_f32_16x16x32_bf16(aH, bL, accp[nt], 0, 0, 0);
      }
    }
#pragma unroll
    for (int nt = 0; nt < 4; nt++) {
      const int tcol = nt * 16 + l16;
      const float kv = kns[tcol];
#pragma unroll
      for (int r = 0; r < 4; r++) {
        const int srow = m16 + qd * 4 + r;
        const float e2 = fmaf(2.0f, accp[nt][r], -(qns[srow] + kv));
        const float val = __expf(fminf(e2, 0.0f) * cc);
        short hb, lb; kar_split_bf(val, hb, lb);
        Ph[srow * LDW + tcol] = hb;
        Pl[srow * LDW + tcol] = lb;
      }
    }
#pragma unroll
    for (int kt = 0; kt < 2; kt++) {
      const int ko = kt * 32 + qd * 8;
      const bf16x8 pH = *(const bf16x8*)&Ph[(m16 + l16) * LDW + ko];
      const bf16x8 pL = *(const bf16x8*)&Pl[(m16 + l16) * LDW + ko];
#pragma unroll
      for (int dt = 0; dt < 4; dt++) {
        const bf16x8 bH = *(const bf16x8*)&Ah[(dt * 16 + l16) * LDW + ko];
        const bf16x8 bL = *(const bf16x8*)&Al[(dt * 16 + l16) * LDW + ko];
        acco[dt] = __builtin_amdgcn_mfma_f32_16x16x32_bf16(pH, bH, acco[dt], 0, 0, 0);
        acco[dt] = __builtin_amdgcn_mfma_f32_16x16x32_bf16(pL, bH, acco[dt], 0, 0, 0);
        acco[dt] = __builtin_amdgcn_mfma_f32_16x16x32_bf16(pH, bL, acco[dt], 0, 0, 0);
      }
    }
  }
  if (FINAL) {
#pragma unroll
    for (int dt = 0; dt < 4; dt++) {
#pragma unroll
      for (int r = 0; r < 4; r++) {
        const int s = s0 + m16 + qd * 4 + r;
        const int d = dt * 16 + l16;
        outp[(size_t)s * kD + h * kDH + d] = acco[dt][r];
      }
    }
  } else {
    const float lamf = (float)SC[1];
#pragma unroll
    for (int dt = 0; dt < 4; dt++) {
#pragma unroll
      for (int r = 0; r < 4; r++) {
        const int s = s0 + m16 + qd * 4 + r;
        const int d = dt * 16 + l16;
        const size_t eg = ((size_t)h * kS + s) * kDH + d;
        outp[eg] = v[eg] - (acco[dt][r] + lamf * alpha[eg]);
      }
    }
  }
}

extern "C" void kernel_launch(void* const* d_in, const int* in_sizes, int n_in,
                              void* d_out, int out_size, void* d_ws, size_t ws_size,
                              hipStream_t stream) {
  (void)in_sizes; (void)n_in; (void)out_size;
  const float* x    = (const float*)d_in[0];
  const float* Wq   = (const float*)d_in[1];
  const float* Wk   = (const float*)d_in[2];
  const float* Wv   = (const float*)d_in[3];
  const float* Wo   = (const float*)d_in[4];
  const float* bw   = (const float*)d_in[5];
  const float* dsc  = (const float*)d_in[6];
  const float* pe   = (const float*)d_in[7];
  const float* hp   = (const float*)d_in[8];
  const float* reg  = (const float*)d_in[9];
  const float* lreg = (const float*)d_in[10];
  float* out = (float*)d_out;

  char* w = (char*)d_ws;
  size_t off = 0;
  auto take = [&](size_t bytes) -> void* {
    void* p = w + off;
    off += (bytes + 255) & ~(size_t)255;
    return p;
  };
  const size_t HSD = (size_t)kH * kS * kDH;  // 2M elements

  // ---- new-path layout ----
  float*  v_    = (float*)take(HSD * 4);
  float*  alpha = (float*)take(HSD * 4);
  float*  rbuf  = (float*)take(HSD * 4);
  short*  qsh   = (short*)take(HSD * 2);
  short*  qsl   = (short*)take(HSD * 2);
  short*  ksh   = (short*)take(HSD * 2);
  short*  ksl   = (short*)take(HSD * 2);
  short*  ath   = (short*)take(HSD * 2);
  short*  atl   = (short*)take(HSD * 2);
  short*  xh    = (short*)take((size_t)kS * kD * 2);  // reused as tmph
  short*  xl    = (short*)take((size_t)kS * kD * 2);  // reused as tmpl
  short*  WTh   = (short*)take((size_t)4 * kD * kD * 2);
  short*  WTl   = (short*)take((size_t)4 * kD * kD * 2);
  double* qn    = (double*)take((size_t)kH * kS * 8);
  double* kn    = (double*)take((size_t)kH * kS * 8);
  double* dgp   = (double*)take((size_t)kH * kS * 8);
  float*  U     = (float*)take((size_t)kH * kS * kR * 4);
  double* utr   = (double*)take((size_t)kH * kR * kDH * 8);
  double* utrp  = (double*)take((size_t)kH * 16 * kR * kDH * 8);
  double* SC    = (double*)take(256);
  const size_t need_new = off;

  if (ws_size >= need_new) {
    // ================= NEW PATH =================
    kar_scalars_kernel<<<1, 64, 0, stream>>>(bw, lreg, SC);
    kar_xsplit_kernel<<<2048, 256, 0, stream>>>(x, xh, xl);
    kar_wsplit_kernel<<<dim3(16, 16, 4), 256, 0, stream>>>(Wq, Wk, Wv, Wo, WTh, WTl);
    kar_mfma_gemm_qkv_kernel<<<dim3(16, 16, 3), 256, 0, stream>>>(
        xh, xl, WTh, WTl, v_, qsh, qsl, ksh, ksl);
    kar_norms2_kernel<<<256, 256, 0, stream>>>(qsh, qsl, ksh, ksl, qn, kn);
    kar_u_kernel<<<2048, 256, 0, stream>>>(pe, hp, U);
    kar_diagp2_kernel<<<128, 256, 0, stream>>>(qsh, qsl, ksh, ksl, qn, kn, SC, dsc, reg, dgp);

    // it 0: alpha == 0 -> r == v
    kar_utr_partial_kernel<<<dim3(16, kH), 256, 0, stream>>>(U, v_, utrp);
    kar_utr_reduce_kernel<<<64, 256, 0, stream>>>(utrp, utr);
    kar_update_kernel<<<8192, 256, 0, stream>>>(v_, dgp, U, utr, alpha, 1);

    for (int it = 1; it < 5; it++) {
      kar_asplit_kernel<<<dim3(32, kH), 256, 0, stream>>>(alpha, ath, atl);
      kar_mfma_iter2_kernel<false><<<dim3(32, kH), 256, 0, stream>>>(
          qsh, qsl, ksh, ksl, ath, atl, alpha, v_, qn, kn, SC, rbuf, nullptr, nullptr);
      kar_utr_partial_kernel<<<dim3(16, kH), 256, 0, stream>>>(U, rbuf, utrp);
      kar_utr_reduce_kernel<<<64, 256, 0, stream>>>(utrp, utr);
      kar_update_kernel<<<8192, 256, 0, stream>>>(rbuf, dgp, U, utr, alpha, 0);
    }

    kar_asplit_kernel<<<dim3(32, kH), 256, 0, stream>>>(alpha, ath, atl);
    kar_mfma_iter2_kernel<true><<<dim3(32, kH), 256, 0, stream>>>(
        qsh, qsl, ksh, ksl, ath, atl, alpha, v_, qn, kn, SC, rbuf, xh, xl);  // xh/xl = tmph/tmpl
    kar_mfma_gemm_wo_kernel<<<dim3(16, 16), 256, 0, stream>>>(
        xh, xl, WTh + (size_t)3 * kD * kD, WTl + (size_t)3 * kD * kD, out);
  } else {
    // ================= OLD PATH (R4) =================
    size_t off2 = 0;
    auto take2 = [&](size_t bytes) -> void* {
      void* p = w + off2;
      off2 += (bytes + 255) & ~(size_t)255;
      return p;
    };
    float*  q2    = (float*)take2(HSD * 4);
    float*  k2    = (float*)take2(HSD * 4);
    float*  v2    = (float*)take2(HSD * 4);
    float*  al2   = (float*)take2(HSD * 4);
    float*  rb2   = (float*)take2(HSD * 4);
    float*  tmp2  = (float*)take2((size_t)kS * kD * 4);
    double* qn2   = (double*)take2((size_t)kH * kS * 8);
    double* kn2   = (double*)take2((size_t)kH * kS * 8);
    double* dgp2  = (double*)take2((size_t)kH * kS * 8);
    float*  U2    = (float*)take2((size_t)kH * kS * kR * 4);
    double* utr2  = (double*)take2((size_t)kH * kR * kDH * 8);
    double* utrp2 = (double*)take2((size_t)kH * 16 * kR * kDH * 8);
    double* SC2   = (double*)take2(256);

    kar_scalars_kernel<<<1, 64, 0, stream>>>(bw, lreg, SC2);
    kar_gemm_qkv_f32_kernel<<<dim3(16, 32, 3), 256, 0, stream>>>(x, Wq, Wk, Wv, q2, k2, v2);
    kar_norms_f32_kernel<<<256, 256, 0, stream>>>(q2, k2, qn2, kn2);
    kar_u_kernel<<<2048, 256, 0, stream>>>(pe, hp, U2);
    kar_diagp_f32_kernel<<<128, 256, 0, stream>>>(q2, k2, qn2, kn2, SC2, dsc, reg, dgp2);

    kar_utr_partial_kernel<<<dim3(16, kH), 256, 0, stream>>>(U2, v2, utrp2);
    kar_utr_reduce_kernel<<<64, 256, 0, stream>>>(utrp2, utr2);
    kar_update_kernel<<<8192, 256, 0, stream>>>(v2, dgp2, U2, utr2, al2, 1);

    for (int it = 1; it < 5; it++) {
      kar_mfma_iterA_kernel<false><<<dim3(32, kH), 256, 0, stream>>>(
          q2, k2, al2, v2, qn2, kn2, SC2, rb2);
      kar_utr_partial_kernel<<<dim3(16, kH), 256, 0, stream>>>(U2, rb2, utrp2);
      kar_utr_reduce_kernel<<<64, 256, 0, stream>>>(utrp2, utr2);
      kar_update_kernel<<<8192, 256, 0, stream>>>(rb2, dgp2, U2, utr2, al2, 0);
    }
    kar_mfma_iterA_kernel<true><<<dim3(32, kH), 256, 0, stream>>>(
        q2, k2, al2, v2, qn2, kn2, SC2, tmp2);
    kar_gemm_plain_kernel<<<dim3(16, 32), 256, 0, stream>>>(tmp2, Wo, out);
  }
}

// Round 7
// 788.181 us; speedup vs baseline: 3.0990x; 1.1137x over previous
//
#include <hip/hip_runtime.h>
#include <cstdint>
#include <cstddef>

constexpr int kS  = 2048;
constexpr int kD  = 1024;
constexpr int kH  = 16;
constexpr int kDH = 64;
constexpr int kR  = 16;

typedef __attribute__((ext_vector_type(8))) short bf16x8;
typedef __attribute__((ext_vector_type(4))) float f32x4;

__device__ __forceinline__ unsigned short kar_f2bf(float x) {
  unsigned u = __float_as_uint(x);
  return (unsigned short)((u + 0x7FFFu + ((u >> 16) & 1u)) >> 16);
}
__device__ __forceinline__ float kar_bf2f(short h) {
  return __uint_as_float((unsigned)(unsigned short)h << 16);
}
__device__ __forceinline__ void kar_split_bf(float x, short& hi, short& lo) {
  unsigned short h = kar_f2bf(x);
  float hf = __uint_as_float((unsigned)h << 16);
  hi = (short)h;
  lo = (short)kar_f2bf(x - hf);
}

// ---------------- scalars ----------------
__global__ __launch_bounds__(64) void kar_scalars_kernel(const float* __restrict__ bw,
                                                         const float* __restrict__ lreg,
                                                         double* __restrict__ SC) {
  if (threadIdx.x == 0) {
    double b = log1p(exp((double)bw[0])) + 1e-6;
    SC[0] = 1.0 / (2.0 * b * b);
    SC[1] = log1p(exp((double)lreg[0]));
  }
}

// ---------------- U[h][s][p] ----------------
__global__ __launch_bounds__(256) void kar_u_kernel(const float* __restrict__ pe,
                                                    const float* __restrict__ hp,
                                                    float* __restrict__ U) {
  int o = blockIdx.x * 256 + threadIdx.x;
  int r = o & 15, s = (o >> 4) & 2047, h = o >> 15;
  double acc = 0.0;
#pragma unroll
  for (int rp = 0; rp < kR; rp++)
    acc += (double)pe[s * kR + rp] * (double)hp[((h * kR) + rp) * kR + r];
  U[o] = (float)acc;
}

// ---------------- ut_r partials / reduce / update ----------------
__global__ __launch_bounds__(256) void kar_utr_partial_kernel(
    const float* __restrict__ Ubuf, const float* __restrict__ rbuf,
    double* __restrict__ utrp) {
  const int h  = blockIdx.y;
  const int sb = blockIdx.x * 128;
  const int t  = threadIdx.x;
  __shared__ float Uch[32][16];
  __shared__ float Rch[32][64];
  double acc[4] = {};
  for (int cs = 0; cs < 128; cs += 32) {
    __syncthreads();
    if (t < 128) {
      const int i = t >> 2, f = (t & 3) * 4;
      *(float4*)&Uch[i][f] = *(const float4*)&Ubuf[((size_t)(h * kS) + sb + cs + i) * kR + f];
    }
#pragma unroll
    for (int rep = 0; rep < 2; rep++) {
      const int e = t + rep * 256;
      const int i = e >> 4, c = (e & 15) * 4;
      *(float4*)&Rch[i][c] = *(const float4*)&rbuf[((size_t)(h * kS) + sb + cs + i) * kDH + c];
    }
    __syncthreads();
    for (int i = 0; i < 32; i++) {
#pragma unroll
      for (int rep = 0; rep < 4; rep++) {
        const int p = t + rep * 256;
        const int r = p >> 6, d = p & 63;
        acc[rep] += (double)Uch[i][r] * (double)Rch[i][d];
      }
    }
  }
#pragma unroll
  for (int rep = 0; rep < 4; rep++) {
    const int p = t + rep * 256;
    const int r = p >> 6, d = p & 63;
    utrp[(((size_t)(h * 16) + blockIdx.x) * kR + r) * kDH + d] = acc[rep];
  }
}

__global__ __launch_bounds__(256) void kar_utr_reduce_kernel(const double* __restrict__ utrp,
                                                             double* __restrict__ utr) {
  int o = blockIdx.x * 256 + threadIdx.x;
  int h = o >> 10, rd = o & 1023;
  double s = 0.0;
#pragma unroll
  for (int j = 0; j < 16; j++) s += utrp[(size_t)h * 16384 + (size_t)j * 1024 + rd];
  utr[o] = s;
}

__global__ __launch_bounds__(256) void kar_update_kernel(
    const float* __restrict__ rsrc, const double* __restrict__ dgp,
    const float* __restrict__ Ubuf, const double* __restrict__ utr,
    float* __restrict__ alpha, int first) {
  int e = blockIdx.x * 256 + threadIdx.x;
  const int d = e & 63;
  const int s = (e >> 6) & 2047;
  const int h = e >> 17;
  const double rv = (double)rsrc[e];
  const double dp = dgp[h * kS + s];
  const float*  Us = &Ubuf[((size_t)(h * kS) + s) * kR];
  const double* uh = &utr[(size_t)h * kR * kDH];
  double sum = 0.0;
#pragma unroll
  for (int ri = 0; ri < kR; ri++) sum += (double)Us[ri] * uh[ri * kDH + d];
  const double p = rv * dp + sum;
  const double an = (first ? 0.0 : (double)alpha[e]) + p;
  alpha[e] = (float)an;
}

// ================= NEW PATH kernels =================

__global__ __launch_bounds__(256) void kar_xsplit_kernel(const float* __restrict__ x,
                                                         short* __restrict__ xh,
                                                         short* __restrict__ xl) {
  size_t e = ((size_t)blockIdx.x * 256 + threadIdx.x) * 4;
  float4 a = *(const float4*)&x[e];
  short h0, l0, h1, l1, h2, l2, h3, l3;
  kar_split_bf(a.x, h0, l0); kar_split_bf(a.y, h1, l1);
  kar_split_bf(a.z, h2, l2); kar_split_bf(a.w, h3, l3);
  *(short4*)&xh[e] = make_short4(h0, h1, h2, h3);
  *(short4*)&xl[e] = make_short4(l0, l1, l2, l3);
}

__global__ __launch_bounds__(256) void kar_wsplit_kernel(
    const float* __restrict__ Wq, const float* __restrict__ Wk,
    const float* __restrict__ Wv, const float* __restrict__ Wo,
    short* __restrict__ WTh, short* __restrict__ WTl) {
  const float* W = (blockIdx.z == 0) ? Wq : (blockIdx.z == 1) ? Wk
                 : (blockIdx.z == 2) ? Wv : Wo;
  short* oh = WTh + (size_t)blockIdx.z * kD * kD;
  short* ol = WTl + (size_t)blockIdx.z * kD * kD;
  const int n0 = blockIdx.x * 64, k0 = blockIdx.y * 64;
  __shared__ float T[64][65];
  const int t = threadIdx.x;
  const int r16 = t >> 4, c4 = (t & 15) * 4;
#pragma unroll
  for (int it = 0; it < 4; it++) {
    int r = it * 16 + r16;
    float4 a = *(const float4*)&W[(size_t)(k0 + r) * kD + n0 + c4];
    T[r][c4] = a.x; T[r][c4 + 1] = a.y; T[r][c4 + 2] = a.z; T[r][c4 + 3] = a.w;
  }
  __syncthreads();
#pragma unroll
  for (int it = 0; it < 4; it++) {
    int n = it * 16 + r16;
    float v0 = T[c4][n], v1 = T[c4 + 1][n], v2 = T[c4 + 2][n], v3 = T[c4 + 3][n];
    short h0, l0, h1, l1, h2, l2, h3, l3;
    kar_split_bf(v0, h0, l0); kar_split_bf(v1, h1, l1);
    kar_split_bf(v2, h2, l2); kar_split_bf(v3, h3, l3);
    *(short4*)&oh[(size_t)(n0 + n) * kD + k0 + c4] = make_short4(h0, h1, h2, h3);
    *(short4*)&ol[(size_t)(n0 + n) * kD + k0 + c4] = make_short4(l0, l1, l2, l3);
  }
}

__global__ __launch_bounds__(256) void kar_asplit_kernel(const float* __restrict__ alpha,
                                                         short* __restrict__ ath,
                                                         short* __restrict__ atl) {
  const int h = blockIdx.y, s0 = blockIdx.x * 64;
  __shared__ float T[64][65];
  const int t = threadIdx.x;
  const int r16 = t >> 4, c4 = (t & 15) * 4;
#pragma unroll
  for (int it = 0; it < 4; it++) {
    int r = it * 16 + r16;
    float4 a = *(const float4*)&alpha[(((size_t)h * kS) + s0 + r) * kDH + c4];
    T[r][c4] = a.x; T[r][c4 + 1] = a.y; T[r][c4 + 2] = a.z; T[r][c4 + 3] = a.w;
  }
  __syncthreads();
#pragma unroll
  for (int it = 0; it < 4; it++) {
    int d = it * 16 + r16;
    float v0 = T[c4][d], v1 = T[c4 + 1][d], v2 = T[c4 + 2][d], v3 = T[c4 + 3][d];
    short h0, l0, h1, l1, h2, l2, h3, l3;
    kar_split_bf(v0, h0, l0); kar_split_bf(v1, h1, l1);
    kar_split_bf(v2, h2, l2); kar_split_bf(v3, h3, l3);
    *(short4*)&ath[((size_t)h * kDH + d) * kS + s0 + c4] = make_short4(h0, h1, h2, h3);
    *(short4*)&atl[((size_t)h * kDH + d) * kS + s0 + c4] = make_short4(l0, l1, l2, l3);
  }
}

// MFMA split-bf16 GEMM: QKV. z=0,1: split dumps q/k; z=2: v fp32.
__global__ __launch_bounds__(256) void kar_mfma_gemm_qkv_kernel(
    const short* __restrict__ xh, const short* __restrict__ xl,
    const short* __restrict__ WTh, const short* __restrict__ WTl,
    float* __restrict__ v,
    short* __restrict__ qsh, short* __restrict__ qsl,
    short* __restrict__ ksh, short* __restrict__ ksl) {
  const int z = blockIdx.z;
  const short* Bh = WTh + (size_t)z * kD * kD;
  const short* Bl = WTl + (size_t)z * kD * kD;
  const int n0 = blockIdx.x * 64;
  const int m0 = blockIdx.y * 128;
  constexpr int LW = 40;
  __shared__ short Xh[128 * LW], Xl[128 * LW], Wh[64 * LW], Wl[64 * LW];
  const int t = threadIdx.x, lane = t & 63, wv = t >> 6;
  const int wm = wv >> 1, wn = wv & 1, l16 = lane & 15, qd = lane >> 4;
  f32x4 acc[4][2];
#pragma unroll
  for (int i = 0; i < 4; i++)
#pragma unroll
    for (int j = 0; j < 2; j++) acc[i][j] = (f32x4){0.f, 0.f, 0.f, 0.f};
  const int xrow = t >> 1, xc = (t & 1) * 16;
  for (int k0 = 0; k0 < kD; k0 += 32) {
    __syncthreads();
    {
      const size_t xs = (size_t)(m0 + xrow) * kD + k0 + xc;
      *(bf16x8*)&Xh[xrow * LW + xc]     = *(const bf16x8*)&xh[xs];
      *(bf16x8*)&Xh[xrow * LW + xc + 8] = *(const bf16x8*)&xh[xs + 8];
      *(bf16x8*)&Xl[xrow * LW + xc]     = *(const bf16x8*)&xl[xs];
      *(bf16x8*)&Xl[xrow * LW + xc + 8] = *(const bf16x8*)&xl[xs + 8];
    }
    if (t < 128) {
      const int wrow = t >> 1, wc = (t & 1) * 16;
      const size_t wsrc = (size_t)(n0 + wrow) * kD + k0 + wc;
      *(bf16x8*)&Wh[wrow * LW + wc]     = *(const bf16x8*)&Bh[wsrc];
      *(bf16x8*)&Wh[wrow * LW + wc + 8] = *(const bf16x8*)&Bh[wsrc + 8];
    } else {
      const int t2 = t - 128, wrow = t2 >> 1, wc = (t2 & 1) * 16;
      const size_t wsrc = (size_t)(n0 + wrow) * kD + k0 + wc;
      *(bf16x8*)&Wl[wrow * LW + wc]     = *(const bf16x8*)&Bl[wsrc];
      *(bf16x8*)&Wl[wrow * LW + wc + 8] = *(const bf16x8*)&Bl[wsrc + 8];
    }
    __syncthreads();
    bf16x8 bH[2], bL[2];
#pragma unroll
    for (int ni = 0; ni < 2; ni++) {
      const int rn = wn * 32 + ni * 16 + l16;
      bH[ni] = *(const bf16x8*)&Wh[rn * LW + qd * 8];
      bL[ni] = *(const bf16x8*)&Wl[rn * LW + qd * 8];
    }
#pragma unroll
    for (int mi = 0; mi < 4; mi++) {
      const int rm = wm * 64 + mi * 16 + l16;
      const bf16x8 aH = *(const bf16x8*)&Xh[rm * LW + qd * 8];
      const bf16x8 aL = *(const bf16x8*)&Xl[rm * LW + qd * 8];
#pragma unroll
      for (int ni = 0; ni < 2; ni++) {
        acc[mi][ni] = __builtin_amdgcn_mfma_f32_16x16x32_bf16(aH, bH[ni], acc[mi][ni], 0, 0, 0);
        acc[mi][ni] = __builtin_amdgcn_mfma_f32_16x16x32_bf16(aL, bH[ni], acc[mi][ni], 0, 0, 0);
        acc[mi][ni] = __builtin_amdgcn_mfma_f32_16x16x32_bf16(aH, bL[ni], acc[mi][ni], 0, 0, 0);
      }
    }
  }
  const int h = blockIdx.x;
#pragma unroll
  for (int mi = 0; mi < 4; mi++)
#pragma unroll
    for (int ni = 0; ni < 2; ni++) {
      const int d = wn * 32 + ni * 16 + l16;
#pragma unroll
      for (int r = 0; r < 4; r++) {
        const int s = m0 + wm * 64 + mi * 16 + qd * 4 + r;
        const float val = acc[mi][ni][r];
        const size_t idx = (((size_t)h * kS) + s) * kDH + d;
        if (z == 2) {
          v[idx] = val;
        } else {
          short hh, ll; kar_split_bf(val, hh, ll);
          if (z == 0) { qsh[idx] = hh; qsl[idx] = ll; }
          else        { ksh[idx] = hh; ksl[idx] = ll; }
        }
      }
    }
}

// MFMA split-bf16 GEMM: out = tmp @ Wo
__global__ __launch_bounds__(256) void kar_mfma_gemm_wo_kernel(
    const short* __restrict__ th, const short* __restrict__ tl,
    const short* __restrict__ Bh, const short* __restrict__ Bl,
    float* __restrict__ outp) {
  const int n0 = blockIdx.x * 64;
  const int m0 = blockIdx.y * 128;
  constexpr int LW = 40;
  __shared__ short Xh[128 * LW], Xl[128 * LW], Wh[64 * LW], Wl[64 * LW];
  const int t = threadIdx.x, lane = t & 63, wv = t >> 6;
  const int wm = wv >> 1, wn = wv & 1, l16 = lane & 15, qd = lane >> 4;
  f32x4 acc[4][2];
#pragma unroll
  for (int i = 0; i < 4; i++)
#pragma unroll
    for (int j = 0; j < 2; j++) acc[i][j] = (f32x4){0.f, 0.f, 0.f, 0.f};
  const int xrow = t >> 1, xc = (t & 1) * 16;
  for (int k0 = 0; k0 < kD; k0 += 32) {
    __syncthreads();
    {
      const size_t xs = (size_t)(m0 + xrow) * kD + k0 + xc;
      *(bf16x8*)&Xh[xrow * LW + xc]     = *(const bf16x8*)&th[xs];
      *(bf16x8*)&Xh[xrow * LW + xc + 8] = *(const bf16x8*)&th[xs + 8];
      *(bf16x8*)&Xl[xrow * LW + xc]     = *(const bf16x8*)&tl[xs];
      *(bf16x8*)&Xl[xrow * LW + xc + 8] = *(const bf16x8*)&tl[xs + 8];
    }
    if (t < 128) {
      const int wrow = t >> 1, wc = (t & 1) * 16;
      const size_t wsrc = (size_t)(n0 + wrow) * kD + k0 + wc;
      *(bf16x8*)&Wh[wrow * LW + wc]     = *(const bf16x8*)&Bh[wsrc];
      *(bf16x8*)&Wh[wrow * LW + wc + 8] = *(const bf16x8*)&Bh[wsrc + 8];
    } else {
      const int t2 = t - 128, wrow = t2 >> 1, wc = (t2 & 1) * 16;
      const size_t wsrc = (size_t)(n0 + wrow) * kD + k0 + wc;
      *(bf16x8*)&Wl[wrow * LW + wc]     = *(const bf16x8*)&Bl[wsrc];
      *(bf16x8*)&Wl[wrow * LW + wc + 8] = *(const bf16x8*)&Bl[wsrc + 8];
    }
    __syncthreads();
    bf16x8 bH[2], bL[2];
#pragma unroll
    for (int ni = 0; ni < 2; ni++) {
      const int rn = wn * 32 + ni * 16 + l16;
      bH[ni] = *(const bf16x8*)&Wh[rn * LW + qd * 8];
      bL[ni] = *(const bf16x8*)&Wl[rn * LW + qd * 8];
    }
#pragma unroll
    for (int mi = 0; mi < 4; mi++) {
      const int rm = wm * 64 + mi * 16 + l16;
      const bf16x8 aH = *(const bf16x8*)&Xh[rm * LW + qd * 8];
      const bf16x8 aL = *(const bf16x8*)&Xl[rm * LW + qd * 8];
#pragma unroll
      for (int ni = 0; ni < 2; ni++) {
        acc[mi][ni] = __builtin_amdgcn_mfma_f32_16x16x32_bf16(aH, bH[ni], acc[mi][ni], 0, 0, 0);
        acc[mi][ni] = __builtin_amdgcn_mfma_f32_16x16x32_bf16(aL, bH[ni], acc[mi][ni], 0, 0, 0);
        acc[mi][ni] = __builtin_amdgcn_mfma_f32_16x16x32_bf16(aH, bL[ni], acc[mi][ni], 0, 0, 0);
      }
    }
  }
#pragma unroll
  for (int mi = 0; mi < 4; mi++)
#pragma unroll
    for (int ni = 0; ni < 2; ni++) {
      const int col = n0 + wn * 32 + ni * 16 + l16;
#pragma unroll
      for (int r = 0; r < 4; r++) {
        const int s = m0 + wm * 64 + mi * 16 + qd * 4 + r;
        outp[(size_t)s * kD + col] = acc[mi][ni][r];
      }
    }
}

// norms from splits
__global__ __launch_bounds__(256) void kar_norms2_kernel(
    const short* __restrict__ qsh, const short* __restrict__ qsl,
    const short* __restrict__ ksh, const short* __restrict__ ksl,
    double* __restrict__ qn, double* __restrict__ kn) {
  int o = blockIdx.x * 256 + threadIdx.x;
  const short *sh, *sl; double* dst; int p;
  if (o < kH * kS) { sh = qsh; sl = qsl; dst = qn; p = o; }
  else             { sh = ksh; sl = ksl; dst = kn; p = o - kH * kS; }
  const short* rh = sh + (size_t)p * kDH;
  const short* rl = sl + (size_t)p * kDH;
  double s = 0.0;
  for (int i = 0; i < kDH; i += 4) {
    short4 a = *(const short4*)&rh[i];
    short4 b = *(const short4*)&rl[i];
    double e0 = (double)kar_bf2f(a.x) + (double)kar_bf2f(b.x);
    double e1 = (double)kar_bf2f(a.y) + (double)kar_bf2f(b.y);
    double e2 = (double)kar_bf2f(a.z) + (double)kar_bf2f(b.z);
    double e3 = (double)kar_bf2f(a.w) + (double)kar_bf2f(b.w);
    s += e0 * e0 + e1 * e1 + e2 * e2 + e3 * e3;
  }
  dst[p] = s;
}

// diag_p from splits
__global__ __launch_bounds__(256) void kar_diagp2_kernel(
    const short* __restrict__ qsh, const short* __restrict__ qsl,
    const short* __restrict__ ksh, const short* __restrict__ ksl,
    const double* __restrict__ qn, const double* __restrict__ kn,
    const double* __restrict__ SC, const float* __restrict__ dsc,
    const float* __restrict__ reg, double* __restrict__ dgp) {
  int o = blockIdx.x * 256 + threadIdx.x;
  int h = o >> 11;
  const short* qh = qsh + (size_t)o * kDH;
  const short* ql = qsl + (size_t)o * kDH;
  const short* kh = ksh + (size_t)o * kDH;
  const short* kl = ksl + (size_t)o * kDH;
  double dot = 0.0;
  for (int i = 0; i < kDH; i++) {
    double qi = (double)kar_bf2f(qh[i]) + (double)kar_bf2f(ql[i]);
    double ki = (double)kar_bf2f(kh[i]) + (double)kar_bf2f(kl[i]);
    dot += qi * ki;
  }
  double dist = fmax(qn[o] + kn[o] - 2.0 * dot, 0.0);
  double Kss = exp(-dist * SC[0]);
  double sp  = log1p(exp(Kss));
  dgp[o] = sp * (double)dsc[h] + (double)reg[0];
}

// fused K-apply v3: Q-frags in registers, P hi-only, 46KB LDS -> 3 blocks/CU
template <bool FINAL>
__global__ __launch_bounds__(256, 3) void kar_mfma_iter3_kernel(
    const short* __restrict__ qsh, const short* __restrict__ qsl,
    const short* __restrict__ ksh, const short* __restrict__ ksl,
    const short* __restrict__ ath, const short* __restrict__ atl,
    const float* __restrict__ alpha, const float* __restrict__ v,
    const double* __restrict__ qn, const double* __restrict__ kn,
    const double* __restrict__ SC, float* __restrict__ outp,
    short* __restrict__ tmph, short* __restrict__ tmpl) {
  constexpr int LDW = 72;
  __shared__ short Kh[64 * LDW], Kl[64 * LDW];
  __shared__ short Ah[64 * LDW], Al[64 * LDW];
  __shared__ short Ph[64 * LDW];
  __shared__ float kns[64];
  const int h   = blockIdx.y;
  const int s0  = blockIdx.x * 64;
  const int tid = threadIdx.x;
  const int lane = tid & 63;
  const int wv   = tid >> 6;
  const int l16  = lane & 15;
  const int qd   = lane >> 4;
  const int m16  = wv * 16;
  const int row = tid >> 2, c8 = (tid & 3) * 16;
  // Q fragments in registers (one-time global load)
  bf16x8 qH[2], qL[2];
  {
    const size_t qb = (((size_t)h * kS) + s0 + m16 + l16) * kDH;
    qH[0] = *(const bf16x8*)&qsh[qb + qd * 8];
    qH[1] = *(const bf16x8*)&qsh[qb + 32 + qd * 8];
    qL[0] = *(const bf16x8*)&qsl[qb + qd * 8];
    qL[1] = *(const bf16x8*)&qsl[qb + 32 + qd * 8];
  }
  float qns_r[4];
#pragma unroll
  for (int r = 0; r < 4; r++)
    qns_r[r] = (float)qn[h * kS + s0 + m16 + qd * 4 + r];
  const float cc = (float)SC[0];
  f32x4 acco[4];
#pragma unroll
  for (int i = 0; i < 4; i++) acco[i] = (f32x4){0.f, 0.f, 0.f, 0.f};

  for (int t0 = 0; t0 < kS; t0 += 64) {
    __syncthreads();
    {
      const size_t ksrc = (((size_t)h * kS) + t0 + row) * kDH;
      *(bf16x8*)&Kh[row * LDW + c8]     = *(const bf16x8*)&ksh[ksrc + c8];
      *(bf16x8*)&Kh[row * LDW + c8 + 8] = *(const bf16x8*)&ksh[ksrc + c8 + 8];
      *(bf16x8*)&Kl[row * LDW + c8]     = *(const bf16x8*)&ksl[ksrc + c8];
      *(bf16x8*)&Kl[row * LDW + c8 + 8] = *(const bf16x8*)&ksl[ksrc + c8 + 8];
      const size_t asrc = ((size_t)h * kDH + row) * kS + t0;
      *(bf16x8*)&Ah[row * LDW + c8]     = *(const bf16x8*)&ath[asrc + c8];
      *(bf16x8*)&Ah[row * LDW + c8 + 8] = *(const bf16x8*)&ath[asrc + c8 + 8];
      *(bf16x8*)&Al[row * LDW + c8]     = *(const bf16x8*)&atl[asrc + c8];
      *(bf16x8*)&Al[row * LDW + c8 + 8] = *(const bf16x8*)&atl[asrc + c8 + 8];
    }
    if (tid < 64) kns[tid] = (float)kn[h * kS + t0 + tid];
    __syncthreads();
    // phase 1: QK^T (Q from registers)
    f32x4 accp[4];
#pragma unroll
    for (int i = 0; i < 4; i++) accp[i] = (f32x4){0.f, 0.f, 0.f, 0.f};
#pragma unroll
    for (int kt = 0; kt < 2; kt++) {
      const int ko = kt * 32 + qd * 8;
#pragma unroll
      for (int nt = 0; nt < 4; nt++) {
        const bf16x8 bH = *(const bf16x8*)&Kh[(nt * 16 + l16) * LDW + ko];
        const bf16x8 bL = *(const bf16x8*)&Kl[(nt * 16 + l16) * LDW + ko];
        accp[nt] = __builtin_amdgcn_mfma_f32_16x16x32_bf16(qH[kt], bH, accp[nt], 0, 0, 0);
        accp[nt] = __builtin_amdgcn_mfma_f32_16x16x32_bf16(qL[kt], bH, accp[nt], 0, 0, 0);
        accp[nt] = __builtin_amdgcn_mfma_f32_16x16x32_bf16(qH[kt], bL, accp[nt], 0, 0, 0);
      }
    }
    // exp + store P hi-only [s][t] (per-wave rows, no barrier needed)
#pragma unroll
    for (int nt = 0; nt < 4; nt++) {
      const int tcol = nt * 16 + l16;
      const float kv = kns[tcol];
#pragma unroll
      for (int r = 0; r < 4; r++) {
        const int srow = m16 + qd * 4 + r;
        const float e2 = fmaf(2.0f, accp[nt][r], -(qns_r[r] + kv));
        const float val = __expf(fminf(e2, 0.0f) * cc);
        Ph[srow * LDW + tcol] = (short)kar_f2bf(val);
      }
    }
    // phase 2: acc += P_hi @ (alpha_hi + alpha_lo)
#pragma unroll
    for (int kt = 0; kt < 2; kt++) {
      const int ko = kt * 32 + qd * 8;
      const bf16x8 pH = *(const bf16x8*)&Ph[(m16 + l16) * LDW + ko];
#pragma unroll
      for (int dt = 0; dt < 4; dt++) {
        const bf16x8 bH = *(const bf16x8*)&Ah[(dt * 16 + l16) * LDW + ko];
        const bf16x8 bL = *(const bf16x8*)&Al[(dt * 16 + l16) * LDW + ko];
        acco[dt] = __builtin_amdgcn_mfma_f32_16x16x32_bf16(pH, bH, acco[dt], 0, 0, 0);
        acco[dt] = __builtin_amdgcn_mfma_f32_16x16x32_bf16(pH, bL, acco[dt], 0, 0, 0);
      }
    }
  }
  if (FINAL) {
#pragma unroll
    for (int dt = 0; dt < 4; dt++) {
#pragma unroll
      for (int r = 0; r < 4; r++) {
        const int s = s0 + m16 + qd * 4 + r;
        const int d = dt * 16 + l16;
        short hh, ll; kar_split_bf(acco[dt][r], hh, ll);
        tmph[(size_t)s * kD + h * kDH + d] = hh;
        tmpl[(size_t)s * kD + h * kDH + d] = ll;
      }
    }
  } else {
    const float lamf = (float)SC[1];
#pragma unroll
    for (int dt = 0; dt < 4; dt++) {
#pragma unroll
      for (int r = 0; r < 4; r++) {
        const int s = s0 + m16 + qd * 4 + r;
        const int d = dt * 16 + l16;
        const size_t eg = ((size_t)h * kS + s) * kDH + d;
        outp[eg] = v[eg] - (acco[dt][r] + lamf * alpha[eg]);
      }
    }
  }
}

// ================= OLD PATH (R4 fallback) kernels =================
__global__ __launch_bounds__(256) void kar_gemm_qkv_f32_kernel(
    const float* __restrict__ x,
    const float* __restrict__ Wq, const float* __restrict__ Wk, const float* __restrict__ Wv,
    float* __restrict__ q, float* __restrict__ k, float* __restrict__ v) {
  const float* W = (blockIdx.z == 0) ? Wq : (blockIdx.z == 1) ? Wk : Wv;
  float* outp    = (blockIdx.z == 0) ? q  : (blockIdx.z == 1) ? k  : v;
  const int n0 = blockIdx.x * 64;
  const int m0 = blockIdx.y * 64;
  const int tid = threadIdx.x;
  const int tx = tid & 15, ty = tid >> 4;
  __shared__ float As[16][68];
  __shared__ float Bs[16][68];
  double acc[4][4] = {};
  const int lr = tid >> 2;
  const int lk = (tid & 3) * 4;
  const int br = tid >> 4;
  const int bc = (tid & 15) * 4;
  for (int k0 = 0; k0 < kD; k0 += 16) {
    const float4 a4 = *(const float4*)&x[(size_t)(m0 + lr) * kD + k0 + lk];
    const float4 b4 = *(const float4*)&W[(size_t)(k0 + br) * kD + n0 + bc];
    __syncthreads();
    As[lk + 0][lr] = a4.x; As[lk + 1][lr] = a4.y;
    As[lk + 2][lr] = a4.z; As[lk + 3][lr] = a4.w;
    *(float4*)&Bs[br][bc] = b4;
    __syncthreads();
    float c32[4][4] = {};
#pragma unroll
    for (int kk = 0; kk < 16; kk++) {
      const float4 av = *(const float4*)&As[kk][ty * 4];
      const float4 bv = *(const float4*)&Bs[kk][tx * 4];
      const float a_[4] = {av.x, av.y, av.z, av.w};
      const float b_[4] = {bv.x, bv.y, bv.z, bv.w};
#pragma unroll
      for (int i = 0; i < 4; i++)
#pragma unroll
        for (int j = 0; j < 4; j++) c32[i][j] = fmaf(a_[i], b_[j], c32[i][j]);
    }
#pragma unroll
    for (int i = 0; i < 4; i++)
#pragma unroll
      for (int j = 0; j < 4; j++) acc[i][j] += (double)c32[i][j];
  }
  const int h = n0 >> 6;
#pragma unroll
  for (int i = 0; i < 4; i++) {
    const int s = m0 + ty * 4 + i;
    float4 o;
    o.x = (float)acc[i][0]; o.y = (float)acc[i][1];
    o.z = (float)acc[i][2]; o.w = (float)acc[i][3];
    *(float4*)&outp[((size_t)h * kS + s) * kDH + tx * 4] = o;
  }
}

__global__ __launch_bounds__(256) void kar_gemm_plain_kernel(
    const float* __restrict__ A, const float* __restrict__ W, float* __restrict__ C) {
  const int n0 = blockIdx.x * 64;
  const int m0 = blockIdx.y * 64;
  const int tid = threadIdx.x;
  const int tx = tid & 15, ty = tid >> 4;
  __shared__ float As[16][68];
  __shared__ float Bs[16][68];
  double acc[4][4] = {};
  const int lr = tid >> 2;
  const int lk = (tid & 3) * 4;
  const int br = tid >> 4;
  const int bc = (tid & 15) * 4;
  for (int k0 = 0; k0 < kD; k0 += 16) {
    const float4 a4 = *(const float4*)&A[(size_t)(m0 + lr) * kD + k0 + lk];
    const float4 b4 = *(const float4*)&W[(size_t)(k0 + br) * kD + n0 + bc];
    __syncthreads();
    As[lk + 0][lr] = a4.x; As[lk + 1][lr] = a4.y;
    As[lk + 2][lr] = a4.z; As[lk + 3][lr] = a4.w;
    *(float4*)&Bs[br][bc] = b4;
    __syncthreads();
    float c32[4][4] = {};
#pragma unroll
    for (int kk = 0; kk < 16; kk++) {
      const float4 av = *(const float4*)&As[kk][ty * 4];
      const float4 bv = *(const float4*)&Bs[kk][tx * 4];
      const float a_[4] = {av.x, av.y, av.z, av.w};
      const float b_[4] = {bv.x, bv.y, bv.z, bv.w};
#pragma unroll
      for (int i = 0; i < 4; i++)
#pragma unroll
        for (int j = 0; j < 4; j++) c32[i][j] = fmaf(a_[i], b_[j], c32[i][j]);
    }
#pragma unroll
    for (int i = 0; i < 4; i++)
#pragma unroll
      for (int j = 0; j < 4; j++) acc[i][j] += (double)c32[i][j];
  }
#pragma unroll
  for (int i = 0; i < 4; i++) {
    const int s = m0 + ty * 4 + i;
    float4 o;
    o.x = (float)acc[i][0]; o.y = (float)acc[i][1];
    o.z = (float)acc[i][2]; o.w = (float)acc[i][3];
    *(float4*)&C[(size_t)s * kD + n0 + tx * 4] = o;
  }
}

__global__ __launch_bounds__(256) void kar_norms_f32_kernel(const float* __restrict__ q,
                                                            const float* __restrict__ k,
                                                            double* __restrict__ qn,
                                                            double* __restrict__ kn) {
  int o = blockIdx.x * 256 + threadIdx.x;
  const float* src; double* dst; int p;
  if (o < kH * kS) { src = q; dst = qn; p = o; }
  else             { src = k; dst = kn; p = o - kH * kS; }
  const float* rowp = src + (size_t)p * kDH;
  double s = 0.0;
  for (int i = 0; i < kDH; i += 4) {
    float4 x4 = *(const float4*)&rowp[i];
    s += (double)x4.x * (double)x4.x + (double)x4.y * (double)x4.y +
         (double)x4.z * (double)x4.z + (double)x4.w * (double)x4.w;
  }
  dst[p] = s;
}

__global__ __launch_bounds__(256) void kar_diagp_f32_kernel(
    const float* __restrict__ q, const float* __restrict__ k,
    const double* __restrict__ qn, const double* __restrict__ kn,
    const double* __restrict__ SC, const float* __restrict__ dsc,
    const float* __restrict__ reg, double* __restrict__ dgp) {
  int o = blockIdx.x * 256 + threadIdx.x;
  int h = o >> 11;
  const float* qp = q + (size_t)o * kDH;
  const float* kp = k + (size_t)o * kDH;
  double dot = 0.0;
  for (int i = 0; i < kDH; i++) dot += (double)qp[i] * (double)kp[i];
  double dist = fmax(qn[o] + kn[o] - 2.0 * dot, 0.0);
  double Kss = exp(-dist * SC[0]);
  double sp  = log1p(exp(Kss));
  dgp[o] = sp * (double)dsc[h] + (double)reg[0];
}

template <bool FINAL>
__global__ __launch_bounds__(256, 2) void kar_mfma_iterA_kernel(
    const float* __restrict__ q, const float* __restrict__ k,
    const float* __restrict__ alpha, const float* __restrict__ v,
    const double* __restrict__ qn, const double* __restrict__ kn,
    const double* __restrict__ SC, float* __restrict__ outp) {
  constexpr int LDW = 72;
  __shared__ short Qh[64 * LDW], Ql[64 * LDW];
  __shared__ short Kh[64 * LDW], Kl[64 * LDW];
  __shared__ short Ph[64 * LDW], Pl[64 * LDW];
  __shared__ short Ah[64 * LDW], Al[64 * LDW];
  __shared__ float qns[64], kns[64];
  const int h   = blockIdx.y;
  const int s0  = blockIdx.x * 64;
  const int tid = threadIdx.x;
  const int lane = tid & 63;
  const int wv   = tid >> 6;
  const int l16  = lane & 15;
  const int qd   = lane >> 4;
  const int m16  = wv * 16;
  const float* qh = q + ((size_t)h * kS + s0) * kDH;
  const float* kh = k + (size_t)h * kS * kDH;
  const float* ah = alpha + (size_t)h * kS * kDH;
  {
    const int row = tid >> 4;
    const int c4  = (tid & 15) * 4;
#pragma unroll
    for (int rep = 0; rep < 4; rep++) {
      const int r = rep * 16 + row;
      const float4 a = *(const float4*)&qh[(size_t)r * kDH + c4];
      short h0, l0, h1, l1, h2, l2, h3, l3;
      kar_split_bf(a.x, h0, l0); kar_split_bf(a.y, h1, l1);
      kar_split_bf(a.z, h2, l2); kar_split_bf(a.w, h3, l3);
      *(short4*)&Qh[r * LDW + c4] = make_short4(h0, h1, h2, h3);
      *(short4*)&Ql[r * LDW + c4] = make_short4(l0, l1, l2, l3);
    }
    if (tid < 64) qns[tid] = (float)qn[h * kS + s0 + tid];
  }
  const float cc = (float)SC[0];
  f32x4 acco[4];
#pragma unroll
  for (int i = 0; i < 4; i++) acco[i] = (f32x4){0.f, 0.f, 0.f, 0.f};
  for (int t0 = 0; t0 < kS; t0 += 64) {
    __syncthreads();
    {
      const int row = tid >> 4;
      const int c4  = (tid & 15) * 4;
#pragma unroll
      for (int rep = 0; rep < 4; rep++) {
        const int r = rep * 16 + row;
        const float4 b = *(const float4*)&kh[(size_t)(t0 + r) * kDH + c4];
        short h0, l0, h1, l1, h2, l2, h3, l3;
        kar_split_bf(b.x, h0, l0); kar_split_bf(b.y, h1, l1);
        kar_split_bf(b.z, h2, l2); kar_split_bf(b.w, h3, l3);
        *(short4*)&Kh[r * LDW + c4] = make_short4(h0, h1, h2, h3);
        *(short4*)&Kl[r * LDW + c4] = make_short4(l0, l1, l2, l3);
        const float4 av = *(const float4*)&ah[(size_t)(t0 + r) * kDH + c4];
        kar_split_bf(av.x, h0, l0); kar_split_bf(av.y, h1, l1);
        kar_split_bf(av.z, h2, l2); kar_split_bf(av.w, h3, l3);
        Ah[(c4 + 0) * LDW + r] = h0; Al[(c4 + 0) * LDW + r] = l0;
        Ah[(c4 + 1) * LDW + r] = h1; Al[(c4 + 1) * LDW + r] = l1;
        Ah[(c4 + 2) * LDW + r] = h2; Al[(c4 + 2) * LDW + r] = l2;
        Ah[(c4 + 3) * LDW + r] = h3; Al[(c4 + 3) * LDW + r] = l3;
      }
      if (tid < 64) kns[tid] = (float)kn[h * kS + t0 + tid];
    }
    __syncthreads();
    f32x4 accp[4];
#pragma unroll
    for (int i = 0; i < 4; i++) accp[i] = (f32x4){0.f, 0.f, 0.f, 0.f};
#pragma unroll
    for (int kt = 0; kt < 2; kt++) {
      const int ko = kt * 32 + qd * 8;
      const bf16x8 aH = *(const bf16x8*)&Qh[(m16 + l16) * LDW + ko];
      const bf16x8 aL = *(const bf16x8*)&Ql[(m16 + l16) * LDW + ko];
#pragma unroll
      for (int nt = 0; nt < 4; nt++) {
        const bf16x8 bH = *(const bf16x8*)&Kh[(nt * 16 + l16) * LDW + ko];
        const bf16x8 bL = *(const bf16x8*)&Kl[(nt * 16 + l16) * LDW + ko];
        accp[nt] = __builtin_amdgcn_mfma_f32_16x16x32_bf16(aH, bH, accp[nt], 0, 0, 0);
        accp[nt] = __builtin_amdgcn_mfma_f32_16x16x32_bf16(aL, bH, accp[nt], 0, 0, 0);
        accp[nt] = __builtin_amdgcn_mfma_f32_16x16x32_bf16(aH, bL, accp[nt], 0, 0, 0);
      }
    }
#pragma unroll
    for (int nt = 0; nt < 4; nt++) {
      const int tcol = nt * 16 + l16;
      const float kv = kns[tcol];
#pragma unroll
      for (int r = 0; r < 4; r++) {
        const int srow = m16 + qd * 4 + r;
        const float e2 = fmaf(2.0f, accp[nt][r], -(qns[srow] + kv));
        const float val = __expf(fminf(e2, 0.0f) * cc);
        short hb, lb; kar_split_bf(val, hb, lb);
        Ph[srow * LDW + tcol] = hb;
        Pl[srow * LDW + tcol] = lb;
      }
    }
#pragma unroll
    for (int kt = 0; kt < 2; kt++) {
      const int ko = kt * 32 + qd * 8;
      const bf16x8 pH = *(const bf16x8*)&Ph[(m16 + l16) * LDW + ko];
      const bf16x8 pL = *(const bf16x8*)&Pl[(m16 + l16) * LDW + ko];
#pragma unroll
      for (int dt = 0; dt < 4; dt++) {
        const bf16x8 bH = *(const bf16x8*)&Ah[(dt * 16 + l16) * LDW + ko];
        const bf16x8 bL = *(const bf16x8*)&Al[(dt * 16 + l16) * LDW + ko];
        acco[dt] = __builtin_amdgcn_mfma_f32_16x16x32_bf16(pH, bH, acco[dt], 0, 0, 0);
        acco[dt] = __builtin_amdgcn_mfma_f32_16x16x32_bf16(pL, bH, acco[dt], 0, 0, 0);
        acco[dt] = __builtin_amdgcn_mfma_f32_16x16x32_bf16(pH, bL, acco[dt], 0, 0, 0);
      }
    }
  }
  if (FINAL) {
#pragma unroll
    for (int dt = 0; dt < 4; dt++) {
#pragma unroll
      for (int r = 0; r < 4; r++) {
        const int s = s0 + m16 + qd * 4 + r;
        const int d = dt * 16 + l16;
        outp[(size_t)s * kD + h * kDH + d] = acco[dt][r];
      }
    }
  } else {
    const float lamf = (float)SC[1];
#pragma unroll
    for (int dt = 0; dt < 4; dt++) {
#pragma unroll
      for (int r = 0; r < 4; r++) {
        const int s = s0 + m16 + qd * 4 + r;
        const int d = dt * 16 + l16;
        const size_t eg = ((size_t)h * kS + s) * kDH + d;
        outp[eg] = v[eg] - (acco[dt][r] + lamf * alpha[eg]);
      }
    }
  }
}

extern "C" void kernel_launch(void* const* d_in, const int* in_sizes, int n_in,
                              void* d_out, int out_size, void* d_ws, size_t ws_size,
                              hipStream_t stream) {
  (void)in_sizes; (void)n_in; (void)out_size;
  const float* x    = (const float*)d_in[0];
  const float* Wq   = (const float*)d_in[1];
  const float* Wk   = (const float*)d_in[2];
  const float* Wv   = (const float*)d_in[3];
  const float* Wo   = (const float*)d_in[4];
  const float* bw   = (const float*)d_in[5];
  const float* dsc  = (const float*)d_in[6];
  const float* pe   = (const float*)d_in[7];
  const float* hp   = (const float*)d_in[8];
  const float* reg  = (const float*)d_in[9];
  const float* lreg = (const float*)d_in[10];
  float* out = (float*)d_out;

  char* w = (char*)d_ws;
  size_t off = 0;
  auto take = [&](size_t bytes) -> void* {
    void* p = w + off;
    off += (bytes + 255) & ~(size_t)255;
    return p;
  };
  const size_t HSD = (size_t)kH * kS * kDH;  // 2M elements

  // ---- new-path layout ----
  float*  v_    = (float*)take(HSD * 4);
  float*  alpha = (float*)take(HSD * 4);
  float*  rbuf  = (float*)take(HSD * 4);
  short*  qsh   = (short*)take(HSD * 2);
  short*  qsl   = (short*)take(HSD * 2);
  short*  ksh   = (short*)take(HSD * 2);
  short*  ksl   = (short*)take(HSD * 2);
  short*  ath   = (short*)take(HSD * 2);
  short*  atl   = (short*)take(HSD * 2);
  short*  xh    = (short*)take((size_t)kS * kD * 2);  // reused as tmph
  short*  xl    = (short*)take((size_t)kS * kD * 2);  // reused as tmpl
  short*  WTh   = (short*)take((size_t)4 * kD * kD * 2);
  short*  WTl   = (short*)take((size_t)4 * kD * kD * 2);
  double* qn    = (double*)take((size_t)kH * kS * 8);
  double* kn    = (double*)take((size_t)kH * kS * 8);
  double* dgp   = (double*)take((size_t)kH * kS * 8);
  float*  U     = (float*)take((size_t)kH * kS * kR * 4);
  double* utr   = (double*)take((size_t)kH * kR * kDH * 8);
  double* utrp  = (double*)take((size_t)kH * 16 * kR * kDH * 8);
  double* SC    = (double*)take(256);
  const size_t need_new = off;

  if (ws_size >= need_new) {
    // ================= NEW PATH =================
    kar_scalars_kernel<<<1, 64, 0, stream>>>(bw, lreg, SC);
    kar_xsplit_kernel<<<2048, 256, 0, stream>>>(x, xh, xl);
    kar_wsplit_kernel<<<dim3(16, 16, 4), 256, 0, stream>>>(Wq, Wk, Wv, Wo, WTh, WTl);
    kar_mfma_gemm_qkv_kernel<<<dim3(16, 16, 3), 256, 0, stream>>>(
        xh, xl, WTh, WTl, v_, qsh, qsl, ksh, ksl);
    kar_norms2_kernel<<<256, 256, 0, stream>>>(qsh, qsl, ksh, ksl, qn, kn);
    kar_u_kernel<<<2048, 256, 0, stream>>>(pe, hp, U);
    kar_diagp2_kernel<<<128, 256, 0, stream>>>(qsh, qsl, ksh, ksl, qn, kn, SC, dsc, reg, dgp);

    // it 0: alpha == 0 -> r == v
    kar_utr_partial_kernel<<<dim3(16, kH), 256, 0, stream>>>(U, v_, utrp);
    kar_utr_reduce_kernel<<<64, 256, 0, stream>>>(utrp, utr);
    kar_update_kernel<<<8192, 256, 0, stream>>>(v_, dgp, U, utr, alpha, 1);

    for (int it = 1; it < 5; it++) {
      kar_asplit_kernel<<<dim3(32, kH), 256, 0, stream>>>(alpha, ath, atl);
      kar_mfma_iter3_kernel<false><<<dim3(32, kH), 256, 0, stream>>>(
          qsh, qsl, ksh, ksl, ath, atl, alpha, v_, qn, kn, SC, rbuf, nullptr, nullptr);
      kar_utr_partial_kernel<<<dim3(16, kH), 256, 0, stream>>>(U, rbuf, utrp);
      kar_utr_reduce_kernel<<<64, 256, 0, stream>>>(utrp, utr);
      kar_update_kernel<<<8192, 256, 0, stream>>>(rbuf, dgp, U, utr, alpha, 0);
    }

    kar_asplit_kernel<<<dim3(32, kH), 256, 0, stream>>>(alpha, ath, atl);
    kar_mfma_iter3_kernel<true><<<dim3(32, kH), 256, 0, stream>>>(
        qsh, qsl, ksh, ksl, ath, atl, alpha, v_, qn, kn, SC, rbuf, xh, xl);  // xh/xl = tmph/tmpl
    kar_mfma_gemm_wo_kernel<<<dim3(16, 16), 256, 0, stream>>>(
        xh, xl, WTh + (size_t)3 * kD * kD, WTl + (size_t)3 * kD * kD, out);
  } else {
    // ================= OLD PATH (R4) =================
    size_t off2 = 0;
    auto take2 = [&](size_t bytes) -> void* {
      void* p = w + off2;
      off2 += (bytes + 255) & ~(size_t)255;
      return p;
    };
    float*  q2    = (float*)take2(HSD * 4);
    float*  k2    = (float*)take2(HSD * 4);
    float*  v2    = (float*)take2(HSD * 4);
    float*  al2   = (float*)take2(HSD * 4);
    float*  rb2   = (float*)take2(HSD * 4);
    float*  tmp2  = (float*)take2((size_t)kS * kD * 4);
    double* qn2   = (double*)take2((size_t)kH * kS * 8);
    double* kn2   = (double*)take2((size_t)kH * kS * 8);
    double* dgp2  = (double*)take2((size_t)kH * kS * 8);
    float*  U2    = (float*)take2((size_t)kH * kS * kR * 4);
    double* utr2  = (double*)take2((size_t)kH * kR * kDH * 8);
    double* utrp2 = (double*)take2((size_t)kH * 16 * kR * kDH * 8);
    double* SC2   = (double*)take2(256);

    kar_scalars_kernel<<<1, 64, 0, stream>>>(bw, lreg, SC2);
    kar_gemm_qkv_f32_kernel<<<dim3(16, 32, 3), 256, 0, stream>>>(x, Wq, Wk, Wv, q2, k2, v2);
    kar_norms_f32_kernel<<<256, 256, 0, stream>>>(q2, k2, qn2, kn2);
    kar_u_kernel<<<2048, 256, 0, stream>>>(pe, hp, U2);
    kar_diagp_f32_kernel<<<128, 256, 0, stream>>>(q2, k2, qn2, kn2, SC2, dsc, reg, dgp2);

    kar_utr_partial_kernel<<<dim3(16, kH), 256, 0, stream>>>(U2, v2, utrp2);
    kar_utr_reduce_kernel<<<64, 256, 0, stream>>>(utrp2, utr2);
    kar_update_kernel<<<8192, 256, 0, stream>>>(v2, dgp2, U2, utr2, al2, 1);

    for (int it = 1; it < 5; it++) {
      kar_mfma_iterA_kernel<false><<<dim3(32, kH), 256, 0, stream>>>(
          q2, k2, al2, v2, qn2, kn2, SC2, rb2);
      kar_utr_partial_kernel<<<dim3(16, kH), 256, 0, stream>>>(U2, rb2, utrp2);
      kar_utr_reduce_kernel<<<64, 256, 0, stream>>>(utrp2, utr2);
      kar_update_kernel<<<8192, 256, 0, stream>>>(rb2, dgp2, U2, utr2, al2, 0);
    }
    kar_mfma_iterA_kernel<true><<<dim3(32, kH), 256, 0, stream>>>(
        q2, k2, al2, v2, qn2, kn2, SC2, tmp2);
    kar_gemm_plain_kernel<<<dim3(16, 32), 256, 0, stream>>>(tmp2, Wo, out);
  }
}

// Round 8
// 693.463 us; speedup vs baseline: 3.5223x; 1.1366x over previous
//
#include <hip/hip_runtime.h>
#include <cstdint>
#include <cstddef>

constexpr int kS  = 2048;
constexpr int kD  = 1024;
constexpr int kH  = 16;
constexpr int kDH = 64;
constexpr int kR  = 16;

typedef __attribute__((ext_vector_type(8))) short bf16x8;
typedef __attribute__((ext_vector_type(4))) float f32x4;

__device__ __forceinline__ unsigned short kar_f2bf(float x) {
  unsigned u = __float_as_uint(x);
  return (unsigned short)((u + 0x7FFFu + ((u >> 16) & 1u)) >> 16);
}
__device__ __forceinline__ float kar_bf2f(short h) {
  return __uint_as_float((unsigned)(unsigned short)h << 16);
}
__device__ __forceinline__ void kar_split_bf(float x, short& hi, short& lo) {
  unsigned short h = kar_f2bf(x);
  float hf = __uint_as_float((unsigned)h << 16);
  hi = (short)h;
  lo = (short)kar_f2bf(x - hf);
}

// ---------------- scalars ----------------
__global__ __launch_bounds__(64) void kar_scalars_kernel(const float* __restrict__ bw,
                                                         const float* __restrict__ lreg,
                                                         double* __restrict__ SC) {
  if (threadIdx.x == 0) {
    double b = log1p(exp((double)bw[0])) + 1e-6;
    SC[0] = 1.0 / (2.0 * b * b);
    SC[1] = log1p(exp((double)lreg[0]));
  }
}

// ---------------- U[h][s][p] ----------------
__global__ __launch_bounds__(256) void kar_u_kernel(const float* __restrict__ pe,
                                                    const float* __restrict__ hp,
                                                    float* __restrict__ U) {
  int o = blockIdx.x * 256 + threadIdx.x;
  int r = o & 15, s = (o >> 4) & 2047, h = o >> 15;
  double acc = 0.0;
#pragma unroll
  for (int rp = 0; rp < kR; rp++)
    acc += (double)pe[s * kR + rp] * (double)hp[((h * kR) + rp) * kR + r];
  U[o] = (float)acc;
}

// ---------------- ut_r partials / reduce ----------------
__global__ __launch_bounds__(256) void kar_utr_partial_kernel(
    const float* __restrict__ Ubuf, const float* __restrict__ rbuf,
    double* __restrict__ utrp) {
  const int h  = blockIdx.y;
  const int sb = blockIdx.x * 128;
  const int t  = threadIdx.x;
  __shared__ float Uch[32][16];
  __shared__ float Rch[32][64];
  double acc[4] = {};
  for (int cs = 0; cs < 128; cs += 32) {
    __syncthreads();
    if (t < 128) {
      const int i = t >> 2, f = (t & 3) * 4;
      *(float4*)&Uch[i][f] = *(const float4*)&Ubuf[((size_t)(h * kS) + sb + cs + i) * kR + f];
    }
#pragma unroll
    for (int rep = 0; rep < 2; rep++) {
      const int e = t + rep * 256;
      const int i = e >> 4, c = (e & 15) * 4;
      *(float4*)&Rch[i][c] = *(const float4*)&rbuf[((size_t)(h * kS) + sb + cs + i) * kDH + c];
    }
    __syncthreads();
    for (int i = 0; i < 32; i++) {
#pragma unroll
      for (int rep = 0; rep < 4; rep++) {
        const int p = t + rep * 256;
        const int r = p >> 6, d = p & 63;
        acc[rep] += (double)Uch[i][r] * (double)Rch[i][d];
      }
    }
  }
#pragma unroll
  for (int rep = 0; rep < 4; rep++) {
    const int p = t + rep * 256;
    const int r = p >> 6, d = p & 63;
    utrp[(((size_t)(h * 16) + blockIdx.x) * kR + r) * kDH + d] = acc[rep];
  }
}

__global__ __launch_bounds__(256) void kar_utr_reduce_kernel(const double* __restrict__ utrp,
                                                             double* __restrict__ utr) {
  int o = blockIdx.x * 256 + threadIdx.x;
  int h = o >> 10, rd = o & 1023;
  double s = 0.0;
#pragma unroll
  for (int j = 0; j < 16; j++) s += utrp[(size_t)h * 16384 + (size_t)j * 1024 + rd];
  utr[o] = s;
}

// old elementwise update (fallback path only)
__global__ __launch_bounds__(256) void kar_update_kernel(
    const float* __restrict__ rsrc, const double* __restrict__ dgp,
    const float* __restrict__ Ubuf, const double* __restrict__ utr,
    float* __restrict__ alpha, int first) {
  int e = blockIdx.x * 256 + threadIdx.x;
  const int d = e & 63;
  const int s = (e >> 6) & 2047;
  const int h = e >> 17;
  const double rv = (double)rsrc[e];
  const double dp = dgp[h * kS + s];
  const float*  Us = &Ubuf[((size_t)(h * kS) + s) * kR];
  const double* uh = &utr[(size_t)h * kR * kDH];
  double sum = 0.0;
#pragma unroll
  for (int ri = 0; ri < kR; ri++) sum += (double)Us[ri] * uh[ri * kDH + d];
  const double p = rv * dp + sum;
  const double an = (first ? 0.0 : (double)alpha[e]) + p;
  alpha[e] = (float)an;
}

// fused update + transpose/split: alpha fp32 + ath/atl [h][d][s] in one pass
__global__ __launch_bounds__(256) void kar_update_t_kernel(
    const float* __restrict__ rsrc, const double* __restrict__ dgp,
    const float* __restrict__ Ubuf, const double* __restrict__ utr,
    float* __restrict__ alpha, short* __restrict__ ath, short* __restrict__ atl,
    int first) {
  const int h = blockIdx.y, s0 = blockIdx.x * 64;
  __shared__ float T[64][65];
  const int t = threadIdx.x;
  const int r16 = t >> 4, c4 = (t & 15) * 4;
  const double* uh = &utr[(size_t)h * kR * kDH];
#pragma unroll
  for (int it = 0; it < 4; it++) {
    const int row = it * 16 + r16;
    const int s = s0 + row;
    const size_t eg = ((size_t)h * kS + s) * kDH + c4;
    const float4 rv4 = *(const float4*)&rsrc[eg];
    const double dp = dgp[h * kS + s];
    const float* Us = &Ubuf[((size_t)h * kS + s) * kR];
    double sum0 = 0.0, sum1 = 0.0, sum2 = 0.0, sum3 = 0.0;
#pragma unroll
    for (int ri = 0; ri < kR; ri++) {
      const double u = (double)Us[ri];
      const double* ur = &uh[ri * kDH + c4];
      sum0 += u * ur[0]; sum1 += u * ur[1];
      sum2 += u * ur[2]; sum3 += u * ur[3];
    }
    double a0 = (first ? 0.0 : (double)alpha[eg + 0]) + ((double)rv4.x * dp + sum0);
    double a1 = (first ? 0.0 : (double)alpha[eg + 1]) + ((double)rv4.y * dp + sum1);
    double a2 = (first ? 0.0 : (double)alpha[eg + 2]) + ((double)rv4.z * dp + sum2);
    double a3 = (first ? 0.0 : (double)alpha[eg + 3]) + ((double)rv4.w * dp + sum3);
    float4 o;
    o.x = (float)a0; o.y = (float)a1; o.z = (float)a2; o.w = (float)a3;
    *(float4*)&alpha[eg] = o;
    T[row][c4] = o.x; T[row][c4 + 1] = o.y; T[row][c4 + 2] = o.z; T[row][c4 + 3] = o.w;
  }
  __syncthreads();
#pragma unroll
  for (int it = 0; it < 4; it++) {
    int d = it * 16 + r16;
    float v0 = T[c4][d], v1 = T[c4 + 1][d], v2 = T[c4 + 2][d], v3 = T[c4 + 3][d];
    short h0, l0, h1, l1, h2, l2, h3, l3;
    kar_split_bf(v0, h0, l0); kar_split_bf(v1, h1, l1);
    kar_split_bf(v2, h2, l2); kar_split_bf(v3, h3, l3);
    *(short4*)&ath[((size_t)h * kDH + d) * kS + s0 + c4] = make_short4(h0, h1, h2, h3);
    *(short4*)&atl[((size_t)h * kDH + d) * kS + s0 + c4] = make_short4(l0, l1, l2, l3);
  }
}

// ================= NEW PATH kernels =================

__global__ __launch_bounds__(256) void kar_xsplit_kernel(const float* __restrict__ x,
                                                         short* __restrict__ xh,
                                                         short* __restrict__ xl) {
  size_t e = ((size_t)blockIdx.x * 256 + threadIdx.x) * 4;
  float4 a = *(const float4*)&x[e];
  short h0, l0, h1, l1, h2, l2, h3, l3;
  kar_split_bf(a.x, h0, l0); kar_split_bf(a.y, h1, l1);
  kar_split_bf(a.z, h2, l2); kar_split_bf(a.w, h3, l3);
  *(short4*)&xh[e] = make_short4(h0, h1, h2, h3);
  *(short4*)&xl[e] = make_short4(l0, l1, l2, l3);
}

__global__ __launch_bounds__(256) void kar_wsplit_kernel(
    const float* __restrict__ Wq, const float* __restrict__ Wk,
    const float* __restrict__ Wv, const float* __restrict__ Wo,
    short* __restrict__ WTh, short* __restrict__ WTl) {
  const float* W = (blockIdx.z == 0) ? Wq : (blockIdx.z == 1) ? Wk
                 : (blockIdx.z == 2) ? Wv : Wo;
  short* oh = WTh + (size_t)blockIdx.z * kD * kD;
  short* ol = WTl + (size_t)blockIdx.z * kD * kD;
  const int n0 = blockIdx.x * 64, k0 = blockIdx.y * 64;
  __shared__ float T[64][65];
  const int t = threadIdx.x;
  const int r16 = t >> 4, c4 = (t & 15) * 4;
#pragma unroll
  for (int it = 0; it < 4; it++) {
    int r = it * 16 + r16;
    float4 a = *(const float4*)&W[(size_t)(k0 + r) * kD + n0 + c4];
    T[r][c4] = a.x; T[r][c4 + 1] = a.y; T[r][c4 + 2] = a.z; T[r][c4 + 3] = a.w;
  }
  __syncthreads();
#pragma unroll
  for (int it = 0; it < 4; it++) {
    int n = it * 16 + r16;
    float v0 = T[c4][n], v1 = T[c4 + 1][n], v2 = T[c4 + 2][n], v3 = T[c4 + 3][n];
    short h0, l0, h1, l1, h2, l2, h3, l3;
    kar_split_bf(v0, h0, l0); kar_split_bf(v1, h1, l1);
    kar_split_bf(v2, h2, l2); kar_split_bf(v3, h3, l3);
    *(short4*)&oh[(size_t)(n0 + n) * kD + k0 + c4] = make_short4(h0, h1, h2, h3);
    *(short4*)&ol[(size_t)(n0 + n) * kD + k0 + c4] = make_short4(l0, l1, l2, l3);
  }
}

// MFMA split-bf16 GEMM: QKV. z=0,1: split dumps q/k; z=2: v fp32.
__global__ __launch_bounds__(256) void kar_mfma_gemm_qkv_kernel(
    const short* __restrict__ xh, const short* __restrict__ xl,
    const short* __restrict__ WTh, const short* __restrict__ WTl,
    float* __restrict__ v,
    short* __restrict__ qsh, short* __restrict__ qsl,
    short* __restrict__ ksh, short* __restrict__ ksl) {
  const int z = blockIdx.z;
  const short* Bh = WTh + (size_t)z * kD * kD;
  const short* Bl = WTl + (size_t)z * kD * kD;
  const int n0 = blockIdx.x * 64;
  const int m0 = blockIdx.y * 128;
  constexpr int LW = 40;
  __shared__ short Xh[128 * LW], Xl[128 * LW], Wh[64 * LW], Wl[64 * LW];
  const int t = threadIdx.x, lane = t & 63, wv = t >> 6;
  const int wm = wv >> 1, wn = wv & 1, l16 = lane & 15, qd = lane >> 4;
  f32x4 acc[4][2];
#pragma unroll
  for (int i = 0; i < 4; i++)
#pragma unroll
    for (int j = 0; j < 2; j++) acc[i][j] = (f32x4){0.f, 0.f, 0.f, 0.f};
  const int xrow = t >> 1, xc = (t & 1) * 16;
  for (int k0 = 0; k0 < kD; k0 += 32) {
    __syncthreads();
    {
      const size_t xs = (size_t)(m0 + xrow) * kD + k0 + xc;
      *(bf16x8*)&Xh[xrow * LW + xc]     = *(const bf16x8*)&xh[xs];
      *(bf16x8*)&Xh[xrow * LW + xc + 8] = *(const bf16x8*)&xh[xs + 8];
      *(bf16x8*)&Xl[xrow * LW + xc]     = *(const bf16x8*)&xl[xs];
      *(bf16x8*)&Xl[xrow * LW + xc + 8] = *(const bf16x8*)&xl[xs + 8];
    }
    if (t < 128) {
      const int wrow = t >> 1, wc = (t & 1) * 16;
      const size_t wsrc = (size_t)(n0 + wrow) * kD + k0 + wc;
      *(bf16x8*)&Wh[wrow * LW + wc]     = *(const bf16x8*)&Bh[wsrc];
      *(bf16x8*)&Wh[wrow * LW + wc + 8] = *(const bf16x8*)&Bh[wsrc + 8];
    } else {
      const int t2 = t - 128, wrow = t2 >> 1, wc = (t2 & 1) * 16;
      const size_t wsrc = (size_t)(n0 + wrow) * kD + k0 + wc;
      *(bf16x8*)&Wl[wrow * LW + wc]     = *(const bf16x8*)&Bl[wsrc];
      *(bf16x8*)&Wl[wrow * LW + wc + 8] = *(const bf16x8*)&Bl[wsrc + 8];
    }
    __syncthreads();
    bf16x8 bH[2], bL[2];
#pragma unroll
    for (int ni = 0; ni < 2; ni++) {
      const int rn = wn * 32 + ni * 16 + l16;
      bH[ni] = *(const bf16x8*)&Wh[rn * LW + qd * 8];
      bL[ni] = *(const bf16x8*)&Wl[rn * LW + qd * 8];
    }
#pragma unroll
    for (int mi = 0; mi < 4; mi++) {
      const int rm = wm * 64 + mi * 16 + l16;
      const bf16x8 aH = *(const bf16x8*)&Xh[rm * LW + qd * 8];
      const bf16x8 aL = *(const bf16x8*)&Xl[rm * LW + qd * 8];
#pragma unroll
      for (int ni = 0; ni < 2; ni++) {
        acc[mi][ni] = __builtin_amdgcn_mfma_f32_16x16x32_bf16(aH, bH[ni], acc[mi][ni], 0, 0, 0);
        acc[mi][ni] = __builtin_amdgcn_mfma_f32_16x16x32_bf16(aL, bH[ni], acc[mi][ni], 0, 0, 0);
        acc[mi][ni] = __builtin_amdgcn_mfma_f32_16x16x32_bf16(aH, bL[ni], acc[mi][ni], 0, 0, 0);
      }
    }
  }
  const int h = blockIdx.x;
#pragma unroll
  for (int mi = 0; mi < 4; mi++)
#pragma unroll
    for (int ni = 0; ni < 2; ni++) {
      const int d = wn * 32 + ni * 16 + l16;
#pragma unroll
      for (int r = 0; r < 4; r++) {
        const int s = m0 + wm * 64 + mi * 16 + qd * 4 + r;
        const float val = acc[mi][ni][r];
        const size_t idx = (((size_t)h * kS) + s) * kDH + d;
        if (z == 2) {
          v[idx] = val;
        } else {
          short hh, ll; kar_split_bf(val, hh, ll);
          if (z == 0) { qsh[idx] = hh; qsl[idx] = ll; }
          else        { ksh[idx] = hh; ksl[idx] = ll; }
        }
      }
    }
}

// MFMA split-bf16 GEMM: out = tmp @ Wo
__global__ __launch_bounds__(256) void kar_mfma_gemm_wo_kernel(
    const short* __restrict__ th, const short* __restrict__ tl,
    const short* __restrict__ Bh, const short* __restrict__ Bl,
    float* __restrict__ outp) {
  const int n0 = blockIdx.x * 64;
  const int m0 = blockIdx.y * 128;
  constexpr int LW = 40;
  __shared__ short Xh[128 * LW], Xl[128 * LW], Wh[64 * LW], Wl[64 * LW];
  const int t = threadIdx.x, lane = t & 63, wv = t >> 6;
  const int wm = wv >> 1, wn = wv & 1, l16 = lane & 15, qd = lane >> 4;
  f32x4 acc[4][2];
#pragma unroll
  for (int i = 0; i < 4; i++)
#pragma unroll
    for (int j = 0; j < 2; j++) acc[i][j] = (f32x4){0.f, 0.f, 0.f, 0.f};
  const int xrow = t >> 1, xc = (t & 1) * 16;
  for (int k0 = 0; k0 < kD; k0 += 32) {
    __syncthreads();
    {
      const size_t xs = (size_t)(m0 + xrow) * kD + k0 + xc;
      *(bf16x8*)&Xh[xrow * LW + xc]     = *(const bf16x8*)&th[xs];
      *(bf16x8*)&Xh[xrow * LW + xc + 8] = *(const bf16x8*)&th[xs + 8];
      *(bf16x8*)&Xl[xrow * LW + xc]     = *(const bf16x8*)&tl[xs];
      *(bf16x8*)&Xl[xrow * LW + xc + 8] = *(const bf16x8*)&tl[xs + 8];
    }
    if (t < 128) {
      const int wrow = t >> 1, wc = (t & 1) * 16;
      const size_t wsrc = (size_t)(n0 + wrow) * kD + k0 + wc;
      *(bf16x8*)&Wh[wrow * LW + wc]     = *(const bf16x8*)&Bh[wsrc];
      *(bf16x8*)&Wh[wrow * LW + wc + 8] = *(const bf16x8*)&Bh[wsrc + 8];
    } else {
      const int t2 = t - 128, wrow = t2 >> 1, wc = (t2 & 1) * 16;
      const size_t wsrc = (size_t)(n0 + wrow) * kD + k0 + wc;
      *(bf16x8*)&Wl[wrow * LW + wc]     = *(const bf16x8*)&Bl[wsrc];
      *(bf16x8*)&Wl[wrow * LW + wc + 8] = *(const bf16x8*)&Bl[wsrc + 8];
    }
    __syncthreads();
    bf16x8 bH[2], bL[2];
#pragma unroll
    for (int ni = 0; ni < 2; ni++) {
      const int rn = wn * 32 + ni * 16 + l16;
      bH[ni] = *(const bf16x8*)&Wh[rn * LW + qd * 8];
      bL[ni] = *(const bf16x8*)&Wl[rn * LW + qd * 8];
    }
#pragma unroll
    for (int mi = 0; mi < 4; mi++) {
      const int rm = wm * 64 + mi * 16 + l16;
      const bf16x8 aH = *(const bf16x8*)&Xh[rm * LW + qd * 8];
      const bf16x8 aL = *(const bf16x8*)&Xl[rm * LW + qd * 8];
#pragma unroll
      for (int ni = 0; ni < 2; ni++) {
        acc[mi][ni] = __builtin_amdgcn_mfma_f32_16x16x32_bf16(aH, bH[ni], acc[mi][ni], 0, 0, 0);
        acc[mi][ni] = __builtin_amdgcn_mfma_f32_16x16x32_bf16(aL, bH[ni], acc[mi][ni], 0, 0, 0);
        acc[mi][ni] = __builtin_amdgcn_mfma_f32_16x16x32_bf16(aH, bL[ni], acc[mi][ni], 0, 0, 0);
      }
    }
  }
#pragma unroll
  for (int mi = 0; mi < 4; mi++)
#pragma unroll
    for (int ni = 0; ni < 2; ni++) {
      const int col = n0 + wn * 32 + ni * 16 + l16;
#pragma unroll
      for (int r = 0; r < 4; r++) {
        const int s = m0 + wm * 64 + mi * 16 + qd * 4 + r;
        outp[(size_t)s * kD + col] = acc[mi][ni][r];
      }
    }
}

// norms from splits
__global__ __launch_bounds__(256) void kar_norms2_kernel(
    const short* __restrict__ qsh, const short* __restrict__ qsl,
    const short* __restrict__ ksh, const short* __restrict__ ksl,
    double* __restrict__ qn, double* __restrict__ kn) {
  int o = blockIdx.x * 256 + threadIdx.x;
  const short *sh, *sl; double* dst; int p;
  if (o < kH * kS) { sh = qsh; sl = qsl; dst = qn; p = o; }
  else             { sh = ksh; sl = ksl; dst = kn; p = o - kH * kS; }
  const short* rh = sh + (size_t)p * kDH;
  const short* rl = sl + (size_t)p * kDH;
  double s = 0.0;
  for (int i = 0; i < kDH; i += 4) {
    short4 a = *(const short4*)&rh[i];
    short4 b = *(const short4*)&rl[i];
    double e0 = (double)kar_bf2f(a.x) + (double)kar_bf2f(b.x);
    double e1 = (double)kar_bf2f(a.y) + (double)kar_bf2f(b.y);
    double e2 = (double)kar_bf2f(a.z) + (double)kar_bf2f(b.z);
    double e3 = (double)kar_bf2f(a.w) + (double)kar_bf2f(b.w);
    s += e0 * e0 + e1 * e1 + e2 * e2 + e3 * e3;
  }
  dst[p] = s;
}

// diag_p from splits
__global__ __launch_bounds__(256) void kar_diagp2_kernel(
    const short* __restrict__ qsh, const short* __restrict__ qsl,
    const short* __restrict__ ksh, const short* __restrict__ ksl,
    const double* __restrict__ qn, const double* __restrict__ kn,
    const double* __restrict__ SC, const float* __restrict__ dsc,
    const float* __restrict__ reg, double* __restrict__ dgp) {
  int o = blockIdx.x * 256 + threadIdx.x;
  int h = o >> 11;
  const short* qh = qsh + (size_t)o * kDH;
  const short* ql = qsl + (size_t)o * kDH;
  const short* kh = ksh + (size_t)o * kDH;
  const short* kl = ksl + (size_t)o * kDH;
  double dot = 0.0;
  for (int i = 0; i < kDH; i++) {
    double qi = (double)kar_bf2f(qh[i]) + (double)kar_bf2f(ql[i]);
    double ki = (double)kar_bf2f(kh[i]) + (double)kar_bf2f(kl[i]);
    dot += qi * ki;
  }
  double dist = fmax(qn[o] + kn[o] - 2.0 * dot, 0.0);
  double Kss = exp(-dist * SC[0]);
  double sp  = log1p(exp(Kss));
  dgp[o] = sp * (double)dsc[h] + (double)reg[0];
}

// fused K-apply v4: wave-owns-t phase1 (Q all-s in regs), wave-owns-d phase2.
// LDS b128 per wave per chunk: 8 stage + 4 K + 8 P + 4 A = 24 (vs 42 in v3).
template <bool FINAL>
__global__ __launch_bounds__(256, 2) void kar_mfma_iter4_kernel(
    const short* __restrict__ qsh, const short* __restrict__ qsl,
    const short* __restrict__ ksh, const short* __restrict__ ksl,
    const short* __restrict__ ath, const short* __restrict__ atl,
    const float* __restrict__ alpha, const float* __restrict__ v,
    const double* __restrict__ qn, const double* __restrict__ kn,
    const double* __restrict__ SC, float* __restrict__ outp,
    short* __restrict__ tmph, short* __restrict__ tmpl) {
  constexpr int LDW = 72;
  __shared__ short Kh[64 * LDW], Kl[64 * LDW];
  __shared__ short Ah[64 * LDW], Al[64 * LDW];
  __shared__ short Ph[64 * LDW];
  __shared__ float qns[64];
  const int h   = blockIdx.y;
  const int s0  = blockIdx.x * 64;
  const int tid = threadIdx.x;
  const int lane = tid & 63;
  const int wv   = tid >> 6;     // wave: owns t-quarter (ph1), d-quarter (ph2)
  const int l16  = lane & 15;
  const int qd   = lane >> 4;
  const int row = tid >> 2, c8 = (tid & 3) * 16;
  // Q fragments for ALL 4 s-quarters in registers (one-time global load)
  bf16x8 qH[4][2], qL[4][2];
#pragma unroll
  for (int sq = 0; sq < 4; sq++) {
    const size_t qb = (((size_t)h * kS) + s0 + sq * 16 + l16) * kDH;
    qH[sq][0] = *(const bf16x8*)&qsh[qb + qd * 8];
    qH[sq][1] = *(const bf16x8*)&qsh[qb + 32 + qd * 8];
    qL[sq][0] = *(const bf16x8*)&qsl[qb + qd * 8];
    qL[sq][1] = *(const bf16x8*)&qsl[qb + 32 + qd * 8];
  }
  if (tid < 64) qns[tid] = (float)qn[h * kS + s0 + tid];
  const float cc = (float)SC[0];
  f32x4 acco[4];  // [sq]: m = s in sq-tile, n = d in wave's 16-range
#pragma unroll
  for (int i = 0; i < 4; i++) acco[i] = (f32x4){0.f, 0.f, 0.f, 0.f};

  for (int t0 = 0; t0 < kS; t0 += 64) {
    __syncthreads();  // prev phase2 done reading Ah/Al/Ph
    {
      const size_t ksrc = (((size_t)h * kS) + t0 + row) * kDH;
      *(bf16x8*)&Kh[row * LDW + c8]     = *(const bf16x8*)&ksh[ksrc + c8];
      *(bf16x8*)&Kh[row * LDW + c8 + 8] = *(const bf16x8*)&ksh[ksrc + c8 + 8];
      *(bf16x8*)&Kl[row * LDW + c8]     = *(const bf16x8*)&ksl[ksrc + c8];
      *(bf16x8*)&Kl[row * LDW + c8 + 8] = *(const bf16x8*)&ksl[ksrc + c8 + 8];
      const size_t asrc = ((size_t)h * kDH + row) * kS + t0;
      *(bf16x8*)&Ah[row * LDW + c8]     = *(const bf16x8*)&ath[asrc + c8];
      *(bf16x8*)&Ah[row * LDW + c8 + 8] = *(const bf16x8*)&ath[asrc + c8 + 8];
      *(bf16x8*)&Al[row * LDW + c8]     = *(const bf16x8*)&atl[asrc + c8];
      *(bf16x8*)&Al[row * LDW + c8 + 8] = *(const bf16x8*)&atl[asrc + c8 + 8];
    }
    const float knr = (float)kn[h * kS + t0 + wv * 16 + l16];  // lane's t-col norm
    __syncthreads();
    // phase 1: QK^T — wave computes columns [wv*16, +16) for all 64 s rows
    f32x4 accp[4];
#pragma unroll
    for (int i = 0; i < 4; i++) accp[i] = (f32x4){0.f, 0.f, 0.f, 0.f};
#pragma unroll
    for (int kt = 0; kt < 2; kt++) {
      const int ko = kt * 32 + qd * 8;
      const bf16x8 bH = *(const bf16x8*)&Kh[(wv * 16 + l16) * LDW + ko];
      const bf16x8 bL = *(const bf16x8*)&Kl[(wv * 16 + l16) * LDW + ko];
#pragma unroll
      for (int sq = 0; sq < 4; sq++) {
        accp[sq] = __builtin_amdgcn_mfma_f32_16x16x32_bf16(qH[sq][kt], bH, accp[sq], 0, 0, 0);
        accp[sq] = __builtin_amdgcn_mfma_f32_16x16x32_bf16(qL[sq][kt], bH, accp[sq], 0, 0, 0);
        accp[sq] = __builtin_amdgcn_mfma_f32_16x16x32_bf16(qH[sq][kt], bL, accp[sq], 0, 0, 0);
      }
    }
    // exp + write P (own t-columns, all s rows)
#pragma unroll
    for (int sq = 0; sq < 4; sq++) {
#pragma unroll
      for (int r = 0; r < 4; r++) {
        const int srow = sq * 16 + qd * 4 + r;
        const float e2 = fmaf(2.0f, accp[sq][r], -(qns[srow] + knr));
        const float val = __expf(fminf(e2, 0.0f) * cc);
        Ph[srow * LDW + wv * 16 + l16] = (short)kar_f2bf(val);
      }
    }
    __syncthreads();  // P complete before cross-wave reads
    // phase 2: acc += P @ alpha — wave computes columns d in [wv*16, +16)
#pragma unroll
    for (int kt = 0; kt < 2; kt++) {
      const int ko = kt * 32 + qd * 8;
      const bf16x8 bH = *(const bf16x8*)&Ah[(wv * 16 + l16) * LDW + ko];
      const bf16x8 bL = *(const bf16x8*)&Al[(wv * 16 + l16) * LDW + ko];
#pragma unroll
      for (int sq = 0; sq < 4; sq++) {
        const bf16x8 pH = *(const bf16x8*)&Ph[(sq * 16 + l16) * LDW + ko];
        acco[sq] = __builtin_amdgcn_mfma_f32_16x16x32_bf16(pH, bH, acco[sq], 0, 0, 0);
        acco[sq] = __builtin_amdgcn_mfma_f32_16x16x32_bf16(pH, bL, acco[sq], 0, 0, 0);
      }
    }
  }
  // epilogue: d = wv*16 + l16; s = s0 + sq*16 + qd*4 + r
  const int d = wv * 16 + l16;
  if (FINAL) {
#pragma unroll
    for (int sq = 0; sq < 4; sq++) {
#pragma unroll
      for (int r = 0; r < 4; r++) {
        const int s = s0 + sq * 16 + qd * 4 + r;
        short hh, ll; kar_split_bf(acco[sq][r], hh, ll);
        tmph[(size_t)s * kD + h * kDH + d] = hh;
        tmpl[(size_t)s * kD + h * kDH + d] = ll;
      }
    }
  } else {
    const float lamf = (float)SC[1];
#pragma unroll
    for (int sq = 0; sq < 4; sq++) {
#pragma unroll
      for (int r = 0; r < 4; r++) {
        const int s = s0 + sq * 16 + qd * 4 + r;
        const size_t eg = ((size_t)h * kS + s) * kDH + d;
        outp[eg] = v[eg] - (acco[sq][r] + lamf * alpha[eg]);
      }
    }
  }
}

// ================= OLD PATH (R4 fallback) kernels =================
__global__ __launch_bounds__(256) void kar_gemm_qkv_f32_kernel(
    const float* __restrict__ x,
    const float* __restrict__ Wq, const float* __restrict__ Wk, const float* __restrict__ Wv,
    float* __restrict__ q, float* __restrict__ k, float* __restrict__ v) {
  const float* W = (blockIdx.z == 0) ? Wq : (blockIdx.z == 1) ? Wk : Wv;
  float* outp    = (blockIdx.z == 0) ? q  : (blockIdx.z == 1) ? k  : v;
  const int n0 = blockIdx.x * 64;
  const int m0 = blockIdx.y * 64;
  const int tid = threadIdx.x;
  const int tx = tid & 15, ty = tid >> 4;
  __shared__ float As[16][68];
  __shared__ float Bs[16][68];
  double acc[4][4] = {};
  const int lr = tid >> 2;
  const int lk = (tid & 3) * 4;
  const int br = tid >> 4;
  const int bc = (tid & 15) * 4;
  for (int k0 = 0; k0 < kD; k0 += 16) {
    const float4 a4 = *(const float4*)&x[(size_t)(m0 + lr) * kD + k0 + lk];
    const float4 b4 = *(const float4*)&W[(size_t)(k0 + br) * kD + n0 + bc];
    __syncthreads();
    As[lk + 0][lr] = a4.x; As[lk + 1][lr] = a4.y;
    As[lk + 2][lr] = a4.z; As[lk + 3][lr] = a4.w;
    *(float4*)&Bs[br][bc] = b4;
    __syncthreads();
    float c32[4][4] = {};
#pragma unroll
    for (int kk = 0; kk < 16; kk++) {
      const float4 av = *(const float4*)&As[kk][ty * 4];
      const float4 bv = *(const float4*)&Bs[kk][tx * 4];
      const float a_[4] = {av.x, av.y, av.z, av.w};
      const float b_[4] = {bv.x, bv.y, bv.z, bv.w};
#pragma unroll
      for (int i = 0; i < 4; i++)
#pragma unroll
        for (int j = 0; j < 4; j++) c32[i][j] = fmaf(a_[i], b_[j], c32[i][j]);
    }
#pragma unroll
    for (int i = 0; i < 4; i++)
#pragma unroll
      for (int j = 0; j < 4; j++) acc[i][j] += (double)c32[i][j];
  }
  const int h = n0 >> 6;
#pragma unroll
  for (int i = 0; i < 4; i++) {
    const int s = m0 + ty * 4 + i;
    float4 o;
    o.x = (float)acc[i][0]; o.y = (float)acc[i][1];
    o.z = (float)acc[i][2]; o.w = (float)acc[i][3];
    *(float4*)&outp[((size_t)h * kS + s) * kDH + tx * 4] = o;
  }
}

__global__ __launch_bounds__(256) void kar_gemm_plain_kernel(
    const float* __restrict__ A, const float* __restrict__ W, float* __restrict__ C) {
  const int n0 = blockIdx.x * 64;
  const int m0 = blockIdx.y * 64;
  const int tid = threadIdx.x;
  const int tx = tid & 15, ty = tid >> 4;
  __shared__ float As[16][68];
  __shared__ float Bs[16][68];
  double acc[4][4] = {};
  const int lr = tid >> 2;
  const int lk = (tid & 3) * 4;
  const int br = tid >> 4;
  const int bc = (tid & 15) * 4;
  for (int k0 = 0; k0 < kD; k0 += 16) {
    const float4 a4 = *(const float4*)&A[(size_t)(m0 + lr) * kD + k0 + lk];
    const float4 b4 = *(const float4*)&W[(size_t)(k0 + br) * kD + n0 + bc];
    __syncthreads();
    As[lk + 0][lr] = a4.x; As[lk + 1][lr] = a4.y;
    As[lk + 2][lr] = a4.z; As[lk + 3][lr] = a4.w;
    *(float4*)&Bs[br][bc] = b4;
    __syncthreads();
    float c32[4][4] = {};
#pragma unroll
    for (int kk = 0; kk < 16; kk++) {
      const float4 av = *(const float4*)&As[kk][ty * 4];
      const float4 bv = *(const float4*)&Bs[kk][tx * 4];
      const float a_[4] = {av.x, av.y, av.z, av.w};
      const float b_[4] = {bv.x, bv.y, bv.z, bv.w};
#pragma unroll
      for (int i = 0; i < 4; i++)
#pragma unroll
        for (int j = 0; j < 4; j++) c32[i][j] = fmaf(a_[i], b_[j], c32[i][j]);
    }
#pragma unroll
    for (int i = 0; i < 4; i++)
#pragma unroll
      for (int j = 0; j < 4; j++) acc[i][j] += (double)c32[i][j];
  }
#pragma unroll
  for (int i = 0; i < 4; i++) {
    const int s = m0 + ty * 4 + i;
    float4 o;
    o.x = (float)acc[i][0]; o.y = (float)acc[i][1];
    o.z = (float)acc[i][2]; o.w = (float)acc[i][3];
    *(float4*)&C[(size_t)s * kD + n0 + tx * 4] = o;
  }
}

__global__ __launch_bounds__(256) void kar_norms_f32_kernel(const float* __restrict__ q,
                                                            const float* __restrict__ k,
                                                            double* __restrict__ qn,
                                                            double* __restrict__ kn) {
  int o = blockIdx.x * 256 + threadIdx.x;
  const float* src; double* dst; int p;
  if (o < kH * kS) { src = q; dst = qn; p = o; }
  else             { src = k; dst = kn; p = o - kH * kS; }
  const float* rowp = src + (size_t)p * kDH;
  double s = 0.0;
  for (int i = 0; i < kDH; i += 4) {
    float4 x4 = *(const float4*)&rowp[i];
    s += (double)x4.x * (double)x4.x + (double)x4.y * (double)x4.y +
         (double)x4.z * (double)x4.z + (double)x4.w * (double)x4.w;
  }
  dst[p] = s;
}

__global__ __launch_bounds__(256) void kar_diagp_f32_kernel(
    const float* __restrict__ q, const float* __restrict__ k,
    const double* __restrict__ qn, const double* __restrict__ kn,
    const double* __restrict__ SC, const float* __restrict__ dsc,
    const float* __restrict__ reg, double* __restrict__ dgp) {
  int o = blockIdx.x * 256 + threadIdx.x;
  int h = o >> 11;
  const float* qp = q + (size_t)o * kDH;
  const float* kp = k + (size_t)o * kDH;
  double dot = 0.0;
  for (int i = 0; i < kDH; i++) dot += (double)qp[i] * (double)kp[i];
  double dist = fmax(qn[o] + kn[o] - 2.0 * dot, 0.0);
  double Kss = exp(-dist * SC[0]);
  double sp  = log1p(exp(Kss));
  dgp[o] = sp * (double)dsc[h] + (double)reg[0];
}

template <bool FINAL>
__global__ __launch_bounds__(256, 2) void kar_mfma_iterA_kernel(
    const float* __restrict__ q, const float* __restrict__ k,
    const float* __restrict__ alpha, const float* __restrict__ v,
    const double* __restrict__ qn, const double* __restrict__ kn,
    const double* __restrict__ SC, float* __restrict__ outp) {
  constexpr int LDW = 72;
  __shared__ short Qh[64 * LDW], Ql[64 * LDW];
  __shared__ short Kh[64 * LDW], Kl[64 * LDW];
  __shared__ short Ph[64 * LDW], Pl[64 * LDW];
  __shared__ short Ah[64 * LDW], Al[64 * LDW];
  __shared__ float qns[64], kns[64];
  const int h   = blockIdx.y;
  const int s0  = blockIdx.x * 64;
  const int tid = threadIdx.x;
  const int lane = tid & 63;
  const int wv   = tid >> 6;
  const int l16  = lane & 15;
  const int qd   = lane >> 4;
  const int m16  = wv * 16;
  const float* qh = q + ((size_t)h * kS + s0) * kDH;
  const float* kh = k + (size_t)h * kS * kDH;
  const float* ah = alpha + (size_t)h * kS * kDH;
  {
    const int row = tid >> 4;
    const int c4  = (tid & 15) * 4;
#pragma unroll
    for (int rep = 0; rep < 4; rep++) {
      const int r = rep * 16 + row;
      const float4 a = *(const float4*)&qh[(size_t)r * kDH + c4];
      short h0, l0, h1, l1, h2, l2, h3, l3;
      kar_split_bf(a.x, h0, l0); kar_split_bf(a.y, h1, l1);
      kar_split_bf(a.z, h2, l2); kar_split_bf(a.w, h3, l3);
      *(short4*)&Qh[r * LDW + c4] = make_short4(h0, h1, h2, h3);
      *(short4*)&Ql[r * LDW + c4] = make_short4(l0, l1, l2, l3);
    }
    if (tid < 64) qns[tid] = (float)qn[h * kS + s0 + tid];
  }
  const float cc = (float)SC[0];
  f32x4 acco[4];
#pragma unroll
  for (int i = 0; i < 4; i++) acco[i] = (f32x4){0.f, 0.f, 0.f, 0.f};
  for (int t0 = 0; t0 < kS; t0 += 64) {
    __syncthreads();
    {
      const int row = tid >> 4;
      const int c4  = (tid & 15) * 4;
#pragma unroll
      for (int rep = 0; rep < 4; rep++) {
        const int r = rep * 16 + row;
        const float4 b = *(const float4*)&kh[(size_t)(t0 + r) * kDH + c4];
        short h0, l0, h1, l1, h2, l2, h3, l3;
        kar_split_bf(b.x, h0, l0); kar_split_bf(b.y, h1, l1);
        kar_split_bf(b.z, h2, l2); kar_split_bf(b.w, h3, l3);
        *(short4*)&Kh[r * LDW + c4] = make_short4(h0, h1, h2, h3);
        *(short4*)&Kl[r * LDW + c4] = make_short4(l0, l1, l2, l3);
        const float4 av = *(const float4*)&ah[(size_t)(t0 + r) * kDH + c4];
        kar_split_bf(av.x, h0, l0); kar_split_bf(av.y, h1, l1);
        kar_split_bf(av.z, h2, l2); kar_split_bf(av.w, h3, l3);
        Ah[(c4 + 0) * LDW + r] = h0; Al[(c4 + 0) * LDW + r] = l0;
        Ah[(c4 + 1) * LDW + r] = h1; Al[(c4 + 1) * LDW + r] = l1;
        Ah[(c4 + 2) * LDW + r] = h2; Al[(c4 + 2) * LDW + r] = l2;
        Ah[(c4 + 3) * LDW + r] = h3; Al[(c4 + 3) * LDW + r] = l3;
      }
      if (tid < 64) kns[tid] = (float)kn[h * kS + t0 + tid];
    }
    __syncthreads();
    f32x4 accp[4];
#pragma unroll
    for (int i = 0; i < 4; i++) accp[i] = (f32x4){0.f, 0.f, 0.f, 0.f};
#pragma unroll
    for (int kt = 0; kt < 2; kt++) {
      const int ko = kt * 32 + qd * 8;
      const bf16x8 aH = *(const bf16x8*)&Qh[(m16 + l16) * LDW + ko];
      const bf16x8 aL = *(const bf16x8*)&Ql[(m16 + l16) * LDW + ko];
#pragma unroll
      for (int nt = 0; nt < 4; nt++) {
        const bf16x8 bH = *(const bf16x8*)&Kh[(nt * 16 + l16) * LDW + ko];
        const bf16x8 bL = *(const bf16x8*)&Kl[(nt * 16 + l16) * LDW + ko];
        accp[nt] = __builtin_amdgcn_mfma_f32_16x16x32_bf16(aH, bH, accp[nt], 0, 0, 0);
        accp[nt] = __builtin_amdgcn_mfma_f32_16x16x32_bf16(aL, bH, accp[nt], 0, 0, 0);
        accp[nt] = __builtin_amdgcn_mfma_f32_16x16x32_bf16(aH, bL, accp[nt], 0, 0, 0);
      }
    }
#pragma unroll
    for (int nt = 0; nt < 4; nt++) {
      const int tcol = nt * 16 + l16;
      const float kv = kns[tcol];
#pragma unroll
      for (int r = 0; r < 4; r++) {
        const int srow = m16 + qd * 4 + r;
        const float e2 = fmaf(2.0f, accp[nt][r], -(qns[srow] + kv));
        const float val = __expf(fminf(e2, 0.0f) * cc);
        short hb, lb; kar_split_bf(val, hb, lb);
        Ph[srow * LDW + tcol] = hb;
        Pl[srow * LDW + tcol] = lb;
      }
    }
#pragma unroll
    for (int kt = 0; kt < 2; kt++) {
      const int ko = kt * 32 + qd * 8;
      const bf16x8 pH = *(const bf16x8*)&Ph[(m16 + l16) * LDW + ko];
      const bf16x8 pL = *(const bf16x8*)&Pl[(m16 + l16) * LDW + ko];
#pragma unroll
      for (int dt = 0; dt < 4; dt++) {
        const bf16x8 bH = *(const bf16x8*)&Ah[(dt * 16 + l16) * LDW + ko];
        const bf16x8 bL = *(const bf16x8*)&Al[(dt * 16 + l16) * LDW + ko];
        acco[dt] = __builtin_amdgcn_mfma_f32_16x16x32_bf16(pH, bH, acco[dt], 0, 0, 0);
        acco[dt] = __builtin_amdgcn_mfma_f32_16x16x32_bf16(pL, bH, acco[dt], 0, 0, 0);
        acco[dt] = __builtin_amdgcn_mfma_f32_16x16x32_bf16(pH, bL, acco[dt], 0, 0, 0);
      }
    }
  }
  if (FINAL) {
#pragma unroll
    for (int dt = 0; dt < 4; dt++) {
#pragma unroll
      for (int r = 0; r < 4; r++) {
        const int s = s0 + m16 + qd * 4 + r;
        const int d = dt * 16 + l16;
        outp[(size_t)s * kD + h * kDH + d] = acco[dt][r];
      }
    }
  } else {
    const float lamf = (float)SC[1];
#pragma unroll
    for (int dt = 0; dt < 4; dt++) {
#pragma unroll
      for (int r = 0; r < 4; r++) {
        const int s = s0 + m16 + qd * 4 + r;
        const int d = dt * 16 + l16;
        const size_t eg = ((size_t)h * kS + s) * kDH + d;
        outp[eg] = v[eg] - (acco[dt][r] + lamf * alpha[eg]);
      }
    }
  }
}

extern "C" void kernel_launch(void* const* d_in, const int* in_sizes, int n_in,
                              void* d_out, int out_size, void* d_ws, size_t ws_size,
                              hipStream_t stream) {
  (void)in_sizes; (void)n_in; (void)out_size;
  const float* x    = (const float*)d_in[0];
  const float* Wq   = (const float*)d_in[1];
  const float* Wk   = (const float*)d_in[2];
  const float* Wv   = (const float*)d_in[3];
  const float* Wo   = (const float*)d_in[4];
  const float* bw   = (const float*)d_in[5];
  const float* dsc  = (const float*)d_in[6];
  const float* pe   = (const float*)d_in[7];
  const float* hp   = (const float*)d_in[8];
  const float* reg  = (const float*)d_in[9];
  const float* lreg = (const float*)d_in[10];
  float* out = (float*)d_out;

  char* w = (char*)d_ws;
  size_t off = 0;
  auto take = [&](size_t bytes) -> void* {
    void* p = w + off;
    off += (bytes + 255) & ~(size_t)255;
    return p;
  };
  const size_t HSD = (size_t)kH * kS * kDH;  // 2M elements

  // ---- new-path layout ----
  float*  v_    = (float*)take(HSD * 4);
  float*  alpha = (float*)take(HSD * 4);
  float*  rbuf  = (float*)take(HSD * 4);
  short*  qsh   = (short*)take(HSD * 2);
  short*  qsl   = (short*)take(HSD * 2);
  short*  ksh   = (short*)take(HSD * 2);
  short*  ksl   = (short*)take(HSD * 2);
  short*  ath   = (short*)take(HSD * 2);
  short*  atl   = (short*)take(HSD * 2);
  short*  xh    = (short*)take((size_t)kS * kD * 2);  // reused as tmph
  short*  xl    = (short*)take((size_t)kS * kD * 2);  // reused as tmpl
  short*  WTh   = (short*)take((size_t)4 * kD * kD * 2);
  short*  WTl   = (short*)take((size_t)4 * kD * kD * 2);
  double* qn    = (double*)take((size_t)kH * kS * 8);
  double* kn    = (double*)take((size_t)kH * kS * 8);
  double* dgp   = (double*)take((size_t)kH * kS * 8);
  float*  U     = (float*)take((size_t)kH * kS * kR * 4);
  double* utr   = (double*)take((size_t)kH * kR * kDH * 8);
  double* utrp  = (double*)take((size_t)kH * 16 * kR * kDH * 8);
  double* SC    = (double*)take(256);
  const size_t need_new = off;

  if (ws_size >= need_new) {
    // ================= NEW PATH =================
    kar_scalars_kernel<<<1, 64, 0, stream>>>(bw, lreg, SC);
    kar_xsplit_kernel<<<2048, 256, 0, stream>>>(x, xh, xl);
    kar_wsplit_kernel<<<dim3(16, 16, 4), 256, 0, stream>>>(Wq, Wk, Wv, Wo, WTh, WTl);
    kar_mfma_gemm_qkv_kernel<<<dim3(16, 16, 3), 256, 0, stream>>>(
        xh, xl, WTh, WTl, v_, qsh, qsl, ksh, ksl);
    kar_norms2_kernel<<<256, 256, 0, stream>>>(qsh, qsl, ksh, ksl, qn, kn);
    kar_u_kernel<<<2048, 256, 0, stream>>>(pe, hp, U);
    kar_diagp2_kernel<<<128, 256, 0, stream>>>(qsh, qsl, ksh, ksl, qn, kn, SC, dsc, reg, dgp);

    // it 0: alpha == 0 -> r == v
    kar_utr_partial_kernel<<<dim3(16, kH), 256, 0, stream>>>(U, v_, utrp);
    kar_utr_reduce_kernel<<<64, 256, 0, stream>>>(utrp, utr);
    kar_update_t_kernel<<<dim3(32, kH), 256, 0, stream>>>(v_, dgp, U, utr, alpha, ath, atl, 1);

    for (int it = 1; it < 5; it++) {
      kar_mfma_iter4_kernel<false><<<dim3(32, kH), 256, 0, stream>>>(
          qsh, qsl, ksh, ksl, ath, atl, alpha, v_, qn, kn, SC, rbuf, nullptr, nullptr);
      kar_utr_partial_kernel<<<dim3(16, kH), 256, 0, stream>>>(U, rbuf, utrp);
      kar_utr_reduce_kernel<<<64, 256, 0, stream>>>(utrp, utr);
      kar_update_t_kernel<<<dim3(32, kH), 256, 0, stream>>>(rbuf, dgp, U, utr, alpha, ath, atl, 0);
    }

    kar_mfma_iter4_kernel<true><<<dim3(32, kH), 256, 0, stream>>>(
        qsh, qsl, ksh, ksl, ath, atl, alpha, v_, qn, kn, SC, rbuf, xh, xl);  // xh/xl = tmph/tmpl
    kar_mfma_gemm_wo_kernel<<<dim3(16, 16), 256, 0, stream>>>(
        xh, xl, WTh + (size_t)3 * kD * kD, WTl + (size_t)3 * kD * kD, out);
  } else {
    // ================= OLD PATH (R4) =================
    size_t off2 = 0;
    auto take2 = [&](size_t bytes) -> void* {
      void* p = w + off2;
      off2 += (bytes + 255) & ~(size_t)255;
      return p;
    };
    float*  q2    = (float*)take2(HSD * 4);
    float*  k2    = (float*)take2(HSD * 4);
    float*  v2    = (float*)take2(HSD * 4);
    float*  al2   = (float*)take2(HSD * 4);
    float*  rb2   = (float*)take2(HSD * 4);
    float*  tmp2  = (float*)take2((size_t)kS * kD * 4);
    double* qn2   = (double*)take2((size_t)kH * kS * 8);
    double* kn2   = (double*)take2((size_t)kH * kS * 8);
    double* dgp2  = (double*)take2((size_t)kH * kS * 8);
    float*  U2    = (float*)take2((size_t)kH * kS * kR * 4);
    double* utr2  = (double*)take2((size_t)kH * kR * kDH * 8);
    double* utrp2 = (double*)take2((size_t)kH * 16 * kR * kDH * 8);
    double* SC2   = (double*)take2(256);

    kar_scalars_kernel<<<1, 64, 0, stream>>>(bw, lreg, SC2);
    kar_gemm_qkv_f32_kernel<<<dim3(16, 32, 3), 256, 0, stream>>>(x, Wq, Wk, Wv, q2, k2, v2);
    kar_norms_f32_kernel<<<256, 256, 0, stream>>>(q2, k2, qn2, kn2);
    kar_u_kernel<<<2048, 256, 0, stream>>>(pe, hp, U2);
    kar_diagp_f32_kernel<<<128, 256, 0, stream>>>(q2, k2, qn2, kn2, SC2, dsc, reg, dgp2);

    kar_utr_partial_kernel<<<dim3(16, kH), 256, 0, stream>>>(U2, v2, utrp2);
    kar_utr_reduce_kernel<<<64, 256, 0, stream>>>(utrp2, utr2);
    kar_update_kernel<<<8192, 256, 0, stream>>>(v2, dgp2, U2, utr2, al2, 1);

    for (int it = 1; it < 5; it++) {
      kar_mfma_iterA_kernel<false><<<dim3(32, kH), 256, 0, stream>>>(
          q2, k2, al2, v2, qn2, kn2, SC2, rb2);
      kar_utr_partial_kernel<<<dim3(16, kH), 256, 0, stream>>>(U2, rb2, utrp2);
      kar_utr_reduce_kernel<<<64, 256, 0, stream>>>(utrp2, utr2);
      kar_update_kernel<<<8192, 256, 0, stream>>>(rb2, dgp2, U2, utr2, al2, 0);
    }
    kar_mfma_iterA_kernel<true><<<dim3(32, kH), 256, 0, stream>>>(
        q2, k2, al2, v2, qn2, kn2, SC2, tmp2);
    kar_gemm_plain_kernel<<<dim3(16, 32), 256, 0, stream>>>(tmp2, Wo, out);
  }
}

// Round 9
// 612.620 us; speedup vs baseline: 3.9872x; 1.1320x over previous
//
#include <hip/hip_runtime.h>
#include <cstdint>
#include <cstddef>

constexpr int kS  = 2048;
constexpr int kD  = 1024;
constexpr int kH  = 16;
constexpr int kDH = 64;
constexpr int kR  = 16;

typedef __attribute__((ext_vector_type(8))) short bf16x8;
typedef __attribute__((ext_vector_type(4))) float f32x4;

__device__ __forceinline__ unsigned short kar_f2bf(float x) {
  unsigned u = __float_as_uint(x);
  return (unsigned short)((u + 0x7FFFu + ((u >> 16) & 1u)) >> 16);
}
__device__ __forceinline__ float kar_bf2f(short h) {
  return __uint_as_float((unsigned)(unsigned short)h << 16);
}
__device__ __forceinline__ void kar_split_bf(float x, short& hi, short& lo) {
  unsigned short h = kar_f2bf(x);
  float hf = __uint_as_float((unsigned)h << 16);
  hi = (short)h;
  lo = (short)kar_f2bf(x - hf);
}

// ---------------- scalars ----------------
__global__ __launch_bounds__(64) void kar_scalars_kernel(const float* __restrict__ bw,
                                                         const float* __restrict__ lreg,
                                                         double* __restrict__ SC) {
  if (threadIdx.x == 0) {
    double b = log1p(exp((double)bw[0])) + 1e-6;
    SC[0] = 1.0 / (2.0 * b * b);
    SC[1] = log1p(exp((double)lreg[0]));
  }
}

// ---------------- U[h][s][p] ----------------
__global__ __launch_bounds__(256) void kar_u_kernel(const float* __restrict__ pe,
                                                    const float* __restrict__ hp,
                                                    float* __restrict__ U) {
  int o = blockIdx.x * 256 + threadIdx.x;
  int r = o & 15, s = (o >> 4) & 2047, h = o >> 15;
  double acc = 0.0;
#pragma unroll
  for (int rp = 0; rp < kR; rp++)
    acc += (double)pe[s * kR + rp] * (double)hp[((h * kR) + rp) * kR + r];
  U[o] = (float)acc;
}

// ---------------- ut_r partials (64-row slices, 32 slots) / reduce ----------------
__global__ __launch_bounds__(256) void kar_utr_partial_kernel(
    const float* __restrict__ Ubuf, const float* __restrict__ rbuf,
    double* __restrict__ utrp) {
  const int h  = blockIdx.y;
  const int sb = blockIdx.x * 64;
  const int t  = threadIdx.x;
  __shared__ float Uch[32][16];
  __shared__ float Rch[32][64];
  double acc[4] = {};
  for (int cs = 0; cs < 64; cs += 32) {
    __syncthreads();
    if (t < 128) {
      const int i = t >> 2, f = (t & 3) * 4;
      *(float4*)&Uch[i][f] = *(const float4*)&Ubuf[((size_t)(h * kS) + sb + cs + i) * kR + f];
    }
#pragma unroll
    for (int rep = 0; rep < 2; rep++) {
      const int e = t + rep * 256;
      const int i = e >> 4, c = (e & 15) * 4;
      *(float4*)&Rch[i][c] = *(const float4*)&rbuf[((size_t)(h * kS) + sb + cs + i) * kDH + c];
    }
    __syncthreads();
    for (int i = 0; i < 32; i++) {
#pragma unroll
      for (int rep = 0; rep < 4; rep++) {
        const int p = t + rep * 256;
        const int r = p >> 6, d = p & 63;
        acc[rep] += (double)Uch[i][r] * (double)Rch[i][d];
      }
    }
  }
#pragma unroll
  for (int rep = 0; rep < 4; rep++) {
    const int p = t + rep * 256;
    const int r = p >> 6, d = p & 63;
    utrp[(((size_t)(h * 32) + blockIdx.x) * kR + r) * kDH + d] = acc[rep];
  }
}

__global__ __launch_bounds__(256) void kar_utr_reduce_kernel(const double* __restrict__ utrp,
                                                             double* __restrict__ utr) {
  int o = blockIdx.x * 256 + threadIdx.x;
  int h = o >> 10, rd = o & 1023;
  double s = 0.0;
#pragma unroll
  for (int j = 0; j < 32; j++) s += utrp[(size_t)h * 32768 + (size_t)j * 1024 + rd];
  utr[o] = s;
}

// old elementwise update (fallback path only)
__global__ __launch_bounds__(256) void kar_update_kernel(
    const float* __restrict__ rsrc, const double* __restrict__ dgp,
    const float* __restrict__ Ubuf, const double* __restrict__ utr,
    float* __restrict__ alpha, int first) {
  int e = blockIdx.x * 256 + threadIdx.x;
  const int d = e & 63;
  const int s = (e >> 6) & 2047;
  const int h = e >> 17;
  const double rv = (double)rsrc[e];
  const double dp = dgp[h * kS + s];
  const float*  Us = &Ubuf[((size_t)(h * kS) + s) * kR];
  const double* uh = &utr[(size_t)h * kR * kDH];
  double sum = 0.0;
#pragma unroll
  for (int ri = 0; ri < kR; ri++) sum += (double)Us[ri] * uh[ri * kDH + d];
  const double p = rv * dp + sum;
  const double an = (first ? 0.0 : (double)alpha[e]) + p;
  alpha[e] = (float)an;
}

// fused update + transpose/split: alpha fp32 + ath [h][d][s] in one pass
__global__ __launch_bounds__(256) void kar_update_t_kernel(
    const float* __restrict__ rsrc, const double* __restrict__ dgp,
    const float* __restrict__ Ubuf, const double* __restrict__ utr,
    float* __restrict__ alpha, short* __restrict__ ath, int first) {
  const int h = blockIdx.y, s0 = blockIdx.x * 64;
  __shared__ float T[64][65];
  const int t = threadIdx.x;
  const int r16 = t >> 4, c4 = (t & 15) * 4;
  const double* uh = &utr[(size_t)h * kR * kDH];
#pragma unroll
  for (int it = 0; it < 4; it++) {
    const int row = it * 16 + r16;
    const int s = s0 + row;
    const size_t eg = ((size_t)h * kS + s) * kDH + c4;
    const float4 rv4 = *(const float4*)&rsrc[eg];
    const double dp = dgp[h * kS + s];
    const float* Us = &Ubuf[((size_t)h * kS + s) * kR];
    double sum0 = 0.0, sum1 = 0.0, sum2 = 0.0, sum3 = 0.0;
#pragma unroll
    for (int ri = 0; ri < kR; ri++) {
      const double u = (double)Us[ri];
      const double* ur = &uh[ri * kDH + c4];
      sum0 += u * ur[0]; sum1 += u * ur[1];
      sum2 += u * ur[2]; sum3 += u * ur[3];
    }
    double a0 = (first ? 0.0 : (double)alpha[eg + 0]) + ((double)rv4.x * dp + sum0);
    double a1 = (first ? 0.0 : (double)alpha[eg + 1]) + ((double)rv4.y * dp + sum1);
    double a2 = (first ? 0.0 : (double)alpha[eg + 2]) + ((double)rv4.z * dp + sum2);
    double a3 = (first ? 0.0 : (double)alpha[eg + 3]) + ((double)rv4.w * dp + sum3);
    float4 o;
    o.x = (float)a0; o.y = (float)a1; o.z = (float)a2; o.w = (float)a3;
    *(float4*)&alpha[eg] = o;
    T[row][c4] = o.x; T[row][c4 + 1] = o.y; T[row][c4 + 2] = o.z; T[row][c4 + 3] = o.w;
  }
  __syncthreads();
#pragma unroll
  for (int it = 0; it < 4; it++) {
    int d = it * 16 + r16;
    float v0 = T[c4][d], v1 = T[c4 + 1][d], v2 = T[c4 + 2][d], v3 = T[c4 + 3][d];
    *(short4*)&ath[((size_t)h * kDH + d) * kS + s0 + c4] =
        make_short4((short)kar_f2bf(v0), (short)kar_f2bf(v1),
                    (short)kar_f2bf(v2), (short)kar_f2bf(v3));
  }
}

// ================= NEW PATH kernels =================

__global__ __launch_bounds__(256) void kar_xsplit_kernel(const float* __restrict__ x,
                                                         short* __restrict__ xh,
                                                         short* __restrict__ xl) {
  size_t e = ((size_t)blockIdx.x * 256 + threadIdx.x) * 4;
  float4 a = *(const float4*)&x[e];
  short h0, l0, h1, l1, h2, l2, h3, l3;
  kar_split_bf(a.x, h0, l0); kar_split_bf(a.y, h1, l1);
  kar_split_bf(a.z, h2, l2); kar_split_bf(a.w, h3, l3);
  *(short4*)&xh[e] = make_short4(h0, h1, h2, h3);
  *(short4*)&xl[e] = make_short4(l0, l1, l2, l3);
}

__global__ __launch_bounds__(256) void kar_wsplit_kernel(
    const float* __restrict__ Wq, const float* __restrict__ Wk,
    const float* __restrict__ Wv, const float* __restrict__ Wo,
    short* __restrict__ WTh, short* __restrict__ WTl) {
  const float* W = (blockIdx.z == 0) ? Wq : (blockIdx.z == 1) ? Wk
                 : (blockIdx.z == 2) ? Wv : Wo;
  short* oh = WTh + (size_t)blockIdx.z * kD * kD;
  short* ol = WTl + (size_t)blockIdx.z * kD * kD;
  const int n0 = blockIdx.x * 64, k0 = blockIdx.y * 64;
  __shared__ float T[64][65];
  const int t = threadIdx.x;
  const int r16 = t >> 4, c4 = (t & 15) * 4;
#pragma unroll
  for (int it = 0; it < 4; it++) {
    int r = it * 16 + r16;
    float4 a = *(const float4*)&W[(size_t)(k0 + r) * kD + n0 + c4];
    T[r][c4] = a.x; T[r][c4 + 1] = a.y; T[r][c4 + 2] = a.z; T[r][c4 + 3] = a.w;
  }
  __syncthreads();
#pragma unroll
  for (int it = 0; it < 4; it++) {
    int n = it * 16 + r16;
    float v0 = T[c4][n], v1 = T[c4 + 1][n], v2 = T[c4 + 2][n], v3 = T[c4 + 3][n];
    short h0, l0, h1, l1, h2, l2, h3, l3;
    kar_split_bf(v0, h0, l0); kar_split_bf(v1, h1, l1);
    kar_split_bf(v2, h2, l2); kar_split_bf(v3, h3, l3);
    *(short4*)&oh[(size_t)(n0 + n) * kD + k0 + c4] = make_short4(h0, h1, h2, h3);
    *(short4*)&ol[(size_t)(n0 + n) * kD + k0 + c4] = make_short4(l0, l1, l2, l3);
  }
}

// MFMA split-bf16 GEMM: QKV. z=0,1: split dumps q/k; z=2: v fp32.
__global__ __launch_bounds__(256) void kar_mfma_gemm_qkv_kernel(
    const short* __restrict__ xh, const short* __restrict__ xl,
    const short* __restrict__ WTh, const short* __restrict__ WTl,
    float* __restrict__ v,
    short* __restrict__ qsh, short* __restrict__ qsl,
    short* __restrict__ ksh, short* __restrict__ ksl) {
  const int z = blockIdx.z;
  const short* Bh = WTh + (size_t)z * kD * kD;
  const short* Bl = WTl + (size_t)z * kD * kD;
  const int n0 = blockIdx.x * 64;
  const int m0 = blockIdx.y * 128;
  constexpr int LW = 40;
  __shared__ short Xh[128 * LW], Xl[128 * LW], Wh[64 * LW], Wl[64 * LW];
  const int t = threadIdx.x, lane = t & 63, wv = t >> 6;
  const int wm = wv >> 1, wn = wv & 1, l16 = lane & 15, qd = lane >> 4;
  f32x4 acc[4][2];
#pragma unroll
  for (int i = 0; i < 4; i++)
#pragma unroll
    for (int j = 0; j < 2; j++) acc[i][j] = (f32x4){0.f, 0.f, 0.f, 0.f};
  const int xrow = t >> 1, xc = (t & 1) * 16;
  for (int k0 = 0; k0 < kD; k0 += 32) {
    __syncthreads();
    {
      const size_t xs = (size_t)(m0 + xrow) * kD + k0 + xc;
      *(bf16x8*)&Xh[xrow * LW + xc]     = *(const bf16x8*)&xh[xs];
      *(bf16x8*)&Xh[xrow * LW + xc + 8] = *(const bf16x8*)&xh[xs + 8];
      *(bf16x8*)&Xl[xrow * LW + xc]     = *(const bf16x8*)&xl[xs];
      *(bf16x8*)&Xl[xrow * LW + xc + 8] = *(const bf16x8*)&xl[xs + 8];
    }
    if (t < 128) {
      const int wrow = t >> 1, wc = (t & 1) * 16;
      const size_t wsrc = (size_t)(n0 + wrow) * kD + k0 + wc;
      *(bf16x8*)&Wh[wrow * LW + wc]     = *(const bf16x8*)&Bh[wsrc];
      *(bf16x8*)&Wh[wrow * LW + wc + 8] = *(const bf16x8*)&Bh[wsrc + 8];
    } else {
      const int t2 = t - 128, wrow = t2 >> 1, wc = (t2 & 1) * 16;
      const size_t wsrc = (size_t)(n0 + wrow) * kD + k0 + wc;
      *(bf16x8*)&Wl[wrow * LW + wc]     = *(const bf16x8*)&Bl[wsrc];
      *(bf16x8*)&Wl[wrow * LW + wc + 8] = *(const bf16x8*)&Bl[wsrc + 8];
    }
    __syncthreads();
    bf16x8 bH[2], bL[2];
#pragma unroll
    for (int ni = 0; ni < 2; ni++) {
      const int rn = wn * 32 + ni * 16 + l16;
      bH[ni] = *(const bf16x8*)&Wh[rn * LW + qd * 8];
      bL[ni] = *(const bf16x8*)&Wl[rn * LW + qd * 8];
    }
#pragma unroll
    for (int mi = 0; mi < 4; mi++) {
      const int rm = wm * 64 + mi * 16 + l16;
      const bf16x8 aH = *(const bf16x8*)&Xh[rm * LW + qd * 8];
      const bf16x8 aL = *(const bf16x8*)&Xl[rm * LW + qd * 8];
#pragma unroll
      for (int ni = 0; ni < 2; ni++) {
        acc[mi][ni] = __builtin_amdgcn_mfma_f32_16x16x32_bf16(aH, bH[ni], acc[mi][ni], 0, 0, 0);
        acc[mi][ni] = __builtin_amdgcn_mfma_f32_16x16x32_bf16(aL, bH[ni], acc[mi][ni], 0, 0, 0);
        acc[mi][ni] = __builtin_amdgcn_mfma_f32_16x16x32_bf16(aH, bL[ni], acc[mi][ni], 0, 0, 0);
      }
    }
  }
  const int h = blockIdx.x;
#pragma unroll
  for (int mi = 0; mi < 4; mi++)
#pragma unroll
    for (int ni = 0; ni < 2; ni++) {
      const int d = wn * 32 + ni * 16 + l16;
#pragma unroll
      for (int r = 0; r < 4; r++) {
        const int s = m0 + wm * 64 + mi * 16 + qd * 4 + r;
        const float val = acc[mi][ni][r];
        const size_t idx = (((size_t)h * kS) + s) * kDH + d;
        if (z == 2) {
          v[idx] = val;
        } else {
          short hh, ll; kar_split_bf(val, hh, ll);
          if (z == 0) { qsh[idx] = hh; qsl[idx] = ll; }
          else        { ksh[idx] = hh; ksl[idx] = ll; }
        }
      }
    }
}

// MFMA split-bf16 GEMM: out = tmp @ Wo
__global__ __launch_bounds__(256) void kar_mfma_gemm_wo_kernel(
    const short* __restrict__ th, const short* __restrict__ tl,
    const short* __restrict__ Bh, const short* __restrict__ Bl,
    float* __restrict__ outp) {
  const int n0 = blockIdx.x * 64;
  const int m0 = blockIdx.y * 128;
  constexpr int LW = 40;
  __shared__ short Xh[128 * LW], Xl[128 * LW], Wh[64 * LW], Wl[64 * LW];
  const int t = threadIdx.x, lane = t & 63, wv = t >> 6;
  const int wm = wv >> 1, wn = wv & 1, l16 = lane & 15, qd = lane >> 4;
  f32x4 acc[4][2];
#pragma unroll
  for (int i = 0; i < 4; i++)
#pragma unroll
    for (int j = 0; j < 2; j++) acc[i][j] = (f32x4){0.f, 0.f, 0.f, 0.f};
  const int xrow = t >> 1, xc = (t & 1) * 16;
  for (int k0 = 0; k0 < kD; k0 += 32) {
    __syncthreads();
    {
      const size_t xs = (size_t)(m0 + xrow) * kD + k0 + xc;
      *(bf16x8*)&Xh[xrow * LW + xc]     = *(const bf16x8*)&th[xs];
      *(bf16x8*)&Xh[xrow * LW + xc + 8] = *(const bf16x8*)&th[xs + 8];
      *(bf16x8*)&Xl[xrow * LW + xc]     = *(const bf16x8*)&tl[xs];
      *(bf16x8*)&Xl[xrow * LW + xc + 8] = *(const bf16x8*)&tl[xs + 8];
    }
    if (t < 128) {
      const int wrow = t >> 1, wc = (t & 1) * 16;
      const size_t wsrc = (size_t)(n0 + wrow) * kD + k0 + wc;
      *(bf16x8*)&Wh[wrow * LW + wc]     = *(const bf16x8*)&Bh[wsrc];
      *(bf16x8*)&Wh[wrow * LW + wc + 8] = *(const bf16x8*)&Bh[wsrc + 8];
    } else {
      const int t2 = t - 128, wrow = t2 >> 1, wc = (t2 & 1) * 16;
      const size_t wsrc = (size_t)(n0 + wrow) * kD + k0 + wc;
      *(bf16x8*)&Wl[wrow * LW + wc]     = *(const bf16x8*)&Bl[wsrc];
      *(bf16x8*)&Wl[wrow * LW + wc + 8] = *(const bf16x8*)&Bl[wsrc + 8];
    }
    __syncthreads();
    bf16x8 bH[2], bL[2];
#pragma unroll
    for (int ni = 0; ni < 2; ni++) {
      const int rn = wn * 32 + ni * 16 + l16;
      bH[ni] = *(const bf16x8*)&Wh[rn * LW + qd * 8];
      bL[ni] = *(const bf16x8*)&Wl[rn * LW + qd * 8];
    }
#pragma unroll
    for (int mi = 0; mi < 4; mi++) {
      const int rm = wm * 64 + mi * 16 + l16;
      const bf16x8 aH = *(const bf16x8*)&Xh[rm * LW + qd * 8];
      const bf16x8 aL = *(const bf16x8*)&Xl[rm * LW + qd * 8];
#pragma unroll
      for (int ni = 0; ni < 2; ni++) {
        acc[mi][ni] = __builtin_amdgcn_mfma_f32_16x16x32_bf16(aH, bH[ni], acc[mi][ni], 0, 0, 0);
        acc[mi][ni] = __builtin_amdgcn_mfma_f32_16x16x32_bf16(aL, bH[ni], acc[mi][ni], 0, 0, 0);
        acc[mi][ni] = __builtin_amdgcn_mfma_f32_16x16x32_bf16(aH, bL[ni], acc[mi][ni], 0, 0, 0);
      }
    }
  }
#pragma unroll
  for (int mi = 0; mi < 4; mi++)
#pragma unroll
    for (int ni = 0; ni < 2; ni++) {
      const int col = n0 + wn * 32 + ni * 16 + l16;
#pragma unroll
      for (int r = 0; r < 4; r++) {
        const int s = m0 + wm * 64 + mi * 16 + qd * 4 + r;
        outp[(size_t)s * kD + col] = acc[mi][ni][r];
      }
    }
}

// norms from splits
__global__ __launch_bounds__(256) void kar_norms2_kernel(
    const short* __restrict__ qsh, const short* __restrict__ qsl,
    const short* __restrict__ ksh, const short* __restrict__ ksl,
    double* __restrict__ qn, double* __restrict__ kn) {
  int o = blockIdx.x * 256 + threadIdx.x;
  const short *sh, *sl; double* dst; int p;
  if (o < kH * kS) { sh = qsh; sl = qsl; dst = qn; p = o; }
  else             { sh = ksh; sl = ksl; dst = kn; p = o - kH * kS; }
  const short* rh = sh + (size_t)p * kDH;
  const short* rl = sl + (size_t)p * kDH;
  double s = 0.0;
  for (int i = 0; i < kDH; i += 4) {
    short4 a = *(const short4*)&rh[i];
    short4 b = *(const short4*)&rl[i];
    double e0 = (double)kar_bf2f(a.x) + (double)kar_bf2f(b.x);
    double e1 = (double)kar_bf2f(a.y) + (double)kar_bf2f(b.y);
    double e2 = (double)kar_bf2f(a.z) + (double)kar_bf2f(b.z);
    double e3 = (double)kar_bf2f(a.w) + (double)kar_bf2f(b.w);
    s += e0 * e0 + e1 * e1 + e2 * e2 + e3 * e3;
  }
  dst[p] = s;
}

// diag_p from splits
__global__ __launch_bounds__(256) void kar_diagp2_kernel(
    const short* __restrict__ qsh, const short* __restrict__ qsl,
    const short* __restrict__ ksh, const short* __restrict__ ksl,
    const double* __restrict__ qn, const double* __restrict__ kn,
    const double* __restrict__ SC, const float* __restrict__ dsc,
    const float* __restrict__ reg, double* __restrict__ dgp) {
  int o = blockIdx.x * 256 + threadIdx.x;
  int h = o >> 11;
  const short* qh = qsh + (size_t)o * kDH;
  const short* ql = qsl + (size_t)o * kDH;
  const short* kh = ksh + (size_t)o * kDH;
  const short* kl = ksl + (size_t)o * kDH;
  double dot = 0.0;
  for (int i = 0; i < kDH; i++) {
    double qi = (double)kar_bf2f(qh[i]) + (double)kar_bf2f(ql[i]);
    double ki = (double)kar_bf2f(kh[i]) + (double)kar_bf2f(kl[i]);
    dot += qi * ki;
  }
  double dist = fmax(qn[o] + kn[o] - 2.0 * dot, 0.0);
  double Kss = exp(-dist * SC[0]);
  double sp  = log1p(exp(Kss));
  dgp[o] = sp * (double)dsc[h] + (double)reg[0];
}

// fused K-apply v5: alpha hi-only, fused U^T r partial in non-FINAL epilogue
template <bool FINAL>
__global__ __launch_bounds__(256, 2) void kar_mfma_iter5_kernel(
    const short* __restrict__ qsh, const short* __restrict__ qsl,
    const short* __restrict__ ksh, const short* __restrict__ ksl,
    const short* __restrict__ ath,
    const float* __restrict__ alpha, const float* __restrict__ v,
    const double* __restrict__ qn, const double* __restrict__ kn,
    const double* __restrict__ SC, float* __restrict__ outp,
    short* __restrict__ tmph, short* __restrict__ tmpl,
    const float* __restrict__ Ug, double* __restrict__ utrp) {
  constexpr int LDW = 72;
  __shared__ short Kh[64 * LDW], Kl[64 * LDW];
  __shared__ short Ah[64 * LDW];
  __shared__ short Ph[64 * LDW];
  __shared__ float qns[64];
  __shared__ float Ub[64][16];
  const int h   = blockIdx.y;
  const int s0  = blockIdx.x * 64;
  const int tid = threadIdx.x;
  const int lane = tid & 63;
  const int wv   = tid >> 6;     // wave: owns t-quarter (ph1), d-quarter (ph2)
  const int l16  = lane & 15;
  const int qd   = lane >> 4;
  const int row = tid >> 2, c8 = (tid & 3) * 16;
  // Q fragments for ALL 4 s-quarters in registers
  bf16x8 qH[4][2], qL[4][2];
#pragma unroll
  for (int sq = 0; sq < 4; sq++) {
    const size_t qb = (((size_t)h * kS) + s0 + sq * 16 + l16) * kDH;
    qH[sq][0] = *(const bf16x8*)&qsh[qb + qd * 8];
    qH[sq][1] = *(const bf16x8*)&qsh[qb + 32 + qd * 8];
    qL[sq][0] = *(const bf16x8*)&qsl[qb + qd * 8];
    qL[sq][1] = *(const bf16x8*)&qsl[qb + 32 + qd * 8];
  }
  if (tid < 64) qns[tid] = (float)qn[h * kS + s0 + tid];
  const float cc = (float)SC[0];
  f32x4 acco[4];
#pragma unroll
  for (int i = 0; i < 4; i++) acco[i] = (f32x4){0.f, 0.f, 0.f, 0.f};

  for (int t0 = 0; t0 < kS; t0 += 64) {
    __syncthreads();
    {
      const size_t ksrc = (((size_t)h * kS) + t0 + row) * kDH;
      *(bf16x8*)&Kh[row * LDW + c8]     = *(const bf16x8*)&ksh[ksrc + c8];
      *(bf16x8*)&Kh[row * LDW + c8 + 8] = *(const bf16x8*)&ksh[ksrc + c8 + 8];
      *(bf16x8*)&Kl[row * LDW + c8]     = *(const bf16x8*)&ksl[ksrc + c8];
      *(bf16x8*)&Kl[row * LDW + c8 + 8] = *(const bf16x8*)&ksl[ksrc + c8 + 8];
      const size_t asrc = ((size_t)h * kDH + row) * kS + t0;
      *(bf16x8*)&Ah[row * LDW + c8]     = *(const bf16x8*)&ath[asrc + c8];
      *(bf16x8*)&Ah[row * LDW + c8 + 8] = *(const bf16x8*)&ath[asrc + c8 + 8];
    }
    const float knr = (float)kn[h * kS + t0 + wv * 16 + l16];
    __syncthreads();
    // phase 1: QK^T — wave computes columns [wv*16, +16) for all 64 s rows
    f32x4 accp[4];
#pragma unroll
    for (int i = 0; i < 4; i++) accp[i] = (f32x4){0.f, 0.f, 0.f, 0.f};
#pragma unroll
    for (int kt = 0; kt < 2; kt++) {
      const int ko = kt * 32 + qd * 8;
      const bf16x8 bH = *(const bf16x8*)&Kh[(wv * 16 + l16) * LDW + ko];
      const bf16x8 bL = *(const bf16x8*)&Kl[(wv * 16 + l16) * LDW + ko];
#pragma unroll
      for (int sq = 0; sq < 4; sq++) {
        accp[sq] = __builtin_amdgcn_mfma_f32_16x16x32_bf16(qH[sq][kt], bH, accp[sq], 0, 0, 0);
        accp[sq] = __builtin_amdgcn_mfma_f32_16x16x32_bf16(qL[sq][kt], bH, accp[sq], 0, 0, 0);
        accp[sq] = __builtin_amdgcn_mfma_f32_16x16x32_bf16(qH[sq][kt], bL, accp[sq], 0, 0, 0);
      }
    }
    // exp + write P (own t-columns, all s rows)
#pragma unroll
    for (int sq = 0; sq < 4; sq++) {
#pragma unroll
      for (int r = 0; r < 4; r++) {
        const int srow = sq * 16 + qd * 4 + r;
        const float e2 = fmaf(2.0f, accp[sq][r], -(qns[srow] + knr));
        const float val = __expf(fminf(e2, 0.0f) * cc);
        Ph[srow * LDW + wv * 16 + l16] = (short)kar_f2bf(val);
      }
    }
    __syncthreads();
    // phase 2: acc += P @ alpha_hi — wave computes columns d in [wv*16, +16)
#pragma unroll
    for (int kt = 0; kt < 2; kt++) {
      const int ko = kt * 32 + qd * 8;
      const bf16x8 bH = *(const bf16x8*)&Ah[(wv * 16 + l16) * LDW + ko];
#pragma unroll
      for (int sq = 0; sq < 4; sq++) {
        const bf16x8 pH = *(const bf16x8*)&Ph[(sq * 16 + l16) * LDW + ko];
        acco[sq] = __builtin_amdgcn_mfma_f32_16x16x32_bf16(pH, bH, acco[sq], 0, 0, 0);
      }
    }
  }
  const int d = wv * 16 + l16;
  if (FINAL) {
#pragma unroll
    for (int sq = 0; sq < 4; sq++) {
#pragma unroll
      for (int r = 0; r < 4; r++) {
        const int s = s0 + sq * 16 + qd * 4 + r;
        short hh, ll; kar_split_bf(acco[sq][r], hh, ll);
        tmph[(size_t)s * kD + h * kDH + d] = hh;
        tmpl[(size_t)s * kD + h * kDH + d] = ll;
      }
    }
  } else {
    const float lamf = (float)SC[1];
    float rv[4][4];
#pragma unroll
    for (int sq = 0; sq < 4; sq++) {
#pragma unroll
      for (int r = 0; r < 4; r++) {
        const int s = s0 + sq * 16 + qd * 4 + r;
        const size_t eg = ((size_t)h * kS + s) * kDH + d;
        const float rr = v[eg] - (acco[sq][r] + lamf * alpha[eg]);
        rv[sq][r] = rr;
        outp[eg] = rr;
      }
    }
    // ---- fused U^T r partial for this 64-s block ----
    *(float4*)&Ub[tid >> 2][(tid & 3) * 4] =
        *(const float4*)&Ug[((size_t)h * kS + s0 + (tid >> 2)) * kR + (tid & 3) * 4];
    __syncthreads();
    double uacc[16];
#pragma unroll
    for (int ri = 0; ri < 16; ri++) uacc[ri] = 0.0;
#pragma unroll
    for (int sq = 0; sq < 4; sq++) {
#pragma unroll
      for (int r = 0; r < 4; r++) {
        const int sl = sq * 16 + qd * 4 + r;
        const double rval = (double)rv[sq][r];
        const float4 u0 = *(const float4*)&Ub[sl][0];
        const float4 u1 = *(const float4*)&Ub[sl][4];
        const float4 u2 = *(const float4*)&Ub[sl][8];
        const float4 u3 = *(const float4*)&Ub[sl][12];
        uacc[0]  += (double)u0.x * rval; uacc[1]  += (double)u0.y * rval;
        uacc[2]  += (double)u0.z * rval; uacc[3]  += (double)u0.w * rval;
        uacc[4]  += (double)u1.x * rval; uacc[5]  += (double)u1.y * rval;
        uacc[6]  += (double)u1.z * rval; uacc[7]  += (double)u1.w * rval;
        uacc[8]  += (double)u2.x * rval; uacc[9]  += (double)u2.y * rval;
        uacc[10] += (double)u2.z * rval; uacc[11] += (double)u2.w * rval;
        uacc[12] += (double)u3.x * rval; uacc[13] += (double)u3.y * rval;
        uacc[14] += (double)u3.z * rval; uacc[15] += (double)u3.w * rval;
      }
    }
#pragma unroll
    for (int ri = 0; ri < 16; ri++) {
      uacc[ri] += __shfl_xor(uacc[ri], 16, 64);
      uacc[ri] += __shfl_xor(uacc[ri], 32, 64);
    }
    if (qd == 0) {
#pragma unroll
      for (int ri = 0; ri < 16; ri++)
        utrp[(((size_t)(h * 32) + blockIdx.x) * kR + ri) * kDH + d] = uacc[ri];
    }
  }
}

// ================= OLD PATH (R4 fallback) kernels =================
__global__ __launch_bounds__(256) void kar_gemm_qkv_f32_kernel(
    const float* __restrict__ x,
    const float* __restrict__ Wq, const float* __restrict__ Wk, const float* __restrict__ Wv,
    float* __restrict__ q, float* __restrict__ k, float* __restrict__ v) {
  const float* W = (blockIdx.z == 0) ? Wq : (blockIdx.z == 1) ? Wk : Wv;
  float* outp    = (blockIdx.z == 0) ? q  : (blockIdx.z == 1) ? k  : v;
  const int n0 = blockIdx.x * 64;
  const int m0 = blockIdx.y * 64;
  const int tid = threadIdx.x;
  const int tx = tid & 15, ty = tid >> 4;
  __shared__ float As[16][68];
  __shared__ float Bs[16][68];
  double acc[4][4] = {};
  const int lr = tid >> 2;
  const int lk = (tid & 3) * 4;
  const int br = tid >> 4;
  const int bc = (tid & 15) * 4;
  for (int k0 = 0; k0 < kD; k0 += 16) {
    const float4 a4 = *(const float4*)&x[(size_t)(m0 + lr) * kD + k0 + lk];
    const float4 b4 = *(const float4*)&W[(size_t)(k0 + br) * kD + n0 + bc];
    __syncthreads();
    As[lk + 0][lr] = a4.x; As[lk + 1][lr] = a4.y;
    As[lk + 2][lr] = a4.z; As[lk + 3][lr] = a4.w;
    *(float4*)&Bs[br][bc] = b4;
    __syncthreads();
    float c32[4][4] = {};
#pragma unroll
    for (int kk = 0; kk < 16; kk++) {
      const float4 av = *(const float4*)&As[kk][ty * 4];
      const float4 bv = *(const float4*)&Bs[kk][tx * 4];
      const float a_[4] = {av.x, av.y, av.z, av.w};
      const float b_[4] = {bv.x, bv.y, bv.z, bv.w};
#pragma unroll
      for (int i = 0; i < 4; i++)
#pragma unroll
        for (int j = 0; j < 4; j++) c32[i][j] = fmaf(a_[i], b_[j], c32[i][j]);
    }
#pragma unroll
    for (int i = 0; i < 4; i++)
#pragma unroll
      for (int j = 0; j < 4; j++) acc[i][j] += (double)c32[i][j];
  }
  const int h = n0 >> 6;
#pragma unroll
  for (int i = 0; i < 4; i++) {
    const int s = m0 + ty * 4 + i;
    float4 o;
    o.x = (float)acc[i][0]; o.y = (float)acc[i][1];
    o.z = (float)acc[i][2]; o.w = (float)acc[i][3];
    *(float4*)&outp[((size_t)h * kS + s) * kDH + tx * 4] = o;
  }
}

__global__ __launch_bounds__(256) void kar_gemm_plain_kernel(
    const float* __restrict__ A, const float* __restrict__ W, float* __restrict__ C) {
  const int n0 = blockIdx.x * 64;
  const int m0 = blockIdx.y * 64;
  const int tid = threadIdx.x;
  const int tx = tid & 15, ty = tid >> 4;
  __shared__ float As[16][68];
  __shared__ float Bs[16][68];
  double acc[4][4] = {};
  const int lr = tid >> 2;
  const int lk = (tid & 3) * 4;
  const int br = tid >> 4;
  const int bc = (tid & 15) * 4;
  for (int k0 = 0; k0 < kD; k0 += 16) {
    const float4 a4 = *(const float4*)&A[(size_t)(m0 + lr) * kD + k0 + lk];
    const float4 b4 = *(const float4*)&W[(size_t)(k0 + br) * kD + n0 + bc];
    __syncthreads();
    As[lk + 0][lr] = a4.x; As[lk + 1][lr] = a4.y;
    As[lk + 2][lr] = a4.z; As[lk + 3][lr] = a4.w;
    *(float4*)&Bs[br][bc] = b4;
    __syncthreads();
    float c32[4][4] = {};
#pragma unroll
    for (int kk = 0; kk < 16; kk++) {
      const float4 av = *(const float4*)&As[kk][ty * 4];
      const float4 bv = *(const float4*)&Bs[kk][tx * 4];
      const float a_[4] = {av.x, av.y, av.z, av.w};
      const float b_[4] = {bv.x, bv.y, bv.z, bv.w};
#pragma unroll
      for (int i = 0; i < 4; i++)
#pragma unroll
        for (int j = 0; j < 4; j++) c32[i][j] = fmaf(a_[i], b_[j], c32[i][j]);
    }
#pragma unroll
    for (int i = 0; i < 4; i++)
#pragma unroll
      for (int j = 0; j < 4; j++) acc[i][j] += (double)c32[i][j];
  }
#pragma unroll
  for (int i = 0; i < 4; i++) {
    const int s = m0 + ty * 4 + i;
    float4 o;
    o.x = (float)acc[i][0]; o.y = (float)acc[i][1];
    o.z = (float)acc[i][2]; o.w = (float)acc[i][3];
    *(float4*)&C[(size_t)s * kD + n0 + tx * 4] = o;
  }
}

__global__ __launch_bounds__(256) void kar_norms_f32_kernel(const float* __restrict__ q,
                                                            const float* __restrict__ k,
                                                            double* __restrict__ qn,
                                                            double* __restrict__ kn) {
  int o = blockIdx.x * 256 + threadIdx.x;
  const float* src; double* dst; int p;
  if (o < kH * kS) { src = q; dst = qn; p = o; }
  else             { src = k; dst = kn; p = o - kH * kS; }
  const float* rowp = src + (size_t)p * kDH;
  double s = 0.0;
  for (int i = 0; i < kDH; i += 4) {
    float4 x4 = *(const float4*)&rowp[i];
    s += (double)x4.x * (double)x4.x + (double)x4.y * (double)x4.y +
         (double)x4.z * (double)x4.z + (double)x4.w * (double)x4.w;
  }
  dst[p] = s;
}

__global__ __launch_bounds__(256) void kar_diagp_f32_kernel(
    const float* __restrict__ q, const float* __restrict__ k,
    const double* __restrict__ qn, const double* __restrict__ kn,
    const double* __restrict__ SC, const float* __restrict__ dsc,
    const float* __restrict__ reg, double* __restrict__ dgp) {
  int o = blockIdx.x * 256 + threadIdx.x;
  int h = o >> 11;
  const float* qp = q + (size_t)o * kDH;
  const float* kp = k + (size_t)o * kDH;
  double dot = 0.0;
  for (int i = 0; i < kDH; i++) dot += (double)qp[i] * (double)kp[i];
  double dist = fmax(qn[o] + kn[o] - 2.0 * dot, 0.0);
  double Kss = exp(-dist * SC[0]);
  double sp  = log1p(exp(Kss));
  dgp[o] = sp * (double)dsc[h] + (double)reg[0];
}

template <bool FINAL>
__global__ __launch_bounds__(256, 2) void kar_mfma_iterA_kernel(
    const float* __restrict__ q, const float* __restrict__ k,
    const float* __restrict__ alpha, const float* __restrict__ v,
    const double* __restrict__ qn, const double* __restrict__ kn,
    const double* __restrict__ SC, float* __restrict__ outp) {
  constexpr int LDW = 72;
  __shared__ short Qh[64 * LDW], Ql[64 * LDW];
  __shared__ short Kh[64 * LDW], Kl[64 * LDW];
  __shared__ short Ph[64 * LDW], Pl[64 * LDW];
  __shared__ short Ah[64 * LDW], Al[64 * LDW];
  __shared__ float qns[64], kns[64];
  const int h   = blockIdx.y;
  const int s0  = blockIdx.x * 64;
  const int tid = threadIdx.x;
  const int lane = tid & 63;
  const int wv   = tid >> 6;
  const int l16  = lane & 15;
  const int qd   = lane >> 4;
  const int m16  = wv * 16;
  const float* qh = q + ((size_t)h * kS + s0) * kDH;
  const float* kh = k + (size_t)h * kS * kDH;
  const float* ah = alpha + (size_t)h * kS * kDH;
  {
    const int row = tid >> 4;
    const int c4  = (tid & 15) * 4;
#pragma unroll
    for (int rep = 0; rep < 4; rep++) {
      const int r = rep * 16 + row;
      const float4 a = *(const float4*)&qh[(size_t)r * kDH + c4];
      short h0, l0, h1, l1, h2, l2, h3, l3;
      kar_split_bf(a.x, h0, l0); kar_split_bf(a.y, h1, l1);
      kar_split_bf(a.z, h2, l2); kar_split_bf(a.w, h3, l3);
      *(short4*)&Qh[r * LDW + c4] = make_short4(h0, h1, h2, h3);
      *(short4*)&Ql[r * LDW + c4] = make_short4(l0, l1, l2, l3);
    }
    if (tid < 64) qns[tid] = (float)qn[h * kS + s0 + tid];
  }
  const float cc = (float)SC[0];
  f32x4 acco[4];
#pragma unroll
  for (int i = 0; i < 4; i++) acco[i] = (f32x4){0.f, 0.f, 0.f, 0.f};
  for (int t0 = 0; t0 < kS; t0 += 64) {
    __syncthreads();
    {
      const int row = tid >> 4;
      const int c4  = (tid & 15) * 4;
#pragma unroll
      for (int rep = 0; rep < 4; rep++) {
        const int r = rep * 16 + row;
        const float4 b = *(const float4*)&kh[(size_t)(t0 + r) * kDH + c4];
        short h0, l0, h1, l1, h2, l2, h3, l3;
        kar_split_bf(b.x, h0, l0); kar_split_bf(b.y, h1, l1);
        kar_split_bf(b.z, h2, l2); kar_split_bf(b.w, h3, l3);
        *(short4*)&Kh[r * LDW + c4] = make_short4(h0, h1, h2, h3);
        *(short4*)&Kl[r * LDW + c4] = make_short4(l0, l1, l2, l3);
        const float4 av = *(const float4*)&ah[(size_t)(t0 + r) * kDH + c4];
        kar_split_bf(av.x, h0, l0); kar_split_bf(av.y, h1, l1);
        kar_split_bf(av.z, h2, l2); kar_split_bf(av.w, h3, l3);
        Ah[(c4 + 0) * LDW + r] = h0; Al[(c4 + 0) * LDW + r] = l0;
        Ah[(c4 + 1) * LDW + r] = h1; Al[(c4 + 1) * LDW + r] = l1;
        Ah[(c4 + 2) * LDW + r] = h2; Al[(c4 + 2) * LDW + r] = l2;
        Ah[(c4 + 3) * LDW + r] = h3; Al[(c4 + 3) * LDW + r] = l3;
      }
      if (tid < 64) kns[tid] = (float)kn[h * kS + t0 + tid];
    }
    __syncthreads();
    f32x4 accp[4];
#pragma unroll
    for (int i = 0; i < 4; i++) accp[i] = (f32x4){0.f, 0.f, 0.f, 0.f};
#pragma unroll
    for (int kt = 0; kt < 2; kt++) {
      const int ko = kt * 32 + qd * 8;
      const bf16x8 aH = *(const bf16x8*)&Qh[(m16 + l16) * LDW + ko];
      const bf16x8 aL = *(const bf16x8*)&Ql[(m16 + l16) * LDW + ko];
#pragma unroll
      for (int nt = 0; nt < 4; nt++) {
        const bf16x8 bH = *(const bf16x8*)&Kh[(nt * 16 + l16) * LDW + ko];
        const bf16x8 bL = *(const bf16x8*)&Kl[(nt * 16 + l16) * LDW + ko];
        accp[nt] = __builtin_amdgcn_mfma_f32_16x16x32_bf16(aH, bH, accp[nt], 0, 0, 0);
        accp[nt] = __builtin_amdgcn_mfma_f32_16x16x32_bf16(aL, bH, accp[nt], 0, 0, 0);
        accp[nt] = __builtin_amdgcn_mfma_f32_16x16x32_bf16(aH, bL, accp[nt], 0, 0, 0);
      }
    }
#pragma unroll
    for (int nt = 0; nt < 4; nt++) {
      const int tcol = nt * 16 + l16;
      const float kv = kns[tcol];
#pragma unroll
      for (int r = 0; r < 4; r++) {
        const int srow = m16 + qd * 4 + r;
        const float e2 = fmaf(2.0f, accp[nt][r], -(qns[srow] + kv));
        const float val = __expf(fminf(e2, 0.0f) * cc);
        short hb, lb; kar_split_bf(val, hb, lb);
        Ph[srow * LDW + tcol] = hb;
        Pl[srow * LDW + tcol] = lb;
      }
    }
#pragma unroll
    for (int kt = 0; kt < 2; kt++) {
      const int ko = kt * 32 + qd * 8;
      const bf16x8 pH = *(const bf16x8*)&Ph[(m16 + l16) * LDW + ko];
      const bf16x8 pL = *(const bf16x8*)&Pl[(m16 + l16) * LDW + ko];
#pragma unroll
      for (int dt = 0; dt < 4; dt++) {
        const bf16x8 bH = *(const bf16x8*)&Ah[(dt * 16 + l16) * LDW + ko];
        const bf16x8 bL = *(const bf16x8*)&Al[(dt * 16 + l16) * LDW + ko];
        acco[dt] = __builtin_amdgcn_mfma_f32_16x16x32_bf16(pH, bH, acco[dt], 0, 0, 0);
        acco[dt] = __builtin_amdgcn_mfma_f32_16x16x32_bf16(pL, bH, acco[dt], 0, 0, 0);
        acco[dt] = __builtin_amdgcn_mfma_f32_16x16x32_bf16(pH, bL, acco[dt], 0, 0, 0);
      }
    }
  }
  if (FINAL) {
#pragma unroll
    for (int dt = 0; dt < 4; dt++) {
#pragma unroll
      for (int r = 0; r < 4; r++) {
        const int s = s0 + m16 + qd * 4 + r;
        const int d = dt * 16 + l16;
        outp[(size_t)s * kD + h * kDH + d] = acco[dt][r];
      }
    }
  } else {
    const float lamf = (float)SC[1];
#pragma unroll
    for (int dt = 0; dt < 4; dt++) {
#pragma unroll
      for (int r = 0; r < 4; r++) {
        const int s = s0 + m16 + qd * 4 + r;
        const int d = dt * 16 + l16;
        const size_t eg = ((size_t)h * kS + s) * kDH + d;
        outp[eg] = v[eg] - (acco[dt][r] + lamf * alpha[eg]);
      }
    }
  }
}

extern "C" void kernel_launch(void* const* d_in, const int* in_sizes, int n_in,
                              void* d_out, int out_size, void* d_ws, size_t ws_size,
                              hipStream_t stream) {
  (void)in_sizes; (void)n_in; (void)out_size;
  const float* x    = (const float*)d_in[0];
  const float* Wq   = (const float*)d_in[1];
  const float* Wk   = (const float*)d_in[2];
  const float* Wv   = (const float*)d_in[3];
  const float* Wo   = (const float*)d_in[4];
  const float* bw   = (const float*)d_in[5];
  const float* dsc  = (const float*)d_in[6];
  const float* pe   = (const float*)d_in[7];
  const float* hp   = (const float*)d_in[8];
  const float* reg  = (const float*)d_in[9];
  const float* lreg = (const float*)d_in[10];
  float* out = (float*)d_out;

  char* w = (char*)d_ws;
  size_t off = 0;
  auto take = [&](size_t bytes) -> void* {
    void* p = w + off;
    off += (bytes + 255) & ~(size_t)255;
    return p;
  };
  const size_t HSD = (size_t)kH * kS * kDH;  // 2M elements

  // ---- new-path layout ----
  float*  v_    = (float*)take(HSD * 4);
  float*  alpha = (float*)take(HSD * 4);
  float*  rbuf  = (float*)take(HSD * 4);
  short*  qsh   = (short*)take(HSD * 2);
  short*  qsl   = (short*)take(HSD * 2);
  short*  ksh   = (short*)take(HSD * 2);
  short*  ksl   = (short*)take(HSD * 2);
  short*  ath   = (short*)take(HSD * 2);
  short*  xh    = (short*)take((size_t)kS * kD * 2);  // reused as tmph
  short*  xl    = (short*)take((size_t)kS * kD * 2);  // reused as tmpl
  short*  WTh   = (short*)take((size_t)4 * kD * kD * 2);
  short*  WTl   = (short*)take((size_t)4 * kD * kD * 2);
  double* qn    = (double*)take((size_t)kH * kS * 8);
  double* kn    = (double*)take((size_t)kH * kS * 8);
  double* dgp   = (double*)take((size_t)kH * kS * 8);
  float*  U     = (float*)take((size_t)kH * kS * kR * 4);
  double* utr   = (double*)take((size_t)kH * kR * kDH * 8);
  double* utrp  = (double*)take((size_t)kH * 32 * kR * kDH * 8);
  double* SC    = (double*)take(256);
  const size_t need_new = off;

  if (ws_size >= need_new) {
    // ================= NEW PATH =================
    kar_scalars_kernel<<<1, 64, 0, stream>>>(bw, lreg, SC);
    kar_xsplit_kernel<<<2048, 256, 0, stream>>>(x, xh, xl);
    kar_wsplit_kernel<<<dim3(16, 16, 4), 256, 0, stream>>>(Wq, Wk, Wv, Wo, WTh, WTl);
    kar_mfma_gemm_qkv_kernel<<<dim3(16, 16, 3), 256, 0, stream>>>(
        xh, xl, WTh, WTl, v_, qsh, qsl, ksh, ksl);
    kar_norms2_kernel<<<256, 256, 0, stream>>>(qsh, qsl, ksh, ksl, qn, kn);
    kar_u_kernel<<<2048, 256, 0, stream>>>(pe, hp, U);
    kar_diagp2_kernel<<<128, 256, 0, stream>>>(qsh, qsl, ksh, ksl, qn, kn, SC, dsc, reg, dgp);

    // it 0: alpha == 0 -> r == v; standalone utr partial on v
    kar_utr_partial_kernel<<<dim3(32, kH), 256, 0, stream>>>(U, v_, utrp);
    kar_utr_reduce_kernel<<<64, 256, 0, stream>>>(utrp, utr);
    kar_update_t_kernel<<<dim3(32, kH), 256, 0, stream>>>(v_, dgp, U, utr, alpha, ath, 1);

    for (int it = 1; it < 5; it++) {
      kar_mfma_iter5_kernel<false><<<dim3(32, kH), 256, 0, stream>>>(
          qsh, qsl, ksh, ksl, ath, alpha, v_, qn, kn, SC, rbuf, nullptr, nullptr, U, utrp);
      kar_utr_reduce_kernel<<<64, 256, 0, stream>>>(utrp, utr);
      kar_update_t_kernel<<<dim3(32, kH), 256, 0, stream>>>(rbuf, dgp, U, utr, alpha, ath, 0);
    }

    kar_mfma_iter5_kernel<true><<<dim3(32, kH), 256, 0, stream>>>(
        qsh, qsl, ksh, ksl, ath, alpha, v_, qn, kn, SC, rbuf, xh, xl, U, utrp);
    kar_mfma_gemm_wo_kernel<<<dim3(16, 16), 256, 0, stream>>>(
        xh, xl, WTh + (size_t)3 * kD * kD, WTl + (size_t)3 * kD * kD, out);
  } else {
    // ================= OLD PATH (R4) =================
    size_t off2 = 0;
    auto take2 = [&](size_t bytes) -> void* {
      void* p = w + off2;
      off2 += (bytes + 255) & ~(size_t)255;
      return p;
    };
    float*  q2    = (float*)take2(HSD * 4);
    float*  k2    = (float*)take2(HSD * 4);
    float*  v2    = (float*)take2(HSD * 4);
    float*  al2   = (float*)take2(HSD * 4);
    float*  rb2   = (float*)take2(HSD * 4);
    float*  tmp2  = (float*)take2((size_t)kS * kD * 4);
    double* qn2   = (double*)take2((size_t)kH * kS * 8);
    double* kn2   = (double*)take2((size_t)kH * kS * 8);
    double* dgp2  = (double*)take2((size_t)kH * kS * 8);
    float*  U2    = (float*)take2((size_t)kH * kS * kR * 4);
    double* utr2  = (double*)take2((size_t)kH * kR * kDH * 8);
    double* utrp2 = (double*)take2((size_t)kH * 32 * kR * kDH * 8);
    double* SC2   = (double*)take2(256);

    kar_scalars_kernel<<<1, 64, 0, stream>>>(bw, lreg, SC2);
    kar_gemm_qkv_f32_kernel<<<dim3(16, 32, 3), 256, 0, stream>>>(x, Wq, Wk, Wv, q2, k2, v2);
    kar_norms_f32_kernel<<<256, 256, 0, stream>>>(q2, k2, qn2, kn2);
    kar_u_kernel<<<2048, 256, 0, stream>>>(pe, hp, U2);
    kar_diagp_f32_kernel<<<128, 256, 0, stream>>>(q2, k2, qn2, kn2, SC2, dsc, reg, dgp2);

    kar_utr_partial_kernel<<<dim3(32, kH), 256, 0, stream>>>(U2, v2, utrp2);
    kar_utr_reduce_kernel<<<64, 256, 0, stream>>>(utrp2, utr2);
    kar_update_kernel<<<8192, 256, 0, stream>>>(v2, dgp2, U2, utr2, al2, 1);

    for (int it = 1; it < 5; it++) {
      kar_mfma_iterA_kernel<false><<<dim3(32, kH), 256, 0, stream>>>(
          q2, k2, al2, v2, qn2, kn2, SC2, rb2);
      kar_utr_partial_kernel<<<dim3(32, kH), 256, 0, stream>>>(U2, rb2, utrp2);
      kar_utr_reduce_kernel<<<64, 256, 0, stream>>>(utrp2, utr2);
      kar_update_kernel<<<8192, 256, 0, stream>>>(rb2, dgp2, U2, utr2, al2, 0);
    }
    kar_mfma_iterA_kernel<true><<<dim3(32, kH), 256, 0, stream>>>(
        q2, k2, al2, v2, qn2, kn2, SC2, tmp2);
    kar_gemm_plain_kernel<<<dim3(16, 32), 256, 0, stream>>>(tmp2, Wo, out);
  }
}

// Round 10
// 607.447 us; speedup vs baseline: 4.0211x; 1.0085x over previous
//
#include <hip/hip_runtime.h>
#include <cstdint>
#include <cstddef>

constexpr int kS  = 2048;
constexpr int kD  = 1024;
constexpr int kH  = 16;
constexpr int kDH = 64;
constexpr int kR  = 16;

typedef __attribute__((ext_vector_type(8))) short bf16x8;
typedef __attribute__((ext_vector_type(4))) float f32x4;

__device__ __forceinline__ unsigned short kar_f2bf(float x) {
  unsigned u = __float_as_uint(x);
  return (unsigned short)((u + 0x7FFFu + ((u >> 16) & 1u)) >> 16);
}
__device__ __forceinline__ float kar_bf2f(short h) {
  return __uint_as_float((unsigned)(unsigned short)h << 16);
}
__device__ __forceinline__ void kar_split_bf(float x, short& hi, short& lo) {
  unsigned short h = kar_f2bf(x);
  float hf = __uint_as_float((unsigned)h << 16);
  hi = (short)h;
  lo = (short)kar_f2bf(x - hf);
}

// ---------------- scalars ----------------
__global__ __launch_bounds__(64) void kar_scalars_kernel(const float* __restrict__ bw,
                                                         const float* __restrict__ lreg,
                                                         double* __restrict__ SC) {
  if (threadIdx.x == 0) {
    double b = log1p(exp((double)bw[0])) + 1e-6;
    SC[0] = 1.0 / (2.0 * b * b);
    SC[1] = log1p(exp((double)lreg[0]));
  }
}

// ---------------- U[h][s][p] ----------------
__global__ __launch_bounds__(256) void kar_u_kernel(const float* __restrict__ pe,
                                                    const float* __restrict__ hp,
                                                    float* __restrict__ U) {
  int o = blockIdx.x * 256 + threadIdx.x;
  int r = o & 15, s = (o >> 4) & 2047, h = o >> 15;
  double acc = 0.0;
#pragma unroll
  for (int rp = 0; rp < kR; rp++)
    acc += (double)pe[s * kR + rp] * (double)hp[((h * kR) + rp) * kR + r];
  U[o] = (float)acc;
}

// ---------------- ut_r partials (64-row slices, 32 slots) / reduce ----------------
__global__ __launch_bounds__(256) void kar_utr_partial_kernel(
    const float* __restrict__ Ubuf, const float* __restrict__ rbuf,
    double* __restrict__ utrp) {
  const int h  = blockIdx.y;
  const int sb = blockIdx.x * 64;
  const int t  = threadIdx.x;
  __shared__ float Uch[32][16];
  __shared__ float Rch[32][64];
  double acc[4] = {};
  for (int cs = 0; cs < 64; cs += 32) {
    __syncthreads();
    if (t < 128) {
      const int i = t >> 2, f = (t & 3) * 4;
      *(float4*)&Uch[i][f] = *(const float4*)&Ubuf[((size_t)(h * kS) + sb + cs + i) * kR + f];
    }
#pragma unroll
    for (int rep = 0; rep < 2; rep++) {
      const int e = t + rep * 256;
      const int i = e >> 4, c = (e & 15) * 4;
      *(float4*)&Rch[i][c] = *(const float4*)&rbuf[((size_t)(h * kS) + sb + cs + i) * kDH + c];
    }
    __syncthreads();
    for (int i = 0; i < 32; i++) {
#pragma unroll
      for (int rep = 0; rep < 4; rep++) {
        const int p = t + rep * 256;
        const int r = p >> 6, d = p & 63;
        acc[rep] += (double)Uch[i][r] * (double)Rch[i][d];
      }
    }
  }
#pragma unroll
  for (int rep = 0; rep < 4; rep++) {
    const int p = t + rep * 256;
    const int r = p >> 6, d = p & 63;
    utrp[(((size_t)(h * 32) + blockIdx.x) * kR + r) * kDH + d] = acc[rep];
  }
}

__global__ __launch_bounds__(256) void kar_utr_reduce_kernel(const double* __restrict__ utrp,
                                                             double* __restrict__ utr) {
  int o = blockIdx.x * 256 + threadIdx.x;
  int h = o >> 10, rd = o & 1023;
  double s = 0.0;
#pragma unroll
  for (int j = 0; j < 32; j++) s += utrp[(size_t)h * 32768 + (size_t)j * 1024 + rd];
  utr[o] = s;
}

// old elementwise update (fallback path only)
__global__ __launch_bounds__(256) void kar_update_kernel(
    const float* __restrict__ rsrc, const double* __restrict__ dgp,
    const float* __restrict__ Ubuf, const double* __restrict__ utr,
    float* __restrict__ alpha, int first) {
  int e = blockIdx.x * 256 + threadIdx.x;
  const int d = e & 63;
  const int s = (e >> 6) & 2047;
  const int h = e >> 17;
  const double rv = (double)rsrc[e];
  const double dp = dgp[h * kS + s];
  const float*  Us = &Ubuf[((size_t)(h * kS) + s) * kR];
  const double* uh = &utr[(size_t)h * kR * kDH];
  double sum = 0.0;
#pragma unroll
  for (int ri = 0; ri < kR; ri++) sum += (double)Us[ri] * uh[ri * kDH + d];
  const double p = rv * dp + sum;
  const double an = (first ? 0.0 : (double)alpha[e]) + p;
  alpha[e] = (float)an;
}

// fused update + transpose/split: alpha fp32 + ath [h][d][s] in one pass
__global__ __launch_bounds__(256) void kar_update_t_kernel(
    const float* __restrict__ rsrc, const double* __restrict__ dgp,
    const float* __restrict__ Ubuf, const double* __restrict__ utr,
    float* __restrict__ alpha, short* __restrict__ ath, int first) {
  const int h = blockIdx.y, s0 = blockIdx.x * 64;
  __shared__ float T[64][65];
  const int t = threadIdx.x;
  const int r16 = t >> 4, c4 = (t & 15) * 4;
  const double* uh = &utr[(size_t)h * kR * kDH];
#pragma unroll
  for (int it = 0; it < 4; it++) {
    const int row = it * 16 + r16;
    const int s = s0 + row;
    const size_t eg = ((size_t)h * kS + s) * kDH + c4;
    const float4 rv4 = *(const float4*)&rsrc[eg];
    const double dp = dgp[h * kS + s];
    const float* Us = &Ubuf[((size_t)h * kS + s) * kR];
    double sum0 = 0.0, sum1 = 0.0, sum2 = 0.0, sum3 = 0.0;
#pragma unroll
    for (int ri = 0; ri < kR; ri++) {
      const double u = (double)Us[ri];
      const double* ur = &uh[ri * kDH + c4];
      sum0 += u * ur[0]; sum1 += u * ur[1];
      sum2 += u * ur[2]; sum3 += u * ur[3];
    }
    double a0 = (first ? 0.0 : (double)alpha[eg + 0]) + ((double)rv4.x * dp + sum0);
    double a1 = (first ? 0.0 : (double)alpha[eg + 1]) + ((double)rv4.y * dp + sum1);
    double a2 = (first ? 0.0 : (double)alpha[eg + 2]) + ((double)rv4.z * dp + sum2);
    double a3 = (first ? 0.0 : (double)alpha[eg + 3]) + ((double)rv4.w * dp + sum3);
    float4 o;
    o.x = (float)a0; o.y = (float)a1; o.z = (float)a2; o.w = (float)a3;
    *(float4*)&alpha[eg] = o;
    T[row][c4] = o.x; T[row][c4 + 1] = o.y; T[row][c4 + 2] = o.z; T[row][c4 + 3] = o.w;
  }
  __syncthreads();
#pragma unroll
  for (int it = 0; it < 4; it++) {
    int d = it * 16 + r16;
    float v0 = T[c4][d], v1 = T[c4 + 1][d], v2 = T[c4 + 2][d], v3 = T[c4 + 3][d];
    *(short4*)&ath[((size_t)h * kDH + d) * kS + s0 + c4] =
        make_short4((short)kar_f2bf(v0), (short)kar_f2bf(v1),
                    (short)kar_f2bf(v2), (short)kar_f2bf(v3));
  }
}

// ================= NEW PATH kernels =================

__global__ __launch_bounds__(256) void kar_xsplit_kernel(const float* __restrict__ x,
                                                         short* __restrict__ xh,
                                                         short* __restrict__ xl) {
  size_t e = ((size_t)blockIdx.x * 256 + threadIdx.x) * 4;
  float4 a = *(const float4*)&x[e];
  short h0, l0, h1, l1, h2, l2, h3, l3;
  kar_split_bf(a.x, h0, l0); kar_split_bf(a.y, h1, l1);
  kar_split_bf(a.z, h2, l2); kar_split_bf(a.w, h3, l3);
  *(short4*)&xh[e] = make_short4(h0, h1, h2, h3);
  *(short4*)&xl[e] = make_short4(l0, l1, l2, l3);
}

__global__ __launch_bounds__(256) void kar_wsplit_kernel(
    const float* __restrict__ Wq, const float* __restrict__ Wk,
    const float* __restrict__ Wv, const float* __restrict__ Wo,
    short* __restrict__ WTh, short* __restrict__ WTl) {
  const float* W = (blockIdx.z == 0) ? Wq : (blockIdx.z == 1) ? Wk
                 : (blockIdx.z == 2) ? Wv : Wo;
  short* oh = WTh + (size_t)blockIdx.z * kD * kD;
  short* ol = WTl + (size_t)blockIdx.z * kD * kD;
  const int n0 = blockIdx.x * 64, k0 = blockIdx.y * 64;
  __shared__ float T[64][65];
  const int t = threadIdx.x;
  const int r16 = t >> 4, c4 = (t & 15) * 4;
#pragma unroll
  for (int it = 0; it < 4; it++) {
    int r = it * 16 + r16;
    float4 a = *(const float4*)&W[(size_t)(k0 + r) * kD + n0 + c4];
    T[r][c4] = a.x; T[r][c4 + 1] = a.y; T[r][c4 + 2] = a.z; T[r][c4 + 3] = a.w;
  }
  __syncthreads();
#pragma unroll
  for (int it = 0; it < 4; it++) {
    int n = it * 16 + r16;
    float v0 = T[c4][n], v1 = T[c4 + 1][n], v2 = T[c4 + 2][n], v3 = T[c4 + 3][n];
    short h0, l0, h1, l1, h2, l2, h3, l3;
    kar_split_bf(v0, h0, l0); kar_split_bf(v1, h1, l1);
    kar_split_bf(v2, h2, l2); kar_split_bf(v3, h3, l3);
    *(short4*)&oh[(size_t)(n0 + n) * kD + k0 + c4] = make_short4(h0, h1, h2, h3);
    *(short4*)&ol[(size_t)(n0 + n) * kD + k0 + c4] = make_short4(l0, l1, l2, l3);
  }
}

// MFMA split-bf16 GEMM: QKV. z=0,1: split dumps q/k; z=2: v fp32.
__global__ __launch_bounds__(256) void kar_mfma_gemm_qkv_kernel(
    const short* __restrict__ xh, const short* __restrict__ xl,
    const short* __restrict__ WTh, const short* __restrict__ WTl,
    float* __restrict__ v,
    short* __restrict__ qsh, short* __restrict__ qsl,
    short* __restrict__ ksh, short* __restrict__ ksl) {
  const int z = blockIdx.z;
  const short* Bh = WTh + (size_t)z * kD * kD;
  const short* Bl = WTl + (size_t)z * kD * kD;
  const int n0 = blockIdx.x * 64;
  const int m0 = blockIdx.y * 128;
  constexpr int LW = 40;
  __shared__ short Xh[128 * LW], Xl[128 * LW], Wh[64 * LW], Wl[64 * LW];
  const int t = threadIdx.x, lane = t & 63, wv = t >> 6;
  const int wm = wv >> 1, wn = wv & 1, l16 = lane & 15, qd = lane >> 4;
  f32x4 acc[4][2];
#pragma unroll
  for (int i = 0; i < 4; i++)
#pragma unroll
    for (int j = 0; j < 2; j++) acc[i][j] = (f32x4){0.f, 0.f, 0.f, 0.f};
  const int xrow = t >> 1, xc = (t & 1) * 16;
  for (int k0 = 0; k0 < kD; k0 += 32) {
    __syncthreads();
    {
      const size_t xs = (size_t)(m0 + xrow) * kD + k0 + xc;
      *(bf16x8*)&Xh[xrow * LW + xc]     = *(const bf16x8*)&xh[xs];
      *(bf16x8*)&Xh[xrow * LW + xc + 8] = *(const bf16x8*)&xh[xs + 8];
      *(bf16x8*)&Xl[xrow * LW + xc]     = *(const bf16x8*)&xl[xs];
      *(bf16x8*)&Xl[xrow * LW + xc + 8] = *(const bf16x8*)&xl[xs + 8];
    }
    if (t < 128) {
      const int wrow = t >> 1, wc = (t & 1) * 16;
      const size_t wsrc = (size_t)(n0 + wrow) * kD + k0 + wc;
      *(bf16x8*)&Wh[wrow * LW + wc]     = *(const bf16x8*)&Bh[wsrc];
      *(bf16x8*)&Wh[wrow * LW + wc + 8] = *(const bf16x8*)&Bh[wsrc + 8];
    } else {
      const int t2 = t - 128, wrow = t2 >> 1, wc = (t2 & 1) * 16;
      const size_t wsrc = (size_t)(n0 + wrow) * kD + k0 + wc;
      *(bf16x8*)&Wl[wrow * LW + wc]     = *(const bf16x8*)&Bl[wsrc];
      *(bf16x8*)&Wl[wrow * LW + wc + 8] = *(const bf16x8*)&Bl[wsrc + 8];
    }
    __syncthreads();
    bf16x8 bH[2], bL[2];
#pragma unroll
    for (int ni = 0; ni < 2; ni++) {
      const int rn = wn * 32 + ni * 16 + l16;
      bH[ni] = *(const bf16x8*)&Wh[rn * LW + qd * 8];
      bL[ni] = *(const bf16x8*)&Wl[rn * LW + qd * 8];
    }
#pragma unroll
    for (int mi = 0; mi < 4; mi++) {
      const int rm = wm * 64 + mi * 16 + l16;
      const bf16x8 aH = *(const bf16x8*)&Xh[rm * LW + qd * 8];
      const bf16x8 aL = *(const bf16x8*)&Xl[rm * LW + qd * 8];
#pragma unroll
      for (int ni = 0; ni < 2; ni++) {
        acc[mi][ni] = __builtin_amdgcn_mfma_f32_16x16x32_bf16(aH, bH[ni], acc[mi][ni], 0, 0, 0);
        acc[mi][ni] = __builtin_amdgcn_mfma_f32_16x16x32_bf16(aL, bH[ni], acc[mi][ni], 0, 0, 0);
        acc[mi][ni] = __builtin_amdgcn_mfma_f32_16x16x32_bf16(aH, bL[ni], acc[mi][ni], 0, 0, 0);
      }
    }
  }
  const int h = blockIdx.x;
#pragma unroll
  for (int mi = 0; mi < 4; mi++)
#pragma unroll
    for (int ni = 0; ni < 2; ni++) {
      const int d = wn * 32 + ni * 16 + l16;
#pragma unroll
      for (int r = 0; r < 4; r++) {
        const int s = m0 + wm * 64 + mi * 16 + qd * 4 + r;
        const float val = acc[mi][ni][r];
        const size_t idx = (((size_t)h * kS) + s) * kDH + d;
        if (z == 2) {
          v[idx] = val;
        } else {
          short hh, ll; kar_split_bf(val, hh, ll);
          if (z == 0) { qsh[idx] = hh; qsl[idx] = ll; }
          else        { ksh[idx] = hh; ksl[idx] = ll; }
        }
      }
    }
}

// MFMA split-bf16 GEMM: out = tmp @ Wo
__global__ __launch_bounds__(256) void kar_mfma_gemm_wo_kernel(
    const short* __restrict__ th, const short* __restrict__ tl,
    const short* __restrict__ Bh, const short* __restrict__ Bl,
    float* __restrict__ outp) {
  const int n0 = blockIdx.x * 64;
  const int m0 = blockIdx.y * 128;
  constexpr int LW = 40;
  __shared__ short Xh[128 * LW], Xl[128 * LW], Wh[64 * LW], Wl[64 * LW];
  const int t = threadIdx.x, lane = t & 63, wv = t >> 6;
  const int wm = wv >> 1, wn = wv & 1, l16 = lane & 15, qd = lane >> 4;
  f32x4 acc[4][2];
#pragma unroll
  for (int i = 0; i < 4; i++)
#pragma unroll
    for (int j = 0; j < 2; j++) acc[i][j] = (f32x4){0.f, 0.f, 0.f, 0.f};
  const int xrow = t >> 1, xc = (t & 1) * 16;
  for (int k0 = 0; k0 < kD; k0 += 32) {
    __syncthreads();
    {
      const size_t xs = (size_t)(m0 + xrow) * kD + k0 + xc;
      *(bf16x8*)&Xh[xrow * LW + xc]     = *(const bf16x8*)&th[xs];
      *(bf16x8*)&Xh[xrow * LW + xc + 8] = *(const bf16x8*)&th[xs + 8];
      *(bf16x8*)&Xl[xrow * LW + xc]     = *(const bf16x8*)&tl[xs];
      *(bf16x8*)&Xl[xrow * LW + xc + 8] = *(const bf16x8*)&tl[xs + 8];
    }
    if (t < 128) {
      const int wrow = t >> 1, wc = (t & 1) * 16;
      const size_t wsrc = (size_t)(n0 + wrow) * kD + k0 + wc;
      *(bf16x8*)&Wh[wrow * LW + wc]     = *(const bf16x8*)&Bh[wsrc];
      *(bf16x8*)&Wh[wrow * LW + wc + 8] = *(const bf16x8*)&Bh[wsrc + 8];
    } else {
      const int t2 = t - 128, wrow = t2 >> 1, wc = (t2 & 1) * 16;
      const size_t wsrc = (size_t)(n0 + wrow) * kD + k0 + wc;
      *(bf16x8*)&Wl[wrow * LW + wc]     = *(const bf16x8*)&Bl[wsrc];
      *(bf16x8*)&Wl[wrow * LW + wc + 8] = *(const bf16x8*)&Bl[wsrc + 8];
    }
    __syncthreads();
    bf16x8 bH[2], bL[2];
#pragma unroll
    for (int ni = 0; ni < 2; ni++) {
      const int rn = wn * 32 + ni * 16 + l16;
      bH[ni] = *(const bf16x8*)&Wh[rn * LW + qd * 8];
      bL[ni] = *(const bf16x8*)&Wl[rn * LW + qd * 8];
    }
#pragma unroll
    for (int mi = 0; mi < 4; mi++) {
      const int rm = wm * 64 + mi * 16 + l16;
      const bf16x8 aH = *(const bf16x8*)&Xh[rm * LW + qd * 8];
      const bf16x8 aL = *(const bf16x8*)&Xl[rm * LW + qd * 8];
#pragma unroll
      for (int ni = 0; ni < 2; ni++) {
        acc[mi][ni] = __builtin_amdgcn_mfma_f32_16x16x32_bf16(aH, bH[ni], acc[mi][ni], 0, 0, 0);
        acc[mi][ni] = __builtin_amdgcn_mfma_f32_16x16x32_bf16(aL, bH[ni], acc[mi][ni], 0, 0, 0);
        acc[mi][ni] = __builtin_amdgcn_mfma_f32_16x16x32_bf16(aH, bL[ni], acc[mi][ni], 0, 0, 0);
      }
    }
  }
#pragma unroll
  for (int mi = 0; mi < 4; mi++)
#pragma unroll
    for (int ni = 0; ni < 2; ni++) {
      const int col = n0 + wn * 32 + ni * 16 + l16;
#pragma unroll
      for (int r = 0; r < 4; r++) {
        const int s = m0 + wm * 64 + mi * 16 + qd * 4 + r;
        outp[(size_t)s * kD + col] = acc[mi][ni][r];
      }
    }
}

// norms from splits
__global__ __launch_bounds__(256) void kar_norms2_kernel(
    const short* __restrict__ qsh, const short* __restrict__ qsl,
    const short* __restrict__ ksh, const short* __restrict__ ksl,
    double* __restrict__ qn, double* __restrict__ kn) {
  int o = blockIdx.x * 256 + threadIdx.x;
  const short *sh, *sl; double* dst; int p;
  if (o < kH * kS) { sh = qsh; sl = qsl; dst = qn; p = o; }
  else             { sh = ksh; sl = ksl; dst = kn; p = o - kH * kS; }
  const short* rh = sh + (size_t)p * kDH;
  const short* rl = sl + (size_t)p * kDH;
  double s = 0.0;
  for (int i = 0; i < kDH; i += 4) {
    short4 a = *(const short4*)&rh[i];
    short4 b = *(const short4*)&rl[i];
    double e0 = (double)kar_bf2f(a.x) + (double)kar_bf2f(b.x);
    double e1 = (double)kar_bf2f(a.y) + (double)kar_bf2f(b.y);
    double e2 = (double)kar_bf2f(a.z) + (double)kar_bf2f(b.z);
    double e3 = (double)kar_bf2f(a.w) + (double)kar_bf2f(b.w);
    s += e0 * e0 + e1 * e1 + e2 * e2 + e3 * e3;
  }
  dst[p] = s;
}

// diag_p from splits
__global__ __launch_bounds__(256) void kar_diagp2_kernel(
    const short* __restrict__ qsh, const short* __restrict__ qsl,
    const short* __restrict__ ksh, const short* __restrict__ ksl,
    const double* __restrict__ qn, const double* __restrict__ kn,
    const double* __restrict__ SC, const float* __restrict__ dsc,
    const float* __restrict__ reg, double* __restrict__ dgp) {
  int o = blockIdx.x * 256 + threadIdx.x;
  int h = o >> 11;
  const short* qh = qsh + (size_t)o * kDH;
  const short* ql = qsl + (size_t)o * kDH;
  const short* kh = ksh + (size_t)o * kDH;
  const short* kl = ksl + (size_t)o * kDH;
  double dot = 0.0;
  for (int i = 0; i < kDH; i++) {
    double qi = (double)kar_bf2f(qh[i]) + (double)kar_bf2f(ql[i]);
    double ki = (double)kar_bf2f(kh[i]) + (double)kar_bf2f(kl[i]);
    dot += qi * ki;
  }
  double dist = fmax(qn[o] + kn[o] - 2.0 * dot, 0.0);
  double Kss = exp(-dist * SC[0]);
  double sp  = log1p(exp(Kss));
  dgp[o] = sp * (double)dsc[h] + (double)reg[0];
}

// fused K-apply v6: K and alpha^T fragments loaded DIRECT from global (no LDS
// staging); only P transposes through LDS (double-buffered, 1 barrier/chunk).
template <bool FINAL>
__global__ __launch_bounds__(256, 2) void kar_mfma_iter6_kernel(
    const short* __restrict__ qsh, const short* __restrict__ qsl,
    const short* __restrict__ ksh, const short* __restrict__ ksl,
    const short* __restrict__ ath,
    const float* __restrict__ alpha, const float* __restrict__ v,
    const double* __restrict__ qn, const double* __restrict__ kn,
    const double* __restrict__ SC, float* __restrict__ outp,
    short* __restrict__ tmph, short* __restrict__ tmpl,
    const float* __restrict__ Ug, double* __restrict__ utrp) {
  constexpr int LDW = 72;
  __shared__ short Ph[2][64 * LDW];
  __shared__ float qns[64];
  __shared__ float Ub[64][16];
  const int h   = blockIdx.y;
  const int s0  = blockIdx.x * 64;
  const int tid = threadIdx.x;
  const int lane = tid & 63;
  const int wv   = tid >> 6;     // wave: owns t-quarter (ph1), d-quarter (ph2)
  const int l16  = lane & 15;
  const int qd   = lane >> 4;
  // Q fragments for ALL 4 s-quarters in registers
  bf16x8 qH[4][2], qL[4][2];
#pragma unroll
  for (int sq = 0; sq < 4; sq++) {
    const size_t qb = (((size_t)h * kS) + s0 + sq * 16 + l16) * kDH;
    qH[sq][0] = *(const bf16x8*)&qsh[qb + qd * 8];
    qH[sq][1] = *(const bf16x8*)&qsh[qb + 32 + qd * 8];
    qL[sq][0] = *(const bf16x8*)&qsl[qb + qd * 8];
    qL[sq][1] = *(const bf16x8*)&qsl[qb + 32 + qd * 8];
  }
  if (tid < 64) qns[tid] = (float)qn[h * kS + s0 + tid];
  if (!FINAL)
    *(float4*)&Ub[tid >> 2][(tid & 3) * 4] =
        *(const float4*)&Ug[((size_t)h * kS + s0 + (tid >> 2)) * kR + (tid & 3) * 4];
  __syncthreads();  // qns (and Ub) visible before first use
  const float cc = (float)SC[0];
  f32x4 acco[4];
#pragma unroll
  for (int i = 0; i < 4; i++) acco[i] = (f32x4){0.f, 0.f, 0.f, 0.f};

  // per-wave global row bases (wave's own t-rows / d-rows)
  const short*  kRowH = &ksh[(((size_t)h * kS) + wv * 16 + l16) * kDH];
  const short*  kRowL = &ksl[(((size_t)h * kS) + wv * 16 + l16) * kDH];
  const short*  aRow  = &ath[((size_t)h * kDH + wv * 16 + l16) * kS];
  const double* knp   = &kn[h * kS + wv * 16 + l16];

  int buf = 0;
  for (int t0 = 0; t0 < kS; t0 += 64, buf ^= 1) {
    // ---- direct global fragment loads (no barrier dependency -> prefetchable)
    const size_t ko0 = (size_t)t0 * kDH + qd * 8;
    const bf16x8 kH0 = *(const bf16x8*)&kRowH[ko0];
    const bf16x8 kH1 = *(const bf16x8*)&kRowH[ko0 + 32];
    const bf16x8 kL0 = *(const bf16x8*)&kRowL[ko0];
    const bf16x8 kL1 = *(const bf16x8*)&kRowL[ko0 + 32];
    const bf16x8 aH0 = *(const bf16x8*)&aRow[t0 + qd * 8];
    const bf16x8 aH1 = *(const bf16x8*)&aRow[t0 + 32 + qd * 8];
    const float  knr = (float)knp[t0];
    // ---- phase 1: QK^T, wave owns t-columns [wv*16,+16) for all 64 s rows
    f32x4 accp[4];
#pragma unroll
    for (int i = 0; i < 4; i++) accp[i] = (f32x4){0.f, 0.f, 0.f, 0.f};
#pragma unroll
    for (int sq = 0; sq < 4; sq++) {
      accp[sq] = __builtin_amdgcn_mfma_f32_16x16x32_bf16(qH[sq][0], kH0, accp[sq], 0, 0, 0);
      accp[sq] = __builtin_amdgcn_mfma_f32_16x16x32_bf16(qL[sq][0], kH0, accp[sq], 0, 0, 0);
      accp[sq] = __builtin_amdgcn_mfma_f32_16x16x32_bf16(qH[sq][0], kL0, accp[sq], 0, 0, 0);
    }
#pragma unroll
    for (int sq = 0; sq < 4; sq++) {
      accp[sq] = __builtin_amdgcn_mfma_f32_16x16x32_bf16(qH[sq][1], kH1, accp[sq], 0, 0, 0);
      accp[sq] = __builtin_amdgcn_mfma_f32_16x16x32_bf16(qL[sq][1], kH1, accp[sq], 0, 0, 0);
      accp[sq] = __builtin_amdgcn_mfma_f32_16x16x32_bf16(qH[sq][1], kL1, accp[sq], 0, 0, 0);
    }
    // ---- exp + write P[buf] (own t-columns, all s rows)
#pragma unroll
    for (int sq = 0; sq < 4; sq++) {
#pragma unroll
      for (int r = 0; r < 4; r++) {
        const int srow = sq * 16 + qd * 4 + r;
        const float e2 = fmaf(2.0f, accp[sq][r], -(qns[srow] + knr));
        const float val = __expf(fminf(e2, 0.0f) * cc);
        Ph[buf][srow * LDW + wv * 16 + l16] = (short)kar_f2bf(val);
      }
    }
    __syncthreads();  // P[buf] complete; prev buffer's readers also done
    // ---- phase 2: acc += P @ alpha_hi, wave owns d-columns [wv*16,+16)
#pragma unroll
    for (int sq = 0; sq < 4; sq++) {
      const bf16x8 pH0 = *(const bf16x8*)&Ph[buf][(sq * 16 + l16) * LDW + qd * 8];
      acco[sq] = __builtin_amdgcn_mfma_f32_16x16x32_bf16(pH0, aH0, acco[sq], 0, 0, 0);
      const bf16x8 pH1 = *(const bf16x8*)&Ph[buf][(sq * 16 + l16) * LDW + 32 + qd * 8];
      acco[sq] = __builtin_amdgcn_mfma_f32_16x16x32_bf16(pH1, aH1, acco[sq], 0, 0, 0);
    }
  }
  const int d = wv * 16 + l16;
  if (FINAL) {
#pragma unroll
    for (int sq = 0; sq < 4; sq++) {
#pragma unroll
      for (int r = 0; r < 4; r++) {
        const int s = s0 + sq * 16 + qd * 4 + r;
        short hh, ll; kar_split_bf(acco[sq][r], hh, ll);
        tmph[(size_t)s * kD + h * kDH + d] = hh;
        tmpl[(size_t)s * kD + h * kDH + d] = ll;
      }
    }
  } else {
    const float lamf = (float)SC[1];
    float rv[4][4];
#pragma unroll
    for (int sq = 0; sq < 4; sq++) {
#pragma unroll
      for (int r = 0; r < 4; r++) {
        const int s = s0 + sq * 16 + qd * 4 + r;
        const size_t eg = ((size_t)h * kS + s) * kDH + d;
        const float rr = v[eg] - (acco[sq][r] + lamf * alpha[eg]);
        rv[sq][r] = rr;
        outp[eg] = rr;
      }
    }
    // ---- fused U^T r partial for this 64-s block ----
    double uacc[16];
#pragma unroll
    for (int ri = 0; ri < 16; ri++) uacc[ri] = 0.0;
#pragma unroll
    for (int sq = 0; sq < 4; sq++) {
#pragma unroll
      for (int r = 0; r < 4; r++) {
        const int sl = sq * 16 + qd * 4 + r;
        const double rval = (double)rv[sq][r];
        const float4 u0 = *(const float4*)&Ub[sl][0];
        const float4 u1 = *(const float4*)&Ub[sl][4];
        const float4 u2 = *(const float4*)&Ub[sl][8];
        const float4 u3 = *(const float4*)&Ub[sl][12];
        uacc[0]  += (double)u0.x * rval; uacc[1]  += (double)u0.y * rval;
        uacc[2]  += (double)u0.z * rval; uacc[3]  += (double)u0.w * rval;
        uacc[4]  += (double)u1.x * rval; uacc[5]  += (double)u1.y * rval;
        uacc[6]  += (double)u1.z * rval; uacc[7]  += (double)u1.w * rval;
        uacc[8]  += (double)u2.x * rval; uacc[9]  += (double)u2.y * rval;
        uacc[10] += (double)u2.z * rval; uacc[11] += (double)u2.w * rval;
        uacc[12] += (double)u3.x * rval; uacc[13] += (double)u3.y * rval;
        uacc[14] += (double)u3.z * rval; uacc[15] += (double)u3.w * rval;
      }
    }
#pragma unroll
    for (int ri = 0; ri < 16; ri++) {
      uacc[ri] += __shfl_xor(uacc[ri], 16, 64);
      uacc[ri] += __shfl_xor(uacc[ri], 32, 64);
    }
    if (qd == 0) {
#pragma unroll
      for (int ri = 0; ri < 16; ri++)
        utrp[(((size_t)(h * 32) + blockIdx.x) * kR + ri) * kDH + d] = uacc[ri];
    }
  }
}

// ================= OLD PATH (R4 fallback) kernels =================
__global__ __launch_bounds__(256) void kar_gemm_qkv_f32_kernel(
    const float* __restrict__ x,
    const float* __restrict__ Wq, const float* __restrict__ Wk, const float* __restrict__ Wv,
    float* __restrict__ q, float* __restrict__ k, float* __restrict__ v) {
  const float* W = (blockIdx.z == 0) ? Wq : (blockIdx.z == 1) ? Wk : Wv;
  float* outp    = (blockIdx.z == 0) ? q  : (blockIdx.z == 1) ? k  : v;
  const int n0 = blockIdx.x * 64;
  const int m0 = blockIdx.y * 64;
  const int tid = threadIdx.x;
  const int tx = tid & 15, ty = tid >> 4;
  __shared__ float As[16][68];
  __shared__ float Bs[16][68];
  double acc[4][4] = {};
  const int lr = tid >> 2;
  const int lk = (tid & 3) * 4;
  const int br = tid >> 4;
  const int bc = (tid & 15) * 4;
  for (int k0 = 0; k0 < kD; k0 += 16) {
    const float4 a4 = *(const float4*)&x[(size_t)(m0 + lr) * kD + k0 + lk];
    const float4 b4 = *(const float4*)&W[(size_t)(k0 + br) * kD + n0 + bc];
    __syncthreads();
    As[lk + 0][lr] = a4.x; As[lk + 1][lr] = a4.y;
    As[lk + 2][lr] = a4.z; As[lk + 3][lr] = a4.w;
    *(float4*)&Bs[br][bc] = b4;
    __syncthreads();
    float c32[4][4] = {};
#pragma unroll
    for (int kk = 0; kk < 16; kk++) {
      const float4 av = *(const float4*)&As[kk][ty * 4];
      const float4 bv = *(const float4*)&Bs[kk][tx * 4];
      const float a_[4] = {av.x, av.y, av.z, av.w};
      const float b_[4] = {bv.x, bv.y, bv.z, bv.w};
#pragma unroll
      for (int i = 0; i < 4; i++)
#pragma unroll
        for (int j = 0; j < 4; j++) c32[i][j] = fmaf(a_[i], b_[j], c32[i][j]);
    }
#pragma unroll
    for (int i = 0; i < 4; i++)
#pragma unroll
      for (int j = 0; j < 4; j++) acc[i][j] += (double)c32[i][j];
  }
  const int h = n0 >> 6;
#pragma unroll
  for (int i = 0; i < 4; i++) {
    const int s = m0 + ty * 4 + i;
    float4 o;
    o.x = (float)acc[i][0]; o.y = (float)acc[i][1];
    o.z = (float)acc[i][2]; o.w = (float)acc[i][3];
    *(float4*)&outp[((size_t)h * kS + s) * kDH + tx * 4] = o;
  }
}

__global__ __launch_bounds__(256) void kar_gemm_plain_kernel(
    const float* __restrict__ A, const float* __restrict__ W, float* __restrict__ C) {
  const int n0 = blockIdx.x * 64;
  const int m0 = blockIdx.y * 64;
  const int tid = threadIdx.x;
  const int tx = tid & 15, ty = tid >> 4;
  __shared__ float As[16][68];
  __shared__ float Bs[16][68];
  double acc[4][4] = {};
  const int lr = tid >> 2;
  const int lk = (tid & 3) * 4;
  const int br = tid >> 4;
  const int bc = (tid & 15) * 4;
  for (int k0 = 0; k0 < kD; k0 += 16) {
    const float4 a4 = *(const float4*)&A[(size_t)(m0 + lr) * kD + k0 + lk];
    const float4 b4 = *(const float4*)&W[(size_t)(k0 + br) * kD + n0 + bc];
    __syncthreads();
    As[lk + 0][lr] = a4.x; As[lk + 1][lr] = a4.y;
    As[lk + 2][lr] = a4.z; As[lk + 3][lr] = a4.w;
    *(float4*)&Bs[br][bc] = b4;
    __syncthreads();
    float c32[4][4] = {};
#pragma unroll
    for (int kk = 0; kk < 16; kk++) {
      const float4 av = *(const float4*)&As[kk][ty * 4];
      const float4 bv = *(const float4*)&Bs[kk][tx * 4];
      const float a_[4] = {av.x, av.y, av.z, av.w};
      const float b_[4] = {bv.x, bv.y, bv.z, bv.w};
#pragma unroll
      for (int i = 0; i < 4; i++)
#pragma unroll
        for (int j = 0; j < 4; j++) c32[i][j] = fmaf(a_[i], b_[j], c32[i][j]);
    }
#pragma unroll
    for (int i = 0; i < 4; i++)
#pragma unroll
      for (int j = 0; j < 4; j++) acc[i][j] += (double)c32[i][j];
  }
#pragma unroll
  for (int i = 0; i < 4; i++) {
    const int s = m0 + ty * 4 + i;
    float4 o;
    o.x = (float)acc[i][0]; o.y = (float)acc[i][1];
    o.z = (float)acc[i][2]; o.w = (float)acc[i][3];
    *(float4*)&C[(size_t)s * kD + n0 + tx * 4] = o;
  }
}

__global__ __launch_bounds__(256) void kar_norms_f32_kernel(const float* __restrict__ q,
                                                            const float* __restrict__ k,
                                                            double* __restrict__ qn,
                                                            double* __restrict__ kn) {
  int o = blockIdx.x * 256 + threadIdx.x;
  const float* src; double* dst; int p;
  if (o < kH * kS) { src = q; dst = qn; p = o; }
  else             { src = k; dst = kn; p = o - kH * kS; }
  const float* rowp = src + (size_t)p * kDH;
  double s = 0.0;
  for (int i = 0; i < kDH; i += 4) {
    float4 x4 = *(const float4*)&rowp[i];
    s += (double)x4.x * (double)x4.x + (double)x4.y * (double)x4.y +
         (double)x4.z * (double)x4.z + (double)x4.w * (double)x4.w;
  }
  dst[p] = s;
}

__global__ __launch_bounds__(256) void kar_diagp_f32_kernel(
    const float* __restrict__ q, const float* __restrict__ k,
    const double* __restrict__ qn, const double* __restrict__ kn,
    const double* __restrict__ SC, const float* __restrict__ dsc,
    const float* __restrict__ reg, double* __restrict__ dgp) {
  int o = blockIdx.x * 256 + threadIdx.x;
  int h = o >> 11;
  const float* qp = q + (size_t)o * kDH;
  const float* kp = k + (size_t)o * kDH;
  double dot = 0.0;
  for (int i = 0; i < kDH; i++) dot += (double)qp[i] * (double)kp[i];
  double dist = fmax(qn[o] + kn[o] - 2.0 * dot, 0.0);
  double Kss = exp(-dist * SC[0]);
  double sp  = log1p(exp(Kss));
  dgp[o] = sp * (double)dsc[h] + (double)reg[0];
}

template <bool FINAL>
__global__ __launch_bounds__(256, 2) void kar_mfma_iterA_kernel(
    const float* __restrict__ q, const float* __restrict__ k,
    const float* __restrict__ alpha, const float* __restrict__ v,
    const double* __restrict__ qn, const double* __restrict__ kn,
    const double* __restrict__ SC, float* __restrict__ outp) {
  constexpr int LDW = 72;
  __shared__ short Qh[64 * LDW], Ql[64 * LDW];
  __shared__ short Kh[64 * LDW], Kl[64 * LDW];
  __shared__ short Ph[64 * LDW], Pl[64 * LDW];
  __shared__ short Ah[64 * LDW], Al[64 * LDW];
  __shared__ float qns[64], kns[64];
  const int h   = blockIdx.y;
  const int s0  = blockIdx.x * 64;
  const int tid = threadIdx.x;
  const int lane = tid & 63;
  const int wv   = tid >> 6;
  const int l16  = lane & 15;
  const int qd   = lane >> 4;
  const int m16  = wv * 16;
  const float* qh = q + ((size_t)h * kS + s0) * kDH;
  const float* kh = k + (size_t)h * kS * kDH;
  const float* ah = alpha + (size_t)h * kS * kDH;
  {
    const int row = tid >> 4;
    const int c4  = (tid & 15) * 4;
#pragma unroll
    for (int rep = 0; rep < 4; rep++) {
      const int r = rep * 16 + row;
      const float4 a = *(const float4*)&qh[(size_t)r * kDH + c4];
      short h0, l0, h1, l1, h2, l2, h3, l3;
      kar_split_bf(a.x, h0, l0); kar_split_bf(a.y, h1, l1);
      kar_split_bf(a.z, h2, l2); kar_split_bf(a.w, h3, l3);
      *(short4*)&Qh[r * LDW + c4] = make_short4(h0, h1, h2, h3);
      *(short4*)&Ql[r * LDW + c4] = make_short4(l0, l1, l2, l3);
    }
    if (tid < 64) qns[tid] = (float)qn[h * kS + s0 + tid];
  }
  const float cc = (float)SC[0];
  f32x4 acco[4];
#pragma unroll
  for (int i = 0; i < 4; i++) acco[i] = (f32x4){0.f, 0.f, 0.f, 0.f};
  for (int t0 = 0; t0 < kS; t0 += 64) {
    __syncthreads();
    {
      const int row = tid >> 4;
      const int c4  = (tid & 15) * 4;
#pragma unroll
      for (int rep = 0; rep < 4; rep++) {
        const int r = rep * 16 + row;
        const float4 b = *(const float4*)&kh[(size_t)(t0 + r) * kDH + c4];
        short h0, l0, h1, l1, h2, l2, h3, l3;
        kar_split_bf(b.x, h0, l0); kar_split_bf(b.y, h1, l1);
        kar_split_bf(b.z, h2, l2); kar_split_bf(b.w, h3, l3);
        *(short4*)&Kh[r * LDW + c4] = make_short4(h0, h1, h2, h3);
        *(short4*)&Kl[r * LDW + c4] = make_short4(l0, l1, l2, l3);
        const float4 av = *(const float4*)&ah[(size_t)(t0 + r) * kDH + c4];
        kar_split_bf(av.x, h0, l0); kar_split_bf(av.y, h1, l1);
        kar_split_bf(av.z, h2, l2); kar_split_bf(av.w, h3, l3);
        Ah[(c4 + 0) * LDW + r] = h0; Al[(c4 + 0) * LDW + r] = l0;
        Ah[(c4 + 1) * LDW + r] = h1; Al[(c4 + 1) * LDW + r] = l1;
        Ah[(c4 + 2) * LDW + r] = h2; Al[(c4 + 2) * LDW + r] = l2;
        Ah[(c4 + 3) * LDW + r] = h3; Al[(c4 + 3) * LDW + r] = l3;
      }
      if (tid < 64) kns[tid] = (float)kn[h * kS + t0 + tid];
    }
    __syncthreads();
    f32x4 accp[4];
#pragma unroll
    for (int i = 0; i < 4; i++) accp[i] = (f32x4){0.f, 0.f, 0.f, 0.f};
#pragma unroll
    for (int kt = 0; kt < 2; kt++) {
      const int ko = kt * 32 + qd * 8;
      const bf16x8 aH = *(const bf16x8*)&Qh[(m16 + l16) * LDW + ko];
      const bf16x8 aL = *(const bf16x8*)&Ql[(m16 + l16) * LDW + ko];
#pragma unroll
      for (int nt = 0; nt < 4; nt++) {
        const bf16x8 bH = *(const bf16x8*)&Kh[(nt * 16 + l16) * LDW + ko];
        const bf16x8 bL = *(const bf16x8*)&Kl[(nt * 16 + l16) * LDW + ko];
        accp[nt] = __builtin_amdgcn_mfma_f32_16x16x32_bf16(aH, bH, accp[nt], 0, 0, 0);
        accp[nt] = __builtin_amdgcn_mfma_f32_16x16x32_bf16(aL, bH, accp[nt], 0, 0, 0);
        accp[nt] = __builtin_amdgcn_mfma_f32_16x16x32_bf16(aH, bL, accp[nt], 0, 0, 0);
      }
    }
#pragma unroll
    for (int nt = 0; nt < 4; nt++) {
      const int tcol = nt * 16 + l16;
      const float kv = kns[tcol];
#pragma unroll
      for (int r = 0; r < 4; r++) {
        const int srow = m16 + qd * 4 + r;
        const float e2 = fmaf(2.0f, accp[nt][r], -(qns[srow] + kv));
        const float val = __expf(fminf(e2, 0.0f) * cc);
        short hb, lb; kar_split_bf(val, hb, lb);
        Ph[srow * LDW + tcol] = hb;
        Pl[srow * LDW + tcol] = lb;
      }
    }
#pragma unroll
    for (int kt = 0; kt < 2; kt++) {
      const int ko = kt * 32 + qd * 8;
      const bf16x8 pH = *(const bf16x8*)&Ph[(m16 + l16) * LDW + ko];
      const bf16x8 pL = *(const bf16x8*)&Pl[(m16 + l16) * LDW + ko];
#pragma unroll
      for (int dt = 0; dt < 4; dt++) {
        const bf16x8 bH = *(const bf16x8*)&Ah[(dt * 16 + l16) * LDW + ko];
        const bf16x8 bL = *(const bf16x8*)&Al[(dt * 16 + l16) * LDW + ko];
        acco[dt] = __builtin_amdgcn_mfma_f32_16x16x32_bf16(pH, bH, acco[dt], 0, 0, 0);
        acco[dt] = __builtin_amdgcn_mfma_f32_16x16x32_bf16(pL, bH, acco[dt], 0, 0, 0);
        acco[dt] = __builtin_amdgcn_mfma_f32_16x16x32_bf16(pH, bL, acco[dt], 0, 0, 0);
      }
    }
  }
  if (FINAL) {
#pragma unroll
    for (int dt = 0; dt < 4; dt++) {
#pragma unroll
      for (int r = 0; r < 4; r++) {
        const int s = s0 + m16 + qd * 4 + r;
        const int d = dt * 16 + l16;
        outp[(size_t)s * kD + h * kDH + d] = acco[dt][r];
      }
    }
  } else {
    const float lamf = (float)SC[1];
#pragma unroll
    for (int dt = 0; dt < 4; dt++) {
#pragma unroll
      for (int r = 0; r < 4; r++) {
        const int s = s0 + m16 + qd * 4 + r;
        const int d = dt * 16 + l16;
        const size_t eg = ((size_t)h * kS + s) * kDH + d;
        outp[eg] = v[eg] - (acco[dt][r] + lamf * alpha[eg]);
      }
    }
  }
}

extern "C" void kernel_launch(void* const* d_in, const int* in_sizes, int n_in,
                              void* d_out, int out_size, void* d_ws, size_t ws_size,
                              hipStream_t stream) {
  (void)in_sizes; (void)n_in; (void)out_size;
  const float* x    = (const float*)d_in[0];
  const float* Wq   = (const float*)d_in[1];
  const float* Wk   = (const float*)d_in[2];
  const float* Wv   = (const float*)d_in[3];
  const float* Wo   = (const float*)d_in[4];
  const float* bw   = (const float*)d_in[5];
  const float* dsc  = (const float*)d_in[6];
  const float* pe   = (const float*)d_in[7];
  const float* hp   = (const float*)d_in[8];
  const float* reg  = (const float*)d_in[9];
  const float* lreg = (const float*)d_in[10];
  float* out = (float*)d_out;

  char* w = (char*)d_ws;
  size_t off = 0;
  auto take = [&](size_t bytes) -> void* {
    void* p = w + off;
    off += (bytes + 255) & ~(size_t)255;
    return p;
  };
  const size_t HSD = (size_t)kH * kS * kDH;  // 2M elements

  // ---- new-path layout ----
  float*  v_    = (float*)take(HSD * 4);
  float*  alpha = (float*)take(HSD * 4);
  float*  rbuf  = (float*)take(HSD * 4);
  short*  qsh   = (short*)take(HSD * 2);
  short*  qsl   = (short*)take(HSD * 2);
  short*  ksh   = (short*)take(HSD * 2);
  short*  ksl   = (short*)take(HSD * 2);
  short*  ath   = (short*)take(HSD * 2);
  short*  xh    = (short*)take((size_t)kS * kD * 2);  // reused as tmph
  short*  xl    = (short*)take((size_t)kS * kD * 2);  // reused as tmpl
  short*  WTh   = (short*)take((size_t)4 * kD * kD * 2);
  short*  WTl   = (short*)take((size_t)4 * kD * kD * 2);
  double* qn    = (double*)take((size_t)kH * kS * 8);
  double* kn    = (double*)take((size_t)kH * kS * 8);
  double* dgp   = (double*)take((size_t)kH * kS * 8);
  float*  U     = (float*)take((size_t)kH * kS * kR * 4);
  double* utr   = (double*)take((size_t)kH * kR * kDH * 8);
  double* utrp  = (double*)take((size_t)kH * 32 * kR * kDH * 8);
  double* SC    = (double*)take(256);
  const size_t need_new = off;

  if (ws_size >= need_new) {
    // ================= NEW PATH =================
    kar_scalars_kernel<<<1, 64, 0, stream>>>(bw, lreg, SC);
    kar_xsplit_kernel<<<2048, 256, 0, stream>>>(x, xh, xl);
    kar_wsplit_kernel<<<dim3(16, 16, 4), 256, 0, stream>>>(Wq, Wk, Wv, Wo, WTh, WTl);
    kar_mfma_gemm_qkv_kernel<<<dim3(16, 16, 3), 256, 0, stream>>>(
        xh, xl, WTh, WTl, v_, qsh, qsl, ksh, ksl);
    kar_norms2_kernel<<<256, 256, 0, stream>>>(qsh, qsl, ksh, ksl, qn, kn);
    kar_u_kernel<<<2048, 256, 0, stream>>>(pe, hp, U);
    kar_diagp2_kernel<<<128, 256, 0, stream>>>(qsh, qsl, ksh, ksl, qn, kn, SC, dsc, reg, dgp);

    // it 0: alpha == 0 -> r == v; standalone utr partial on v
    kar_utr_partial_kernel<<<dim3(32, kH), 256, 0, stream>>>(U, v_, utrp);
    kar_utr_reduce_kernel<<<64, 256, 0, stream>>>(utrp, utr);
    kar_update_t_kernel<<<dim3(32, kH), 256, 0, stream>>>(v_, dgp, U, utr, alpha, ath, 1);

    for (int it = 1; it < 5; it++) {
      kar_mfma_iter6_kernel<false><<<dim3(32, kH), 256, 0, stream>>>(
          qsh, qsl, ksh, ksl, ath, alpha, v_, qn, kn, SC, rbuf, nullptr, nullptr, U, utrp);
      kar_utr_reduce_kernel<<<64, 256, 0, stream>>>(utrp, utr);
      kar_update_t_kernel<<<dim3(32, kH), 256, 0, stream>>>(rbuf, dgp, U, utr, alpha, ath, 0);
    }

    kar_mfma_iter6_kernel<true><<<dim3(32, kH), 256, 0, stream>>>(
        qsh, qsl, ksh, ksl, ath, alpha, v_, qn, kn, SC, rbuf, xh, xl, U, utrp);
    kar_mfma_gemm_wo_kernel<<<dim3(16, 16), 256, 0, stream>>>(
        xh, xl, WTh + (size_t)3 * kD * kD, WTl + (size_t)3 * kD * kD, out);
  } else {
    // ================= OLD PATH (R4) =================
    size_t off2 = 0;
    auto take2 = [&](size_t bytes) -> void* {
      void* p = w + off2;
      off2 += (bytes + 255) & ~(size_t)255;
      return p;
    };
    float*  q2    = (float*)take2(HSD * 4);
    float*  k2    = (float*)take2(HSD * 4);
    float*  v2    = (float*)take2(HSD * 4);
    float*  al2   = (float*)take2(HSD * 4);
    float*  rb2   = (float*)take2(HSD * 4);
    float*  tmp2  = (float*)take2((size_t)kS * kD * 4);
    double* qn2   = (double*)take2((size_t)kH * kS * 8);
    double* kn2   = (double*)take2((size_t)kH * kS * 8);
    double* dgp2  = (double*)take2((size_t)kH * kS * 8);
    float*  U2    = (float*)take2((size_t)kH * kS * kR * 4);
    double* utr2  = (double*)take2((size_t)kH * kR * kDH * 8);
    double* utrp2 = (double*)take2((size_t)kH * 32 * kR * kDH * 8);
    double* SC2   = (double*)take2(256);

    kar_scalars_kernel<<<1, 64, 0, stream>>>(bw, lreg, SC2);
    kar_gemm_qkv_f32_kernel<<<dim3(16, 32, 3), 256, 0, stream>>>(x, Wq, Wk, Wv, q2, k2, v2);
    kar_norms_f32_kernel<<<256, 256, 0, stream>>>(q2, k2, qn2, kn2);
    kar_u_kernel<<<2048, 256, 0, stream>>>(pe, hp, U2);
    kar_diagp_f32_kernel<<<128, 256, 0, stream>>>(q2, k2, qn2, kn2, SC2, dsc, reg, dgp2);

    kar_utr_partial_kernel<<<dim3(32, kH), 256, 0, stream>>>(U2, v2, utrp2);
    kar_utr_reduce_kernel<<<64, 256, 0, stream>>>(utrp2, utr2);
    kar_update_kernel<<<8192, 256, 0, stream>>>(v2, dgp2, U2, utr2, al2, 1);

    for (int it = 1; it < 5; it++) {
      kar_mfma_iterA_kernel<false><<<dim3(32, kH), 256, 0, stream>>>(
          q2, k2, al2, v2, qn2, kn2, SC2, rb2);
      kar_utr_partial_kernel<<<dim3(32, kH), 256, 0, stream>>>(U2, rb2, utrp2);
      kar_utr_reduce_kernel<<<64, 256, 0, stream>>>(utrp2, utr2);
      kar_update_kernel<<<8192, 256, 0, stream>>>(rb2, dgp2, U2, utr2, al2, 0);
    }
    kar_mfma_iterA_kernel<true><<<dim3(32, kH), 256, 0, stream>>>(
        q2, k2, al2, v2, qn2, kn2, SC2, tmp2);
    kar_gemm_plain_kernel<<<dim3(16, 32), 256, 0, stream>>>(tmp2, Wo, out);
  }
}